// Round 16
// baseline (409.277 us; speedup 1.0000x reference)
//
#include <hip/hip_runtime.h>

typedef float          f32x4  __attribute__((ext_vector_type(4)));
typedef short          bf16x8 __attribute__((ext_vector_type(8)));
typedef _Float16       f16x8  __attribute__((ext_vector_type(8)));
typedef unsigned short u16x4  __attribute__((ext_vector_type(4)));

static constexpr int kBS = 16;
static constexpr int kHW = 1024;

__device__ __forceinline__ unsigned short f2bf(float x) {
  union { float f; unsigned int u; } v; v.f = x;
  unsigned int r = v.u + 0x7fffu + ((v.u >> 16) & 1u);
  return (unsigned short)(r >> 16);
}
__device__ __forceinline__ float bf2f(unsigned short h) {
  union { unsigned int u; float f; } v; v.u = ((unsigned int)h) << 16;
  return v.f;
}
__device__ __forceinline__ unsigned short h2u(_Float16 h) {
  union { _Float16 h; unsigned short u; } v; v.h = h; return v.u;
}
// order-preserving f32 -> u32 (finite floats)
__device__ __forceinline__ unsigned int fmono(float f) {
  union { float f; unsigned int u; } v; v.f = f;
  return (v.u & 0x80000000u) ? ~v.u : (v.u | 0x80000000u);
}

// 2-plane fp16 split with 4096-scaled residual: x ~= p0 + p1/4096.
__device__ __forceinline__ void split2h(float x, unsigned short& u0, unsigned short& u1) {
  _Float16 h0 = (_Float16)x;
  if (fabsf(x) < 6.1035156e-05f) h0 = (_Float16)0.f;
  const float r = (x - (float)h0) * 4096.f;
  u0 = h2u(h0);
  u1 = h2u((_Float16)r);
}

// ---------------------------------------------------------------------------
__global__ __launch_bounds__(256)
void split_act2h(const f32x4* __restrict__ X, u16x4* __restrict__ P0,
                 u16x4* __restrict__ P1, int n4)
{
  int i = blockIdx.x * 256 + threadIdx.x;
  if (i >= n4) return;
  f32x4 x = X[i];
  u16x4 s0, s1;
#pragma unroll
  for (int u = 0; u < 4; ++u) {
    unsigned short a, b;
    split2h(x[u], a, b);
    s0[u] = a; s1[u] = b;
  }
  P0[i] = s0; P1[i] = s1;
}

__global__ __launch_bounds__(256)
void split_wT2h(const float* __restrict__ Wm, unsigned short* __restrict__ T0,
                unsigned short* __restrict__ T1, int K, int N)
{
  __shared__ float ts[32][33];
  const int k0 = blockIdx.x * 32, n0 = blockIdx.y * 32;
  const int tx = threadIdx.x, ty = threadIdx.y;   // 32 x 8
#pragma unroll
  for (int r = 0; r < 4; ++r)
    ts[ty + r * 8][tx] = Wm[(size_t)(k0 + ty + r * 8) * N + n0 + tx];
  __syncthreads();
#pragma unroll
  for (int r = 0; r < 4; ++r) {
    const int n = ty + r * 8;
    const size_t off = (size_t)(n0 + n) * K + k0 + tx;
    unsigned short a, b;
    split2h(ts[tx][n], a, b);
    T0[off] = a; T1[off] = b;
  }
}

template<bool F16>
__global__ __launch_bounds__(256)
void split_wT1(const float* __restrict__ Wm, unsigned short* __restrict__ T0,
               int K, int N)
{
  __shared__ float ts[32][33];
  const int k0 = blockIdx.x * 32, n0 = blockIdx.y * 32;
  const int tx = threadIdx.x, ty = threadIdx.y;
#pragma unroll
  for (int r = 0; r < 4; ++r)
    ts[ty + r * 8][tx] = Wm[(size_t)(k0 + ty + r * 8) * N + n0 + tx];
  __syncthreads();
#pragma unroll
  for (int r = 0; r < 4; ++r) {
    const int n = ty + r * 8;
    const float x = ts[tx][n];
    const size_t off = (size_t)(n0 + n) * K + k0 + tx;
    T0[off] = F16 ? h2u((_Float16)x) : f2bf(x);
  }
}

// ---------------------------------------------------------------------------
// Staging: one 128x32 16-bit tile -> linear LDS via global_load_lds(16B),
// involution pre-swizzled source cols. 2 loads/wave.
// ---------------------------------------------------------------------------
__device__ __forceinline__ void stage_tile(const unsigned short* src, int K,
                                           unsigned short* ldst, int wv, int lane)
{
#pragma unroll
  for (int i = 0; i < 2; ++i) {
    const int s   = wv * 128 + i * 64 + lane;
    const int row = s >> 2;
    const int gc  = ((s & 3) ^ ((row >> 1) & 3)) * 8;
    __builtin_amdgcn_global_load_lds(
        (const __attribute__((address_space(1))) void*)(src + (size_t)row * K + gc),
        (__attribute__((address_space(3))) void*)(ldst + ((wv * 128 + i * 64) << 3)),
        16, 0, 0);
  }
}

// ---------------------------------------------------------------------------
// ORD0 register-pipelined GEMM: 128x128 tile, 4 waves, BK=32, 3-slot LDS ring
// (48 KB). Per tile: vmcnt -> barrier -> issue NEXT tile's fragment ds_reads
// (2nd register set) -> MFMA CURRENT fragments (no lgkm dependency) ->
// barrier -> stage tile t+3. Breaks the per-phase ds_read->wait->MFMA chain.
// OUTM: 0=f32, 3=bf16, 4=bf16 transposed ([N][M], stride ldc).
// ---------------------------------------------------------------------------
template<int OUTM, bool BIAS, bool RELU, bool F16IN>
__global__ __launch_bounds__(256)
void gkp(const unsigned short* __restrict__ A0, const unsigned short* __restrict__ B0,
         const float* __restrict__ bias,
         float* __restrict__ Cf, unsigned short* __restrict__ O0,
         int K, int ldc, long sA, long sB, long sC, float scale)
{
  extern __shared__ __align__(16) unsigned short lds[];   // 3 slots x 8192

  const int tid  = threadIdx.x;
  const int wv   = tid >> 6, lane = tid & 63;
  const int wr   = wv >> 1,  wc   = wv & 1;
  const int cr   = lane & 15, cg  = lane >> 4;
  const int bm   = blockIdx.x * 128, bn = blockIdx.y * 128;

  const unsigned short* Ap = A0 + (size_t)blockIdx.z * (size_t)sA + (size_t)bm * K;
  const unsigned short* Bp = B0 + (size_t)blockIdx.z * (size_t)sB + (size_t)bn * K;
  const size_t zC = (size_t)blockIdx.z * (size_t)sC;

  f32x4 acc[4][4];
#pragma unroll
  for (int i = 0; i < 4; ++i)
#pragma unroll
    for (int j = 0; j < 4; ++j)
#pragma unroll
      for (int r = 0; r < 4; ++r) acc[i][j][r] = 0.f;

  bf16x8 fX[8], fY[8];   // ping-pong fragment sets: [0..3]=A, [4..7]=B

#define STAGE_SLOT(t, sl)                                                      \
  {                                                                            \
    stage_tile(Ap + (t) * 32, K, lds + (size_t)(sl) * 8192,        wv, lane);  \
    stage_tile(Bp + (t) * 32, K, lds + (size_t)(sl) * 8192 + 4096, wv, lane);  \
  }
#define READF(FR, sl)                                                          \
  {                                                                            \
    const unsigned short* lb = lds + (size_t)(sl) * 8192;                      \
    _Pragma("unroll")                                                          \
    for (int f = 0; f < 4; ++f) {                                              \
      const int ra = wr * 64 + f * 16 + cr;                                    \
      FR[f] = *(const bf16x8*)&lb[(ra * 4 + (cg ^ ((ra >> 1) & 3))) * 8];      \
      const int rb = wc * 64 + f * 16 + cr;                                    \
      FR[4 + f] = *(const bf16x8*)&lb[4096 + (rb * 4 + (cg ^ ((rb >> 1) & 3))) * 8]; \
    }                                                                          \
  }
#define DOMM(FR)                                                               \
  {                                                                            \
    _Pragma("unroll")                                                          \
    for (int i = 0; i < 4; ++i)                                                \
      _Pragma("unroll")                                                        \
      for (int j = 0; j < 4; ++j) {                                            \
        if constexpr (F16IN)                                                   \
          acc[i][j] = __builtin_amdgcn_mfma_f32_16x16x32_f16(                  \
              __builtin_bit_cast(f16x8, FR[i]), __builtin_bit_cast(f16x8, FR[4 + j]), \
              acc[i][j], 0, 0, 0);                                             \
        else                                                                   \
          acc[i][j] = __builtin_amdgcn_mfma_f32_16x16x32_bf16(FR[i], FR[4 + j], \
              acc[i][j], 0, 0, 0);                                             \
      }                                                                        \
  }

  const int nt = K >> 5;                 // 16/32/48 here: even, >= 4
  STAGE_SLOT(0, 0);
  STAGE_SLOT(1, 1);
  STAGE_SLOT(2, 2);
  asm volatile("s_waitcnt vmcnt(8)" ::: "memory");   // slot0 landed
  __builtin_amdgcn_sched_barrier(0);
  __builtin_amdgcn_s_barrier();
  READF(fX, 0);

  for (int t = 0; t < nt; t += 2) {
    // ---- tile t: compute fX; prefetch fY <- slot (t+1)%3 ----
    if (t + 2 < nt) asm volatile("s_waitcnt vmcnt(4)" ::: "memory");
    else            asm volatile("s_waitcnt vmcnt(0)" ::: "memory");
    __builtin_amdgcn_sched_barrier(0);
    __builtin_amdgcn_s_barrier();        // slot t+1 visible to all waves
    READF(fY, (t + 1) % 3);
    DOMM(fX);
    __builtin_amdgcn_s_barrier();        // readers of slot t%3 done (prev iter)
    __builtin_amdgcn_sched_barrier(0);
    if (t + 3 < nt) STAGE_SLOT(t + 3, t % 3);
    // ---- tile t+1: compute fY; prefetch fX <- slot (t+2)%3 ----
    if (t + 3 < nt) asm volatile("s_waitcnt vmcnt(4)" ::: "memory");
    else            asm volatile("s_waitcnt vmcnt(0)" ::: "memory");
    __builtin_amdgcn_sched_barrier(0);
    __builtin_amdgcn_s_barrier();
    if (t + 2 < nt) READF(fX, (t + 2) % 3);
    DOMM(fY);
    __builtin_amdgcn_s_barrier();
    __builtin_amdgcn_sched_barrier(0);
    if (t + 4 < nt) STAGE_SLOT(t + 4, (t + 1) % 3);
  }
#undef STAGE_SLOT
#undef READF
#undef DOMM

  // epilogue: C/D layout col = lane&15, row = 4*(lane>>4)+reg
  float* CfB = Cf + zC;
  unsigned short* O0B = O0 + zC;
#pragma unroll
  for (int fm = 0; fm < 4; ++fm) {
#pragma unroll
    for (int fn = 0; fn < 4; ++fn) {
      const int n  = bn + wc * 64 + fn * 16 + cr;
      const int m0 = bm + wr * 64 + fm * 16 + 4 * cg;
      float bv = 0.f;
      if (BIAS) bv = bias[n];
      f32x4 v = acc[fm][fn];
      if (OUTM == 4) {
        u16x4 o;
#pragma unroll
        for (int r = 0; r < 4; ++r) {
          float x = v[r] * scale + bv;
          if (RELU) x = fmaxf(x, 0.f);
          o[r] = f2bf(x);
        }
        *(u16x4*)(O0B + (size_t)n * ldc + m0) = o;
      } else {
#pragma unroll
        for (int r = 0; r < 4; ++r) {
          float x = v[r] * scale + bv;
          if (RELU) x = fmaxf(x, 0.f);
          const size_t off = (size_t)(m0 + r) * ldc + n;
          if (OUTM == 0) CfB[off] = x;
          else O0B[off] = f2bf(x);
        }
      }
    }
  }
}

// ---------------------------------------------------------------------------
// ORD1 fp16 scaled-residual 2-plane engine (r10-proven, unchanged): 128x128,
// 4 waves, BK=32, KU tiles/phase, DEPTH-deep circular dbuf, counted vmcnt.
// OUTM: 0=f32, 1=2 fp16 planes, 5=2 fp16 planes + fused row-argmax.
// ---------------------------------------------------------------------------
template<int ORD, int KU, int DEPTH, int OUTM, bool BIAS, bool RELU, bool F16IN>
__global__ __launch_bounds__(256)
void gke(const unsigned short* __restrict__ A0, const unsigned short* __restrict__ A1,
         const unsigned short* __restrict__ B0, const unsigned short* __restrict__ B1,
         const float* __restrict__ bias,
         float* __restrict__ Cf, unsigned short* __restrict__ O0,
         unsigned short* __restrict__ O1, unsigned long long* __restrict__ keys,
         int K, int ldc, long sA, long sB, long sC, long sBias, float scale)
{
  constexpr int NP   = ORD + 1;
  constexpr int NT   = 2 * NP;
  constexpr int TPP  = KU * NT;
  constexpr int LPP  = TPP * 2;
  static_assert(DEPTH == 2 || DEPTH == 4, "DEPTH in {2,4}");
  static_assert(LPP == 4 || LPP == 8 || LPP == 16, "vmcnt literals");
  extern __shared__ __align__(16) unsigned short lds[];

  const int tid  = threadIdx.x;
  const int wv   = tid >> 6, lane = tid & 63;
  const int wr   = wv >> 1,  wc   = wv & 1;
  const int cr   = lane & 15, cg  = lane >> 4;
  const int bm   = blockIdx.x * 128, bn = blockIdx.y * 128;

  const size_t zA = (size_t)blockIdx.z * (size_t)sA;
  const size_t zB = (size_t)blockIdx.z * (size_t)sB;
  const size_t zC = (size_t)blockIdx.z * (size_t)sC;
  const size_t zBias = (size_t)blockIdx.z * (size_t)sBias;

  const unsigned short* srcs[NT];
  srcs[0] = A0 + zA + (size_t)bm * K;
  if (NP == 2) srcs[1] = A1 + zA + (size_t)bm * K;
  srcs[NP + 0] = B0 + zB + (size_t)bn * K;
  if (NP == 2) srcs[NP + 1] = B1 + zB + (size_t)bn * K;

  f32x4 acc0[4][4], acc1[4][4];
#pragma unroll
  for (int i = 0; i < 4; ++i)
#pragma unroll
    for (int j = 0; j < 4; ++j)
#pragma unroll
      for (int r = 0; r < 4; ++r) {
        acc0[i][j][r] = 0.f;
        if (ORD == 1) acc1[i][j][r] = 0.f;
      }

#define STAGE_PH(ph, buf)                                                       \
  {                                                                             \
    _Pragma("unroll")                                                           \
    for (int u = 0; u < KU; ++u)                                                \
      _Pragma("unroll")                                                         \
      for (int t = 0; t < NT; ++t)                                              \
        stage_tile(srcs[t] + ((ph) * KU + u) * 32, K,                           \
                   lds + (size_t)((buf) * TPP + u * NT + t) * 4096, wv, lane);  \
  }
#define LOADA(u, pa)                                                            \
  {                                                                             \
    _Pragma("unroll")                                                           \
    for (int f = 0; f < 4; ++f) {                                               \
      const int ra = wr * 64 + f * 16 + cr;                                     \
      af[f] = *(const bf16x8*)&lb[(size_t)((u) * NT + (pa)) * 4096 +            \
                                  (ra * 4 + (cg ^ ((ra >> 1) & 3))) * 8];       \
    }                                                                           \
  }
#define DOPB(u, pb, ACC)                                                        \
  {                                                                             \
    bf16x8 bfr[4];                                                              \
    _Pragma("unroll")                                                           \
    for (int f = 0; f < 4; ++f) {                                               \
      const int rb = wc * 64 + f * 16 + cr;                                     \
      bfr[f] = *(const bf16x8*)&lb[(size_t)((u) * NT + NP + (pb)) * 4096 +      \
                                   (rb * 4 + (cg ^ ((rb >> 1) & 3))) * 8];      \
    }                                                                           \
    _Pragma("unroll")                                                           \
    for (int i = 0; i < 4; ++i)                                                 \
      _Pragma("unroll")                                                         \
      for (int j = 0; j < 4; ++j) {                                             \
        if constexpr (F16IN)                                                    \
          ACC[i][j] = __builtin_amdgcn_mfma_f32_16x16x32_f16(                   \
              __builtin_bit_cast(f16x8, af[i]), __builtin_bit_cast(f16x8, bfr[j]), \
              ACC[i][j], 0, 0, 0);                                              \
        else                                                                    \
          ACC[i][j] = __builtin_amdgcn_mfma_f32_16x16x32_bf16(af[i], bfr[j],    \
              ACC[i][j], 0, 0, 0);                                              \
      }                                                                         \
  }
#define COMPUTE_PH(buf)                                                         \
  {                                                                             \
    const unsigned short* lb = lds + (size_t)(buf) * TPP * 4096;                \
    bf16x8 af[4];                                                               \
    _Pragma("unroll")                                                           \
    for (int u = 0; u < KU; ++u) {                                              \
      if constexpr (ORD == 1) {                                                 \
        LOADA(u, 0); DOPB(u, 0, acc0); DOPB(u, 1, acc1);                        \
        LOADA(u, 1); DOPB(u, 0, acc1);                                          \
      } else {                                                                  \
        LOADA(u, 0); DOPB(u, 0, acc0);                                          \
      }                                                                         \
    }                                                                           \
  }

  const int nph = K / (32 * KU);
#pragma unroll
  for (int d = 0; d < DEPTH; ++d)
    if (d < nph) STAGE_PH(d, d);

  for (int ph = 0; ph < nph; ++ph) {
    const int rem = nph - 1 - ph;
    const int fut = rem < (DEPTH - 1) ? rem : (DEPTH - 1);
    if constexpr (LPP == 4) {
      if (fut >= 3)      asm volatile("s_waitcnt vmcnt(12)" ::: "memory");
      else if (fut == 2) asm volatile("s_waitcnt vmcnt(8)" ::: "memory");
      else if (fut == 1) asm volatile("s_waitcnt vmcnt(4)" ::: "memory");
      else               asm volatile("s_waitcnt vmcnt(0)" ::: "memory");
    } else if constexpr (LPP == 8) {
      if (fut >= 3)      asm volatile("s_waitcnt vmcnt(24)" ::: "memory");
      else if (fut == 2) asm volatile("s_waitcnt vmcnt(16)" ::: "memory");
      else if (fut == 1) asm volatile("s_waitcnt vmcnt(8)" ::: "memory");
      else               asm volatile("s_waitcnt vmcnt(0)" ::: "memory");
    } else {
      if (fut >= 1)      asm volatile("s_waitcnt vmcnt(16)" ::: "memory");
      else               asm volatile("s_waitcnt vmcnt(0)" ::: "memory");
    }
    __builtin_amdgcn_sched_barrier(0);
    __builtin_amdgcn_s_barrier();        // all waves' stores for buf landed
    COMPUTE_PH(ph & (DEPTH - 1));
    __builtin_amdgcn_s_barrier();        // all readers of buf done
    __builtin_amdgcn_sched_barrier(0);
    if (ph + DEPTH < nph) STAGE_PH(ph + DEPTH, ph & (DEPTH - 1));
  }
#undef STAGE_PH
#undef LOADA
#undef DOPB
#undef COMPUTE_PH

  const float RS = 2.44140625e-4f;       // 1/4096
  float* CfB = Cf + zC;
  unsigned short* O0B = O0 + zC;
  unsigned short* O1B = O1 + zC;

  if constexpr (OUTM == 5) {
#pragma unroll
    for (int fm = 0; fm < 4; ++fm) {
      const int m0 = bm + wr * 64 + fm * 16 + 4 * cg;
      unsigned long long bk[4] = {0ull, 0ull, 0ull, 0ull};
#pragma unroll
      for (int fn = 0; fn < 4; ++fn) {
        const int n = bn + wc * 64 + fn * 16 + cr;
#pragma unroll
        for (int r = 0; r < 4; ++r) {
          const float x = (acc0[fm][fn][r] + acc1[fm][fn][r] * RS) * scale;
          unsigned short a, b;
          split2h(x, a, b);
          const size_t off = (size_t)(m0 + r) * ldc + n;
          O0B[off] = a; O1B[off] = b;
          const unsigned long long k =
              ((unsigned long long)fmono(x) << 32) | (unsigned)(255 - n);
          if (k > bk[r]) bk[r] = k;
        }
      }
#pragma unroll
      for (int r = 0; r < 4; ++r) {
        unsigned long long k = bk[r];
#pragma unroll
        for (int o = 1; o < 16; o <<= 1) {
          const unsigned long long ok =
              (unsigned long long)__shfl_xor((long long)k, o, 16);
          if (ok > k) k = ok;
        }
        if ((lane & 15) == 0)
          atomicMax(keys + (size_t)blockIdx.z * 1024 + (m0 + r), k);
      }
    }
    return;
  }

#pragma unroll
  for (int fm = 0; fm < 4; ++fm) {
#pragma unroll
    for (int fn = 0; fn < 4; ++fn) {
      const int n  = bn + wc * 64 + fn * 16 + cr;
      const int m0 = bm + wr * 64 + fm * 16 + 4 * cg;
      float bv = 0.f;
      if (BIAS) bv = bias[zBias + n];
#pragma unroll
      for (int r = 0; r < 4; ++r) {
        float x = acc0[fm][fn][r];
        if constexpr (ORD == 1) x += acc1[fm][fn][r] * RS;
        x = x * scale + bv;
        if (RELU) x = fmaxf(x, 0.f);
        const size_t off = (size_t)(m0 + r) * ldc + n;
        if (OUTM == 0) CfB[off] = x;
        else {
          unsigned short a, b;
          split2h(x, a, b);
          O0B[off] = a; O1B[off] = b;
        }
      }
    }
  }
}

// ---------------------------------------------------------------------------
// Masked softmax over rows of length 1024 for a 512-row i-half; emits
// P^T[b][j][i_global] bf16. Argmax indices decoded from packed keys.
// ---------------------------------------------------------------------------
__global__ __launch_bounds__(256)
void softmax_T(const float* __restrict__ Lg, const unsigned long long* __restrict__ keysA,
               const unsigned long long* __restrict__ keysB,
               unsigned short* __restrict__ PT, int ihalf)
{
  __shared__ int bj[1024];
  __shared__ unsigned short tile[1024 * 17];
  const int tid = threadIdx.x;
  const int i0  = blockIdx.x * 16;
  const int b   = blockIdx.y;
  const int r   = tid >> 4;
  const int l16 = tid & 15;

  for (int j = tid; j < 1024; j += 256)
    bj[j] = 255 - (int)(keysB[(b << 10) + j] & 0xFFFFFFFFull);
  __syncthreads();

  const int ai = 255 - (int)(keysA[(b << 10) + (ihalf << 9) + i0 + r] & 0xFFFFFFFFull);
  const float* Lr = Lg + ((size_t)b * 512 + i0 + r) * 1024;
  const int jb = l16 * 64;

  float x[64];
  float mx = -3.0e38f;
#pragma unroll
  for (int q = 0; q < 16; ++q) {
    f32x4 f = *(const f32x4*)(Lr + jb + (q << 2));
#pragma unroll
    for (int u = 0; u < 4; ++u) {
      const int j = jb + (q << 2) + u;
      float t = f[u];
      if (bj[j] != ai) t -= 1e6f;
      x[(q << 2) + u] = t;
      mx = fmaxf(mx, t);
    }
  }
#pragma unroll
  for (int off = 8; off >= 1; off >>= 1) mx = fmaxf(mx, __shfl_xor(mx, off));
  float s = 0.f;
#pragma unroll
  for (int k = 0; k < 64; ++k) { float e = expf(x[k] - mx); x[k] = e; s += e; }
#pragma unroll
  for (int off = 8; off >= 1; off >>= 1) s += __shfl_xor(s, off);
  const float inv = 1.f / s;

#pragma unroll
  for (int k = 0; k < 64; ++k)
    tile[(jb + k) * 17 + r] = f2bf(x[k] * inv);
  __syncthreads();

  for (int j = tid; j < 1024; j += 256) {
    const unsigned short* tp = &tile[j * 17];
    unsigned int w[8];
#pragma unroll
    for (int q = 0; q < 8; ++q)
      w[q] = (unsigned int)tp[2 * q] | ((unsigned int)tp[2 * q + 1] << 16);
    const size_t off = ((size_t)b << 20) + ((size_t)j << 10) + (ihalf << 9) + i0;
    unsigned int* dst = (unsigned int*)(PT + off);
    *(uint4*)dst       = make_uint4(w[0], w[1], w[2], w[3]);
    *((uint4*)dst + 1) = make_uint4(w[4], w[5], w[6], w[7]);
  }
}

// ---------------------------------------------------------------------------
extern "C" void kernel_launch(void* const* d_in, const int* in_sizes, int n_in,
                              void* d_out, int out_size, void* d_ws, size_t ws_size,
                              hipStream_t stream)
{
  (void)in_sizes; (void)n_in; (void)out_size; (void)ws_size;

  const float* tok  = (const float*)d_in[0];
  const float* supp = (const float*)d_in[1];
  const float* qry  = (const float*)d_in[2];
  const float* W_qa = (const float*)d_in[3];
  const float* b_qa = (const float*)d_in[4];
  const float* W_ks = (const float*)d_in[5];
  const float* b_ks = (const float*)d_in[6];
  const float* W_ka = (const float*)d_in[7];
  const float* b_ka = (const float*)d_in[8];
  const float* W_vs = (const float*)d_in[9];
  const float* b_vs = (const float*)d_in[10];
  const float* W_f1 = (const float*)d_in[11];
  const float* b_f1 = (const float*)d_in[12];
  const float* W_f2 = (const float*)d_in[13];
  const float* b_f2 = (const float*)d_in[14];

  // ORD1 engines unchanged; ORD0 engines -> register-pipelined gkp (48 KB)
  auto kProj  = &gke<1,1,2,1,true ,false,true >;   // 64 KB, vmcnt(8)
  auto kScore = &gke<1,2,2,5,false,false,true >;   // 128 KB, vmcnt(16)
  auto kLogit = &gke<1,1,2,0,false,false,true >;   // 64 KB
  auto kVsT   = &gkp<4,true ,false,true >;         // 48 KB fp16
  auto kPV    = &gkp<3,false,false,false>;         // 48 KB bf16
  auto kFFN1  = &gkp<3,true ,true ,false>;         // 48 KB bf16
  auto kFFN2  = &gkp<0,true ,false,false>;         // 48 KB bf16
  hipFuncSetAttribute((const void*)kProj,  hipFuncAttributeMaxDynamicSharedMemorySize, 65536);
  hipFuncSetAttribute((const void*)kScore, hipFuncAttributeMaxDynamicSharedMemorySize, 131072);
  hipFuncSetAttribute((const void*)kLogit, hipFuncAttributeMaxDynamicSharedMemorySize, 65536);
  hipFuncSetAttribute((const void*)kVsT,   hipFuncAttributeMaxDynamicSharedMemorySize, 49152);
  hipFuncSetAttribute((const void*)kPV,    hipFuncAttributeMaxDynamicSharedMemorySize, 49152);
  hipFuncSetAttribute((const void*)kFFN1,  hipFuncAttributeMaxDynamicSharedMemorySize, 49152);
  hipFuncSetAttribute((const void*)kFFN2,  hipFuncAttributeMaxDynamicSharedMemorySize, 49152);

  char* W = (char*)d_ws;
  constexpr size_t MiB = 1048576;
  auto U = [&](double off) { return (unsigned short*)(W + (size_t)(off * MiB)); };
  auto F = [&](double off) { return (float*)(W + (size_t)(off * MiB)); };
  auto KY = [&](double off) { return (unsigned long long*)(W + (size_t)(off * MiB)); };

  const double oTOK0=0, oTOK1=4, oSUP0=0, oPT=0;
  const double oWQAT=16, oWKAT=17.5, oWKST=19, oWVST=20.5;
  const double oQA0=22, oQA1=26, oDEC=32, oKA0=34, oKA1=38;
  const double oQRY0=46, oQRY1=62, oQTP0=46, oQTP1=54;
  const double oSUP1=62, oVST=62, oSAP0=78, oSAP1=86;
  const double oQQ0=94, oQQ1=110, oLG=94, oMID=62;
  const double oWF1=142, oWF2=143.5, oBIA=148, oKEYB=148.5, oKEYA=148.75;
  const double hP = 0.5;

  const dim3 B256(256), BW(32, 8);
  float* dummyF = F(oLG);
  unsigned short* dummyU = U(oLG);
  unsigned long long* dummyK = KY(oLG);

  // S0: biases adjacent for merged dual launch; zero argmax key buffers
  hipMemcpyAsync(W + (size_t)(oBIA * MiB), b_qa, 2048, hipMemcpyDeviceToDevice, stream);
  hipMemcpyAsync(W + (size_t)(oBIA * MiB) + 2048, b_ka, 2048, hipMemcpyDeviceToDevice, stream);
  hipMemsetAsync(KY(oKEYB), 0, kBS * kHW * 8, stream);
  hipMemsetAsync(KY(oKEYA), 0, kBS * kHW * 8, stream);

  // S1: weight + tok splits
  split_wT2h<<<dim3(16,16), BW, 0, stream>>>(W_qa, U(oWQAT), U(oWQAT+hP), 512, 512);
  split_wT2h<<<dim3(16,16), BW, 0, stream>>>(W_ka, U(oWKAT), U(oWKAT+hP), 512, 512);
  split_wT2h<<<dim3(16,16), BW, 0, stream>>>(W_ks, U(oWKST), U(oWKST+hP), 512, 512);
  split_wT1<true><<<dim3(16,16), BW, 0, stream>>>(W_vs, U(oWVST), 512, 512);
  split_act2h<<<dim3(2048), B256, 0, stream>>>((const f32x4*)tok, (u16x4*)U(oTOK0), (u16x4*)U(oTOK1), 524288);
  // S2: qa|ka merged projection
  kProj<<<dim3(32,4,2), B256, 65536, stream>>>(
      U(oTOK0),U(oTOK1), U(oWQAT),U(oWQAT+hP),
      F(oBIA), dummyF, U(oQA0),U(oQA1), dummyK, 512, 512, 0, 786432, 6291456, 512, 1.f);
  // S3: qry split
  split_act2h<<<dim3(8192), B256, 0, stream>>>((const f32x4*)qry, (u16x4*)U(oQRY0), (u16x4*)U(oQRY1), 2097152);
  // S4: qq projection
  kProj<<<dim3(128,4,1), B256, 65536, stream>>>(
      U(oQRY0),U(oQRY1), U(oWQAT),U(oWQAT+hP),
      b_qa, dummyF, U(oQQ0),U(oQQ1), dummyK, 512, 512, 0,0,0,0, 1.f);
  // S5: qt score -> 2 fp16 planes + fused argmax (keysB)
  kScore<<<dim3(8,2,16), B256, 131072, stream>>>(
      U(oQQ0),U(oQQ1), U(oKA0),U(oKA1),
      nullptr, dummyF, U(oQTP0),U(oQTP1), KY(oKEYB), 512, 256,
      524288, 131072, 262144, 0, 0.125f);
  // S6: supp split
  split_act2h<<<dim3(8192), B256, 0, stream>>>((const f32x4*)supp, (u16x4*)U(oSUP0), (u16x4*)U(oSUP1), 2097152);
  // S7: ks projection, then vs^T (fp16 1-pass, register-pipelined)
  kProj<<<dim3(128,4,1), B256, 65536, stream>>>(
      U(oSUP0),U(oSUP1), U(oWKST),U(oWKST+hP),
      b_ks, dummyF, U(oQQ0),U(oQQ1), dummyK, 512, 512, 0,0,0,0, 1.f);
  kVsT<<<dim3(8,4,16), B256, 49152, stream>>>(
      U(oSUP0), U(oWVST), b_vs, dummyF, U(oVST), 512, 1024,
      524288, 0, 524288, 1.f);
  // S8: sa score -> 2 fp16 planes + fused argmax (keysA)
  kScore<<<dim3(8,2,16), B256, 131072, stream>>>(
      U(oQQ0),U(oQQ1), U(oQA0),U(oQA1),
      nullptr, dummyF, U(oSAP0),U(oSAP1), KY(oKEYA), 512, 256,
      524288, 131072, 262144, 0, 0.125f);
  // FFN weight splits
  split_wT1<false><<<dim3(16,48), BW, 0, stream>>>(W_f1, U(oWF1), 512, 1536);
  split_wT1<false><<<dim3(48,16), BW, 0, stream>>>(W_f2, U(oWF2), 1536, 512);
  // S9/S10: logits halves + masked softmax -> P^T
  for (int h = 0; h < 2; ++h) {
    kLogit<<<dim3(4,8,16), B256, 65536, stream>>>(
        U(oSAP0) + (size_t)h*512*256, U(oSAP1) + (size_t)h*512*256,
        U(oQTP0), U(oQTP1),
        nullptr, F(oLG), dummyU,dummyU, dummyK, 256, 1024,
        262144, 262144, 524288, 0, 1.f);
    softmax_T<<<dim3(32,16), B256, 0, stream>>>(F(oLG), KY(oKEYA), KY(oKEYB), U(oPT), h);
  }
  // S11: dec = P^T . vs (bf16, K=1024, register-pipelined)
  kPV<<<dim3(8,4,16), B256, 49152, stream>>>(
      U(oPT), U(oVST), nullptr, dummyF, U(oDEC), 1024, 512,
      1048576, 524288, 524288, 1.f);
  // S12: FFN1 = relu(dec @ W_f1 + b1) -> bf16
  kFFN1<<<dim3(128,12,1), B256, 49152, stream>>>(
      U(oDEC), U(oWF1), b_f1, dummyF, U(oMID), 512, 1536, 0,0,0, 1.f);
  // S13: FFN2 = mid @ W_f2 + b2 -> d_out fp32 (K=1536)
  kFFN2<<<dim3(128,4,1), B256, 49152, stream>>>(
      U(oMID), U(oWF2), b_f2, (float*)d_out, dummyU, 1536, 512, 0,0,0, 1.f);
}

// Round 18
// 395.979 us; speedup vs baseline: 1.0336x; 1.0336x over previous
//
#include <hip/hip_runtime.h>

typedef float          f32x4  __attribute__((ext_vector_type(4)));
typedef short          bf16x8 __attribute__((ext_vector_type(8)));
typedef _Float16       f16x8  __attribute__((ext_vector_type(8)));
typedef unsigned short u16x4  __attribute__((ext_vector_type(4)));

static constexpr int kBS = 16;
static constexpr int kHW = 1024;

__device__ __forceinline__ unsigned short f2bf(float x) {
  union { float f; unsigned int u; } v; v.f = x;
  unsigned int r = v.u + 0x7fffu + ((v.u >> 16) & 1u);
  return (unsigned short)(r >> 16);
}
__device__ __forceinline__ float bf2f(unsigned short h) {
  union { unsigned int u; float f; } v; v.u = ((unsigned int)h) << 16;
  return v.f;
}
__device__ __forceinline__ unsigned short h2u(_Float16 h) {
  union { _Float16 h; unsigned short u; } v; v.h = h; return v.u;
}
// order-preserving f32 -> u32 (finite floats)
__device__ __forceinline__ unsigned int fmono(float f) {
  union { float f; unsigned int u; } v; v.f = f;
  return (v.u & 0x80000000u) ? ~v.u : (v.u | 0x80000000u);
}

// 2-plane fp16 split with 4096-scaled residual: x ~= p0 + p1/4096.
__device__ __forceinline__ void split2h(float x, unsigned short& u0, unsigned short& u1) {
  _Float16 h0 = (_Float16)x;
  if (fabsf(x) < 6.1035156e-05f) h0 = (_Float16)0.f;
  const float r = (x - (float)h0) * 4096.f;
  u0 = h2u(h0);
  u1 = h2u((_Float16)r);
}

// ---------------------------------------------------------------------------
__global__ __launch_bounds__(256)
void split_act2h(const f32x4* __restrict__ X, u16x4* __restrict__ P0,
                 u16x4* __restrict__ P1, int n4)
{
  int i = blockIdx.x * 256 + threadIdx.x;
  if (i >= n4) return;
  f32x4 x = X[i];
  u16x4 s0, s1;
#pragma unroll
  for (int u = 0; u < 4; ++u) {
    unsigned short a, b;
    split2h(x[u], a, b);
    s0[u] = a; s1[u] = b;
  }
  P0[i] = s0; P1[i] = s1;
}

__global__ __launch_bounds__(256)
void split_wT2h(const float* __restrict__ Wm, unsigned short* __restrict__ T0,
                unsigned short* __restrict__ T1, int K, int N)
{
  __shared__ float ts[32][33];
  const int k0 = blockIdx.x * 32, n0 = blockIdx.y * 32;
  const int tx = threadIdx.x, ty = threadIdx.y;   // 32 x 8
#pragma unroll
  for (int r = 0; r < 4; ++r)
    ts[ty + r * 8][tx] = Wm[(size_t)(k0 + ty + r * 8) * N + n0 + tx];
  __syncthreads();
#pragma unroll
  for (int r = 0; r < 4; ++r) {
    const int n = ty + r * 8;
    const size_t off = (size_t)(n0 + n) * K + k0 + tx;
    unsigned short a, b;
    split2h(ts[tx][n], a, b);
    T0[off] = a; T1[off] = b;
  }
}

template<bool F16>
__global__ __launch_bounds__(256)
void split_wT1(const float* __restrict__ Wm, unsigned short* __restrict__ T0,
               int K, int N)
{
  __shared__ float ts[32][33];
  const int k0 = blockIdx.x * 32, n0 = blockIdx.y * 32;
  const int tx = threadIdx.x, ty = threadIdx.y;
#pragma unroll
  for (int r = 0; r < 4; ++r)
    ts[ty + r * 8][tx] = Wm[(size_t)(k0 + ty + r * 8) * N + n0 + tx];
  __syncthreads();
#pragma unroll
  for (int r = 0; r < 4; ++r) {
    const int n = ty + r * 8;
    const float x = ts[tx][n];
    const size_t off = (size_t)(n0 + n) * K + k0 + tx;
    T0[off] = F16 ? h2u((_Float16)x) : f2bf(x);
  }
}

// ---------------------------------------------------------------------------
// Staging: one 128x32 16-bit tile -> linear LDS via global_load_lds(16B),
// involution pre-swizzled source cols. 2 loads/wave.
// ---------------------------------------------------------------------------
__device__ __forceinline__ void stage_tile(const unsigned short* src, int K,
                                           unsigned short* ldst, int wv, int lane)
{
#pragma unroll
  for (int i = 0; i < 2; ++i) {
    const int s   = wv * 128 + i * 64 + lane;
    const int row = s >> 2;
    const int gc  = ((s & 3) ^ ((row >> 1) & 3)) * 8;
    __builtin_amdgcn_global_load_lds(
        (const __attribute__((address_space(1))) void*)(src + (size_t)row * K + gc),
        (__attribute__((address_space(3))) void*)(ldst + ((wv * 128 + i * 64) << 3)),
        16, 0, 0);
  }
}

// ---------------------------------------------------------------------------
// Unified 128x128 MFMA GEMM engine (r10 measured-best config). 4 waves, BK=32,
// KU tiles/phase, DEPTH-deep circular dbuf with counted vmcnt.
//  ORD0: 1-pass;  ORD1: fp16 scaled-residual 2-plane, 3 passes.
// OUTM: 0=f32, 1=2 fp16 planes, 3=bf16, 4=bf16 transposed ([N][M], ldc),
//       5=2 fp16 planes + fused row-argmax (packed-key atomicMax;
//         row = z*1024+m, key = mono(x)<<32 | (255-n); np first-max order).
// Batched via blockIdx.z strides sA/sB/sC/sBias (affine merged dispatches).
// ---------------------------------------------------------------------------
template<int ORD, int KU, int DEPTH, int OUTM, bool BIAS, bool RELU, bool F16IN>
__global__ __launch_bounds__(256)
void gke(const unsigned short* __restrict__ A0, const unsigned short* __restrict__ A1,
         const unsigned short* __restrict__ B0, const unsigned short* __restrict__ B1,
         const float* __restrict__ bias,
         float* __restrict__ Cf, unsigned short* __restrict__ O0,
         unsigned short* __restrict__ O1, unsigned long long* __restrict__ keys,
         int K, int ldc, long sA, long sB, long sC, long sBias, float scale)
{
  constexpr int NP   = ORD + 1;
  constexpr int NT   = 2 * NP;
  constexpr int TPP  = KU * NT;
  constexpr int LPP  = TPP * 2;
  static_assert(DEPTH == 2 || DEPTH == 4, "DEPTH in {2,4}");
  static_assert(LPP == 4 || LPP == 8 || LPP == 16, "vmcnt literals");
  extern __shared__ __align__(16) unsigned short lds[];

  const int tid  = threadIdx.x;
  const int wv   = tid >> 6, lane = tid & 63;
  const int wr   = wv >> 1,  wc   = wv & 1;
  const int cr   = lane & 15, cg  = lane >> 4;
  const int bm   = blockIdx.x * 128, bn = blockIdx.y * 128;

  const size_t zA = (size_t)blockIdx.z * (size_t)sA;
  const size_t zB = (size_t)blockIdx.z * (size_t)sB;
  const size_t zC = (size_t)blockIdx.z * (size_t)sC;
  const size_t zBias = (size_t)blockIdx.z * (size_t)sBias;

  const unsigned short* srcs[NT];
  srcs[0] = A0 + zA + (size_t)bm * K;
  if (NP == 2) srcs[1] = A1 + zA + (size_t)bm * K;
  srcs[NP + 0] = B0 + zB + (size_t)bn * K;
  if (NP == 2) srcs[NP + 1] = B1 + zB + (size_t)bn * K;

  f32x4 acc0[4][4], acc1[4][4];
#pragma unroll
  for (int i = 0; i < 4; ++i)
#pragma unroll
    for (int j = 0; j < 4; ++j)
#pragma unroll
      for (int r = 0; r < 4; ++r) {
        acc0[i][j][r] = 0.f;
        if (ORD == 1) acc1[i][j][r] = 0.f;
      }

#define STAGE_PH(ph, buf)                                                       \
  {                                                                             \
    _Pragma("unroll")                                                           \
    for (int u = 0; u < KU; ++u)                                                \
      _Pragma("unroll")                                                         \
      for (int t = 0; t < NT; ++t)                                              \
        stage_tile(srcs[t] + ((ph) * KU + u) * 32, K,                           \
                   lds + (size_t)((buf) * TPP + u * NT + t) * 4096, wv, lane);  \
  }
#define LOADA(u, pa)                                                            \
  {                                                                             \
    _Pragma("unroll")                                                           \
    for (int f = 0; f < 4; ++f) {                                               \
      const int ra = wr * 64 + f * 16 + cr;                                     \
      af[f] = *(const bf16x8*)&lb[(size_t)((u) * NT + (pa)) * 4096 +            \
                                  (ra * 4 + (cg ^ ((ra >> 1) & 3))) * 8];       \
    }                                                                           \
  }
#define DOPB(u, pb, ACC)                                                        \
  {                                                                             \
    bf16x8 bfr[4];                                                              \
    _Pragma("unroll")                                                           \
    for (int f = 0; f < 4; ++f) {                                               \
      const int rb = wc * 64 + f * 16 + cr;                                     \
      bfr[f] = *(const bf16x8*)&lb[(size_t)((u) * NT + NP + (pb)) * 4096 +      \
                                   (rb * 4 + (cg ^ ((rb >> 1) & 3))) * 8];      \
    }                                                                           \
    _Pragma("unroll")                                                           \
    for (int i = 0; i < 4; ++i)                                                 \
      _Pragma("unroll")                                                         \
      for (int j = 0; j < 4; ++j) {                                             \
        if constexpr (F16IN)                                                    \
          ACC[i][j] = __builtin_amdgcn_mfma_f32_16x16x32_f16(                   \
              __builtin_bit_cast(f16x8, af[i]), __builtin_bit_cast(f16x8, bfr[j]), \
              ACC[i][j], 0, 0, 0);                                              \
        else                                                                    \
          ACC[i][j] = __builtin_amdgcn_mfma_f32_16x16x32_bf16(af[i], bfr[j],    \
              ACC[i][j], 0, 0, 0);                                              \
      }                                                                         \
  }
#define COMPUTE_PH(buf)                                                         \
  {                                                                             \
    const unsigned short* lb = lds + (size_t)(buf) * TPP * 4096;                \
    bf16x8 af[4];                                                               \
    _Pragma("unroll")                                                           \
    for (int u = 0; u < KU; ++u) {                                              \
      if constexpr (ORD == 1) {                                                 \
        LOADA(u, 0); DOPB(u, 0, acc0); DOPB(u, 1, acc1);                        \
        LOADA(u, 1); DOPB(u, 0, acc1);                                          \
      } else {                                                                  \
        LOADA(u, 0); DOPB(u, 0, acc0);                                          \
      }                                                                         \
    }                                                                           \
  }

  const int nph = K / (32 * KU);
#pragma unroll
  for (int d = 0; d < DEPTH; ++d)
    if (d < nph) STAGE_PH(d, d);

  for (int ph = 0; ph < nph; ++ph) {
    const int rem = nph - 1 - ph;
    const int fut = rem < (DEPTH - 1) ? rem : (DEPTH - 1);
    if constexpr (LPP == 4) {
      if (fut >= 3)      asm volatile("s_waitcnt vmcnt(12)" ::: "memory");
      else if (fut == 2) asm volatile("s_waitcnt vmcnt(8)" ::: "memory");
      else if (fut == 1) asm volatile("s_waitcnt vmcnt(4)" ::: "memory");
      else               asm volatile("s_waitcnt vmcnt(0)" ::: "memory");
    } else if constexpr (LPP == 8) {
      if (fut >= 3)      asm volatile("s_waitcnt vmcnt(24)" ::: "memory");
      else if (fut == 2) asm volatile("s_waitcnt vmcnt(16)" ::: "memory");
      else if (fut == 1) asm volatile("s_waitcnt vmcnt(8)" ::: "memory");
      else               asm volatile("s_waitcnt vmcnt(0)" ::: "memory");
    } else {
      if (fut >= 1)      asm volatile("s_waitcnt vmcnt(16)" ::: "memory");
      else               asm volatile("s_waitcnt vmcnt(0)" ::: "memory");
    }
    __builtin_amdgcn_sched_barrier(0);
    __builtin_amdgcn_s_barrier();        // all waves' stores for buf landed
    COMPUTE_PH(ph & (DEPTH - 1));
    __builtin_amdgcn_s_barrier();        // all readers of buf done
    __builtin_amdgcn_sched_barrier(0);
    if (ph + DEPTH < nph) STAGE_PH(ph + DEPTH, ph & (DEPTH - 1));
  }
#undef STAGE_PH
#undef LOADA
#undef DOPB
#undef COMPUTE_PH

  // epilogue: C/D layout col = lane&15, row = 4*(lane>>4)+reg  [m89-verified]
  const float RS = 2.44140625e-4f;       // 1/4096
  float* CfB = Cf + zC;
  unsigned short* O0B = O0 + zC;
  unsigned short* O1B = O1 + zC;

  if constexpr (OUTM == 5) {
#pragma unroll
    for (int fm = 0; fm < 4; ++fm) {
      const int m0 = bm + wr * 64 + fm * 16 + 4 * cg;
      unsigned long long bk[4] = {0ull, 0ull, 0ull, 0ull};
#pragma unroll
      for (int fn = 0; fn < 4; ++fn) {
        const int n = bn + wc * 64 + fn * 16 + cr;
#pragma unroll
        for (int r = 0; r < 4; ++r) {
          const float x = (acc0[fm][fn][r] + acc1[fm][fn][r] * RS) * scale;
          unsigned short a, b;
          split2h(x, a, b);
          const size_t off = (size_t)(m0 + r) * ldc + n;
          O0B[off] = a; O1B[off] = b;
          const unsigned long long k =
              ((unsigned long long)fmono(x) << 32) | (unsigned)(255 - n);
          if (k > bk[r]) bk[r] = k;
        }
      }
#pragma unroll
      for (int r = 0; r < 4; ++r) {
        unsigned long long k = bk[r];
#pragma unroll
        for (int o = 1; o < 16; o <<= 1) {
          const unsigned long long ok =
              (unsigned long long)__shfl_xor((long long)k, o, 16);
          if (ok > k) k = ok;
        }
        if ((lane & 15) == 0)
          atomicMax(keys + (size_t)blockIdx.z * 1024 + (m0 + r), k);
      }
    }
    return;
  }

#pragma unroll
  for (int fm = 0; fm < 4; ++fm) {
#pragma unroll
    for (int fn = 0; fn < 4; ++fn) {
      const int n  = bn + wc * 64 + fn * 16 + cr;
      const int m0 = bm + wr * 64 + fm * 16 + 4 * cg;
      float bv = 0.f;
      if (BIAS) bv = bias[zBias + n];
      if (OUTM == 4) {
        u16x4 o;
#pragma unroll
        for (int r = 0; r < 4; ++r) {
          float x = acc0[fm][fn][r];
          if constexpr (ORD == 1) x += acc1[fm][fn][r] * RS;
          x = x * scale + bv;
          if (RELU) x = fmaxf(x, 0.f);
          o[r] = f2bf(x);
        }
        *(u16x4*)(O0B + (size_t)n * ldc + m0) = o;
      } else {
#pragma unroll
        for (int r = 0; r < 4; ++r) {
          float x = acc0[fm][fn][r];
          if constexpr (ORD == 1) x += acc1[fm][fn][r] * RS;
          x = x * scale + bv;
          if (RELU) x = fmaxf(x, 0.f);
          const size_t off = (size_t)(m0 + r) * ldc + n;
          if (OUTM == 0) CfB[off] = x;
          else if (OUTM == 3) O0B[off] = f2bf(x);
          else {
            unsigned short a, b;
            split2h(x, a, b);
            O0B[off] = a; O1B[off] = b;
          }
        }
      }
    }
  }
}

// ---------------------------------------------------------------------------
// Masked softmax over full rows of length 1024; emits P^T[b][j][i] bf16.
// Lg layout [b][1024][1024]. Argmax indices decoded from packed keys:
// idx = 255 - (key & 0xFFFFFFFF).
// ---------------------------------------------------------------------------
__global__ __launch_bounds__(256)
void softmax_T(const float* __restrict__ Lg, const unsigned long long* __restrict__ keysA,
               const unsigned long long* __restrict__ keysB,
               unsigned short* __restrict__ PT)
{
  __shared__ int bj[1024];
  __shared__ unsigned short tile[1024 * 17];
  const int tid = threadIdx.x;
  const int i0  = blockIdx.x * 16;          // 0..1008
  const int b   = blockIdx.y;
  const int r   = tid >> 4;
  const int l16 = tid & 15;

  for (int j = tid; j < 1024; j += 256)
    bj[j] = 255 - (int)(keysB[(b << 10) + j] & 0xFFFFFFFFull);
  __syncthreads();

  const int ai = 255 - (int)(keysA[(b << 10) + i0 + r] & 0xFFFFFFFFull);
  const float* Lr = Lg + ((size_t)(b << 10) + i0 + r) * 1024;
  const int jb = l16 * 64;

  float x[64];
  float mx = -3.0e38f;
#pragma unroll
  for (int q = 0; q < 16; ++q) {
    f32x4 f = *(const f32x4*)(Lr + jb + (q << 2));
#pragma unroll
    for (int u = 0; u < 4; ++u) {
      const int j = jb + (q << 2) + u;
      float t = f[u];
      if (bj[j] != ai) t -= 1e6f;
      x[(q << 2) + u] = t;
      mx = fmaxf(mx, t);
    }
  }
#pragma unroll
  for (int off = 8; off >= 1; off >>= 1) mx = fmaxf(mx, __shfl_xor(mx, off));
  float s = 0.f;
#pragma unroll
  for (int k = 0; k < 64; ++k) { float e = expf(x[k] - mx); x[k] = e; s += e; }
#pragma unroll
  for (int off = 8; off >= 1; off >>= 1) s += __shfl_xor(s, off);
  const float inv = 1.f / s;

#pragma unroll
  for (int k = 0; k < 64; ++k)
    tile[(jb + k) * 17 + r] = f2bf(x[k] * inv);
  __syncthreads();

  for (int j = tid; j < 1024; j += 256) {
    const unsigned short* tp = &tile[j * 17];
    unsigned int w[8];
#pragma unroll
    for (int q = 0; q < 8; ++q)
      w[q] = (unsigned int)tp[2 * q] | ((unsigned int)tp[2 * q + 1] << 16);
    const size_t off = ((size_t)b << 20) + ((size_t)j << 10) + i0;
    unsigned int* dst = (unsigned int*)(PT + off);
    *(uint4*)dst       = make_uint4(w[0], w[1], w[2], w[3]);
    *((uint4*)dst + 1) = make_uint4(w[4], w[5], w[6], w[7]);
  }
}

// ---------------------------------------------------------------------------
extern "C" void kernel_launch(void* const* d_in, const int* in_sizes, int n_in,
                              void* d_out, int out_size, void* d_ws, size_t ws_size,
                              hipStream_t stream)
{
  (void)in_sizes; (void)n_in; (void)out_size; (void)ws_size;

  const float* tok  = (const float*)d_in[0];
  const float* supp = (const float*)d_in[1];
  const float* qry  = (const float*)d_in[2];
  const float* W_qa = (const float*)d_in[3];
  const float* b_qa = (const float*)d_in[4];
  const float* W_ks = (const float*)d_in[5];
  const float* b_ks = (const float*)d_in[6];
  const float* W_ka = (const float*)d_in[7];
  const float* b_ka = (const float*)d_in[8];
  const float* W_vs = (const float*)d_in[9];
  const float* b_vs = (const float*)d_in[10];
  const float* W_f1 = (const float*)d_in[11];
  const float* b_f1 = (const float*)d_in[12];
  const float* W_f2 = (const float*)d_in[13];
  const float* b_f2 = (const float*)d_in[14];

  auto kProj  = &gke<1,1,2,1,true ,false,true >;   // 64 KB, vmcnt(8)
  auto kScore = &gke<1,2,2,5,false,false,true >;   // 128 KB, vmcnt(16)
  auto kLogit = &gke<1,1,2,0,false,false,true >;   // 64 KB
  auto kVsT   = &gke<0,1,2,4,true ,false,true >;   // 32 KB fp16 1-pass
  auto kPV    = &gke<0,1,2,3,false,false,false>;   // 32 KB bf16
  auto kFFN1  = &gke<0,1,2,3,true ,true ,false>;   // 32 KB bf16
  auto kFFN2  = &gke<0,1,2,0,true ,false,false>;   // 32 KB bf16
  hipFuncSetAttribute((const void*)kProj,  hipFuncAttributeMaxDynamicSharedMemorySize, 65536);
  hipFuncSetAttribute((const void*)kScore, hipFuncAttributeMaxDynamicSharedMemorySize, 131072);
  hipFuncSetAttribute((const void*)kLogit, hipFuncAttributeMaxDynamicSharedMemorySize, 65536);
  hipFuncSetAttribute((const void*)kVsT,   hipFuncAttributeMaxDynamicSharedMemorySize, 32768);
  hipFuncSetAttribute((const void*)kPV,    hipFuncAttributeMaxDynamicSharedMemorySize, 32768);
  hipFuncSetAttribute((const void*)kFFN1,  hipFuncAttributeMaxDynamicSharedMemorySize, 32768);
  hipFuncSetAttribute((const void*)kFFN2,  hipFuncAttributeMaxDynamicSharedMemorySize, 32768);

  char* W = (char*)d_ws;
  constexpr size_t MiB = 1048576;
  auto U = [&](double off) { return (unsigned short*)(W + (size_t)(off * MiB)); };
  auto F = [&](double off) { return (float*)(W + (size_t)(off * MiB)); };
  auto KY = [&](double off) { return (unsigned long long*)(W + (size_t)(off * MiB)); };

  // layout (MiB), re-walked after r17 race:
  // tokP 0-8 -> suppP0 0-16 -> score[qt|sa] P0 0-16 -> PT 0-32
  // W: KA_p0@16 QA_p0@16.5 KA_p1@17 QA_p1@17.5 KS_p0@18 KS_p1@18.5 VS@19
  //   (dead after S8; PT may overwrite)
  // kaqa P0 22-30, P1 30-38 (dead after S8) | dec 32-48 (written S11)
  // qryP0 46-62 -> suppP1 46-62 -> score[qt|sa] P1 46-62 (dead after S9)
  // qryP1 62-78 -> vsT 62-78 (dead after S11)
  // qq/ks planes 78-142 -> Lg 78-142 (dead after S10) -> mid 94-142 (S12)
  //   [mid 94-142 disjoint from dec 32-48: r17 race fixed]
  // WF1 142-143.5, WF2 143.5-145 | bias 148, keys 148.5-148.75
  const dim3 B256(256), BW(32, 8);
  float* dummyF = F(78);
  unsigned short* dummyU = U(78);
  unsigned long long* dummyK = KY(78);

  // S0: biases adjacent (ka first: merged-proj z=0 -> ka); zero merged keys
  hipMemcpyAsync(W + (size_t)(148.0 * MiB), b_ka, 2048, hipMemcpyDeviceToDevice, stream);
  hipMemcpyAsync(W + (size_t)(148.0 * MiB) + 2048, b_qa, 2048, hipMemcpyDeviceToDevice, stream);
  hipMemsetAsync(KY(148.5), 0, 32 * 1024 * 8, stream);

  // S1: weight + tok splits (W_ka/W_qa planes interleaved for affine z-stride)
  split_wT2h<<<dim3(16,16), BW, 0, stream>>>(W_ka, U(16),   U(17),   512, 512);
  split_wT2h<<<dim3(16,16), BW, 0, stream>>>(W_qa, U(16.5), U(17.5), 512, 512);
  split_wT2h<<<dim3(16,16), BW, 0, stream>>>(W_ks, U(18),   U(18.5), 512, 512);
  split_wT1<true><<<dim3(16,16), BW, 0, stream>>>(W_vs, U(19), 512, 512);
  split_act2h<<<dim3(2048), B256, 0, stream>>>((const f32x4*)tok, (u16x4*)U(0), (u16x4*)U(4), 524288);
  // S2: ka|qa merged projection (z=0 -> {W_ka,b_ka}, z=1 -> {W_qa,b_qa})
  kProj<<<dim3(32,4,2), B256, 65536, stream>>>(
      U(0),U(4), U(16),U(17),
      F(148), dummyF, U(22),U(30), dummyK, 512, 512, 0, 262144, 2097152, 512, 1.f);
  // S3: qry split
  split_act2h<<<dim3(8192), B256, 0, stream>>>((const f32x4*)qry, (u16x4*)U(46), (u16x4*)U(62), 2097152);
  // S4: qq projection -> qqP0@78, qqP1@110
  kProj<<<dim3(128,4,1), B256, 65536, stream>>>(
      U(46),U(62), U(16.5),U(17.5),
      b_qa, dummyF, U(78),U(110), dummyK, 512, 512, 0,0,0,0, 1.f);
  // S5: supp split (over dead tok / dead qryP0)
  split_act2h<<<dim3(8192), B256, 0, stream>>>((const f32x4*)supp, (u16x4*)U(0), (u16x4*)U(46), 2097152);
  // S6: ks projection -> ksP0@94, ksP1@126
  kProj<<<dim3(128,4,1), B256, 65536, stream>>>(
      U(0),U(46), U(18),U(18.5),
      b_ks, dummyF, U(94),U(126), dummyK, 512, 512, 0,0,0,0, 1.f);
  // S7: vs^T (reads suppP0) -> vsT@62 (over dead qryP1)
  kVsT<<<dim3(8,4,16), B256, 32768, stream>>>(
      U(0),dummyU, U(19),dummyU,
      b_vs, dummyF, U(62),dummyU, dummyK, 512, 1024,
      524288, 0, 524288, 0, 1.f);
  // S8: MERGED scores (z=0..15: qt = qq.ka^T/8; z=16..31: sa = ks.qa^T/8)
  kScore<<<dim3(8,2,32), B256, 131072, stream>>>(
      U(78),U(110), U(22),U(30),
      nullptr, dummyF, U(0),U(46), KY(148.5), 512, 256,
      524288, 131072, 262144, 0, 0.125f);
  // FFN weight splits (region 142-145 free throughout)
  split_wT1<false><<<dim3(16,48), BW, 0, stream>>>(W_f1, U(142), 512, 1536);
  split_wT1<false><<<dim3(48,16), BW, 0, stream>>>(W_f2, U(143.5), 1536, 512);
  // S9: MERGED logits = sa . qt^T -> Lg[b][1024][1024] fp32 @78 (64 MiB)
  kLogit<<<dim3(8,8,16), B256, 65536, stream>>>(
      U(8),U(54), U(0),U(46),
      nullptr, F(78), dummyU,dummyU, dummyK, 256, 1024,
      262144, 262144, 1048576, 0, 1.f);
  // S10: masked softmax (full rows) -> P^T bf16 @0 (32 MiB)
  softmax_T<<<dim3(64,16), B256, 0, stream>>>(F(78), KY(148.5) + 16384, KY(148.5), U(0));
  // S11: dec = P^T . vs -> bf16 @32
  kPV<<<dim3(8,4,16), B256, 32768, stream>>>(
      U(0),dummyU, U(62),dummyU,
      nullptr, dummyF, U(32),dummyU, dummyK, 1024, 512,
      1048576, 524288, 524288, 0, 1.f);
  // S12: FFN1 = relu(dec @ W_f1 + b1) -> bf16 @94 (over dead Lg; disjoint
  //      from dec@32-48 -- r17's race fixed)
  kFFN1<<<dim3(128,12,1), B256, 32768, stream>>>(
      U(32),dummyU, U(142),dummyU,
      b_f1, dummyF, U(94),dummyU, dummyK, 512, 1536, 0,0,0,0, 1.f);
  // S13: FFN2 = mid @ W_f2 + b2 -> d_out fp32
  kFFN2<<<dim3(128,4,1), B256, 32768, stream>>>(
      U(94),dummyU, U(143.5),dummyU,
      b_f2, (float*)d_out, dummyU,dummyU, dummyK, 1536, 512, 0,0,0,0, 1.f);
}

// Round 19
// 387.811 us; speedup vs baseline: 1.0554x; 1.0211x over previous
//
#include <hip/hip_runtime.h>

typedef float          f32x4  __attribute__((ext_vector_type(4)));
typedef short          bf16x8 __attribute__((ext_vector_type(8)));
typedef _Float16       f16x8  __attribute__((ext_vector_type(8)));
typedef unsigned short u16x4  __attribute__((ext_vector_type(4)));

static constexpr int kBS = 16;
static constexpr int kHW = 1024;

__device__ __forceinline__ unsigned short f2bf(float x) {
  union { float f; unsigned int u; } v; v.f = x;
  unsigned int r = v.u + 0x7fffu + ((v.u >> 16) & 1u);
  return (unsigned short)(r >> 16);
}
__device__ __forceinline__ float bf2f(unsigned short h) {
  union { unsigned int u; float f; } v; v.u = ((unsigned int)h) << 16;
  return v.f;
}
__device__ __forceinline__ unsigned short h2u(_Float16 h) {
  union { _Float16 h; unsigned short u; } v; v.h = h; return v.u;
}
// order-preserving f32 -> u32 (finite floats)
__device__ __forceinline__ unsigned int fmono(float f) {
  union { float f; unsigned int u; } v; v.f = f;
  return (v.u & 0x80000000u) ? ~v.u : (v.u | 0x80000000u);
}

// 2-plane fp16 split with 4096-scaled residual: x ~= p0 + p1/4096.
__device__ __forceinline__ void split2h(float x, unsigned short& u0, unsigned short& u1) {
  _Float16 h0 = (_Float16)x;
  if (fabsf(x) < 6.1035156e-05f) h0 = (_Float16)0.f;
  const float r = (x - (float)h0) * 4096.f;
  u0 = h2u(h0);
  u1 = h2u((_Float16)r);
}

// ---------------------------------------------------------------------------
__global__ __launch_bounds__(256)
void split_act2h(const f32x4* __restrict__ X, u16x4* __restrict__ P0,
                 u16x4* __restrict__ P1, int n4)
{
  int i = blockIdx.x * 256 + threadIdx.x;
  if (i >= n4) return;
  f32x4 x = X[i];
  u16x4 s0, s1;
#pragma unroll
  for (int u = 0; u < 4; ++u) {
    unsigned short a, b;
    split2h(x[u], a, b);
    s0[u] = a; s1[u] = b;
  }
  P0[i] = s0; P1[i] = s1;
}

__global__ __launch_bounds__(256)
void split_wT2h(const float* __restrict__ Wm, unsigned short* __restrict__ T0,
                unsigned short* __restrict__ T1, int K, int N)
{
  __shared__ float ts[32][33];
  const int k0 = blockIdx.x * 32, n0 = blockIdx.y * 32;
  const int tx = threadIdx.x, ty = threadIdx.y;   // 32 x 8
#pragma unroll
  for (int r = 0; r < 4; ++r)
    ts[ty + r * 8][tx] = Wm[(size_t)(k0 + ty + r * 8) * N + n0 + tx];
  __syncthreads();
#pragma unroll
  for (int r = 0; r < 4; ++r) {
    const int n = ty + r * 8;
    const size_t off = (size_t)(n0 + n) * K + k0 + tx;
    unsigned short a, b;
    split2h(ts[tx][n], a, b);
    T0[off] = a; T1[off] = b;
  }
}

template<bool F16>
__global__ __launch_bounds__(256)
void split_wT1(const float* __restrict__ Wm, unsigned short* __restrict__ T0,
               int K, int N)
{
  __shared__ float ts[32][33];
  const int k0 = blockIdx.x * 32, n0 = blockIdx.y * 32;
  const int tx = threadIdx.x, ty = threadIdx.y;
#pragma unroll
  for (int r = 0; r < 4; ++r)
    ts[ty + r * 8][tx] = Wm[(size_t)(k0 + ty + r * 8) * N + n0 + tx];
  __syncthreads();
#pragma unroll
  for (int r = 0; r < 4; ++r) {
    const int n = ty + r * 8;
    const float x = ts[tx][n];
    const size_t off = (size_t)(n0 + n) * K + k0 + tx;
    T0[off] = F16 ? h2u((_Float16)x) : f2bf(x);
  }
}

// ---------------------------------------------------------------------------
// Staging: one 128x32 16-bit tile -> linear LDS via global_load_lds(16B),
// involution pre-swizzled source cols. 2 loads/wave.
// ---------------------------------------------------------------------------
__device__ __forceinline__ void stage_tile(const unsigned short* src, int K,
                                           unsigned short* ldst, int wv, int lane)
{
#pragma unroll
  for (int i = 0; i < 2; ++i) {
    const int s   = wv * 128 + i * 64 + lane;
    const int row = s >> 2;
    const int gc  = ((s & 3) ^ ((row >> 1) & 3)) * 8;
    __builtin_amdgcn_global_load_lds(
        (const __attribute__((address_space(1))) void*)(src + (size_t)row * K + gc),
        (__attribute__((address_space(3))) void*)(ldst + ((wv * 128 + i * 64) << 3)),
        16, 0, 0);
  }
}

// ---------------------------------------------------------------------------
// Unified 128x128 MFMA GEMM engine (r10 measured-best config). 4 waves, BK=32,
// KU tiles/phase, DEPTH-deep circular dbuf with counted vmcnt.
//  ORD0: 1-pass;  ORD1: fp16 scaled-residual 2-plane, 3 passes.
// OUTM: 0=f32, 1=2 fp16 planes, 3=bf16, 4=bf16 transposed ([N][M], ldc),
//       5=2 fp16 planes + fused row-argmax (packed-key atomicMax;
//         row = z*1024+m, key = mono(x)<<32 | (255-n); np first-max order).
// Batched via blockIdx.z strides sA/sB/sC/sBias (affine merged dispatches).
// ---------------------------------------------------------------------------
template<int ORD, int KU, int DEPTH, int OUTM, bool BIAS, bool RELU, bool F16IN>
__global__ __launch_bounds__(256)
void gke(const unsigned short* __restrict__ A0, const unsigned short* __restrict__ A1,
         const unsigned short* __restrict__ B0, const unsigned short* __restrict__ B1,
         const float* __restrict__ bias,
         float* __restrict__ Cf, unsigned short* __restrict__ O0,
         unsigned short* __restrict__ O1, unsigned long long* __restrict__ keys,
         int K, int ldc, long sA, long sB, long sC, long sBias, float scale)
{
  constexpr int NP   = ORD + 1;
  constexpr int NT   = 2 * NP;
  constexpr int TPP  = KU * NT;
  constexpr int LPP  = TPP * 2;
  static_assert(DEPTH == 2 || DEPTH == 4, "DEPTH in {2,4}");
  static_assert(LPP == 4 || LPP == 8 || LPP == 16, "vmcnt literals");
  extern __shared__ __align__(16) unsigned short lds[];

  const int tid  = threadIdx.x;
  const int wv   = tid >> 6, lane = tid & 63;
  const int wr   = wv >> 1,  wc   = wv & 1;
  const int cr   = lane & 15, cg  = lane >> 4;
  const int bm   = blockIdx.x * 128, bn = blockIdx.y * 128;

  const size_t zA = (size_t)blockIdx.z * (size_t)sA;
  const size_t zB = (size_t)blockIdx.z * (size_t)sB;
  const size_t zC = (size_t)blockIdx.z * (size_t)sC;
  const size_t zBias = (size_t)blockIdx.z * (size_t)sBias;

  const unsigned short* srcs[NT];
  srcs[0] = A0 + zA + (size_t)bm * K;
  if (NP == 2) srcs[1] = A1 + zA + (size_t)bm * K;
  srcs[NP + 0] = B0 + zB + (size_t)bn * K;
  if (NP == 2) srcs[NP + 1] = B1 + zB + (size_t)bn * K;

  f32x4 acc0[4][4], acc1[4][4];
#pragma unroll
  for (int i = 0; i < 4; ++i)
#pragma unroll
    for (int j = 0; j < 4; ++j)
#pragma unroll
      for (int r = 0; r < 4; ++r) {
        acc0[i][j][r] = 0.f;
        if (ORD == 1) acc1[i][j][r] = 0.f;
      }

#define STAGE_PH(ph, buf)                                                       \
  {                                                                             \
    _Pragma("unroll")                                                           \
    for (int u = 0; u < KU; ++u)                                                \
      _Pragma("unroll")                                                         \
      for (int t = 0; t < NT; ++t)                                              \
        stage_tile(srcs[t] + ((ph) * KU + u) * 32, K,                           \
                   lds + (size_t)((buf) * TPP + u * NT + t) * 4096, wv, lane);  \
  }
#define LOADA(u, pa)                                                            \
  {                                                                             \
    _Pragma("unroll")                                                           \
    for (int f = 0; f < 4; ++f) {                                               \
      const int ra = wr * 64 + f * 16 + cr;                                     \
      af[f] = *(const bf16x8*)&lb[(size_t)((u) * NT + (pa)) * 4096 +            \
                                  (ra * 4 + (cg ^ ((ra >> 1) & 3))) * 8];       \
    }                                                                           \
  }
#define DOPB(u, pb, ACC)                                                        \
  {                                                                             \
    bf16x8 bfr[4];                                                              \
    _Pragma("unroll")                                                           \
    for (int f = 0; f < 4; ++f) {                                               \
      const int rb = wc * 64 + f * 16 + cr;                                     \
      bfr[f] = *(const bf16x8*)&lb[(size_t)((u) * NT + NP + (pb)) * 4096 +      \
                                   (rb * 4 + (cg ^ ((rb >> 1) & 3))) * 8];      \
    }                                                                           \
    _Pragma("unroll")                                                           \
    for (int i = 0; i < 4; ++i)                                                 \
      _Pragma("unroll")                                                         \
      for (int j = 0; j < 4; ++j) {                                             \
        if constexpr (F16IN)                                                    \
          ACC[i][j] = __builtin_amdgcn_mfma_f32_16x16x32_f16(                   \
              __builtin_bit_cast(f16x8, af[i]), __builtin_bit_cast(f16x8, bfr[j]), \
              ACC[i][j], 0, 0, 0);                                              \
        else                                                                    \
          ACC[i][j] = __builtin_amdgcn_mfma_f32_16x16x32_bf16(af[i], bfr[j],    \
              ACC[i][j], 0, 0, 0);                                              \
      }                                                                         \
  }
#define COMPUTE_PH(buf)                                                         \
  {                                                                             \
    const unsigned short* lb = lds + (size_t)(buf) * TPP * 4096;                \
    bf16x8 af[4];                                                               \
    _Pragma("unroll")                                                           \
    for (int u = 0; u < KU; ++u) {                                              \
      if constexpr (ORD == 1) {                                                 \
        LOADA(u, 0); DOPB(u, 0, acc0); DOPB(u, 1, acc1);                        \
        LOADA(u, 1); DOPB(u, 0, acc1);                                          \
      } else {                                                                  \
        LOADA(u, 0); DOPB(u, 0, acc0);                                          \
      }                                                                         \
    }                                                                           \
  }

  const int nph = K / (32 * KU);
#pragma unroll
  for (int d = 0; d < DEPTH; ++d)
    if (d < nph) STAGE_PH(d, d);

  for (int ph = 0; ph < nph; ++ph) {
    const int rem = nph - 1 - ph;
    const int fut = rem < (DEPTH - 1) ? rem : (DEPTH - 1);
    if constexpr (LPP == 4) {
      if (fut >= 3)      asm volatile("s_waitcnt vmcnt(12)" ::: "memory");
      else if (fut == 2) asm volatile("s_waitcnt vmcnt(8)" ::: "memory");
      else if (fut == 1) asm volatile("s_waitcnt vmcnt(4)" ::: "memory");
      else               asm volatile("s_waitcnt vmcnt(0)" ::: "memory");
    } else if constexpr (LPP == 8) {
      if (fut >= 3)      asm volatile("s_waitcnt vmcnt(24)" ::: "memory");
      else if (fut == 2) asm volatile("s_waitcnt vmcnt(16)" ::: "memory");
      else if (fut == 1) asm volatile("s_waitcnt vmcnt(8)" ::: "memory");
      else               asm volatile("s_waitcnt vmcnt(0)" ::: "memory");
    } else {
      if (fut >= 1)      asm volatile("s_waitcnt vmcnt(16)" ::: "memory");
      else               asm volatile("s_waitcnt vmcnt(0)" ::: "memory");
    }
    __builtin_amdgcn_sched_barrier(0);
    __builtin_amdgcn_s_barrier();        // all waves' stores for buf landed
    COMPUTE_PH(ph & (DEPTH - 1));
    __builtin_amdgcn_s_barrier();        // all readers of buf done
    __builtin_amdgcn_sched_barrier(0);
    if (ph + DEPTH < nph) STAGE_PH(ph + DEPTH, ph & (DEPTH - 1));
  }
#undef STAGE_PH
#undef LOADA
#undef DOPB
#undef COMPUTE_PH

  // epilogue: C/D layout col = lane&15, row = 4*(lane>>4)+reg  [m89-verified]
  const float RS = 2.44140625e-4f;       // 1/4096
  float* CfB = Cf + zC;
  unsigned short* O0B = O0 + zC;
  unsigned short* O1B = O1 + zC;

  if constexpr (OUTM == 5) {
#pragma unroll
    for (int fm = 0; fm < 4; ++fm) {
      const int m0 = bm + wr * 64 + fm * 16 + 4 * cg;
      unsigned long long bk[4] = {0ull, 0ull, 0ull, 0ull};
#pragma unroll
      for (int fn = 0; fn < 4; ++fn) {
        const int n = bn + wc * 64 + fn * 16 + cr;
#pragma unroll
        for (int r = 0; r < 4; ++r) {
          const float x = (acc0[fm][fn][r] + acc1[fm][fn][r] * RS) * scale;
          unsigned short a, b;
          split2h(x, a, b);
          const size_t off = (size_t)(m0 + r) * ldc + n;
          O0B[off] = a; O1B[off] = b;
          const unsigned long long k =
              ((unsigned long long)fmono(x) << 32) | (unsigned)(255 - n);
          if (k > bk[r]) bk[r] = k;
        }
      }
#pragma unroll
      for (int r = 0; r < 4; ++r) {
        unsigned long long k = bk[r];
#pragma unroll
        for (int o = 1; o < 16; o <<= 1) {
          const unsigned long long ok =
              (unsigned long long)__shfl_xor((long long)k, o, 16);
          if (ok > k) k = ok;
        }
        if ((lane & 15) == 0)
          atomicMax(keys + (size_t)blockIdx.z * 1024 + (m0 + r), k);
      }
    }
    return;
  }

#pragma unroll
  for (int fm = 0; fm < 4; ++fm) {
#pragma unroll
    for (int fn = 0; fn < 4; ++fn) {
      const int n  = bn + wc * 64 + fn * 16 + cr;
      const int m0 = bm + wr * 64 + fm * 16 + 4 * cg;
      float bv = 0.f;
      if (BIAS) bv = bias[zBias + n];
      if (OUTM == 4) {
        u16x4 o;
#pragma unroll
        for (int r = 0; r < 4; ++r) {
          float x = acc0[fm][fn][r];
          if constexpr (ORD == 1) x += acc1[fm][fn][r] * RS;
          x = x * scale + bv;
          if (RELU) x = fmaxf(x, 0.f);
          o[r] = f2bf(x);
        }
        *(u16x4*)(O0B + (size_t)n * ldc + m0) = o;
      } else {
#pragma unroll
        for (int r = 0; r < 4; ++r) {
          float x = acc0[fm][fn][r];
          if constexpr (ORD == 1) x += acc1[fm][fn][r] * RS;
          x = x * scale + bv;
          if (RELU) x = fmaxf(x, 0.f);
          const size_t off = (size_t)(m0 + r) * ldc + n;
          if (OUTM == 0) CfB[off] = x;
          else if (OUTM == 3) O0B[off] = f2bf(x);
          else {
            unsigned short a, b;
            split2h(x, a, b);
            O0B[off] = a; O1B[off] = b;
          }
        }
      }
    }
  }
}

// ---------------------------------------------------------------------------
// Masked softmax over full rows of length 1024; emits P^T[b][j][i] bf16.
// Lg layout [b][1024][1024]. Argmax indices decoded from packed keys:
// idx = 255 - (key & 0xFFFFFFFF).
// ---------------------------------------------------------------------------
__global__ __launch_bounds__(256)
void softmax_T(const float* __restrict__ Lg, const unsigned long long* __restrict__ keysA,
               const unsigned long long* __restrict__ keysB,
               unsigned short* __restrict__ PT)
{
  __shared__ int bj[1024];
  __shared__ unsigned short tile[1024 * 17];
  const int tid = threadIdx.x;
  const int i0  = blockIdx.x * 16;          // 0..1008
  const int b   = blockIdx.y;
  const int r   = tid >> 4;
  const int l16 = tid & 15;

  for (int j = tid; j < 1024; j += 256)
    bj[j] = 255 - (int)(keysB[(b << 10) + j] & 0xFFFFFFFFull);
  __syncthreads();

  const int ai = 255 - (int)(keysA[(b << 10) + i0 + r] & 0xFFFFFFFFull);
  const float* Lr = Lg + ((size_t)(b << 10) + i0 + r) * 1024;
  const int jb = l16 * 64;

  float x[64];
  float mx = -3.0e38f;
#pragma unroll
  for (int q = 0; q < 16; ++q) {
    f32x4 f = *(const f32x4*)(Lr + jb + (q << 2));
#pragma unroll
    for (int u = 0; u < 4; ++u) {
      const int j = jb + (q << 2) + u;
      float t = f[u];
      if (bj[j] != ai) t -= 1e6f;
      x[(q << 2) + u] = t;
      mx = fmaxf(mx, t);
    }
  }
#pragma unroll
  for (int off = 8; off >= 1; off >>= 1) mx = fmaxf(mx, __shfl_xor(mx, off));
  float s = 0.f;
#pragma unroll
  for (int k = 0; k < 64; ++k) { float e = expf(x[k] - mx); x[k] = e; s += e; }
#pragma unroll
  for (int off = 8; off >= 1; off >>= 1) s += __shfl_xor(s, off);
  const float inv = 1.f / s;

#pragma unroll
  for (int k = 0; k < 64; ++k)
    tile[(jb + k) * 17 + r] = f2bf(x[k] * inv);
  __syncthreads();

  for (int j = tid; j < 1024; j += 256) {
    const unsigned short* tp = &tile[j * 17];
    unsigned int w[8];
#pragma unroll
    for (int q = 0; q < 8; ++q)
      w[q] = (unsigned int)tp[2 * q] | ((unsigned int)tp[2 * q + 1] << 16);
    const size_t off = ((size_t)b << 20) + ((size_t)j << 10) + i0;
    unsigned int* dst = (unsigned int*)(PT + off);
    *(uint4*)dst       = make_uint4(w[0], w[1], w[2], w[3]);
    *((uint4*)dst + 1) = make_uint4(w[4], w[5], w[6], w[7]);
  }
}

// ---------------------------------------------------------------------------
extern "C" void kernel_launch(void* const* d_in, const int* in_sizes, int n_in,
                              void* d_out, int out_size, void* d_ws, size_t ws_size,
                              hipStream_t stream)
{
  (void)in_sizes; (void)n_in; (void)out_size; (void)ws_size;

  const float* tok  = (const float*)d_in[0];
  const float* supp = (const float*)d_in[1];
  const float* qry  = (const float*)d_in[2];
  const float* W_qa = (const float*)d_in[3];
  const float* b_qa = (const float*)d_in[4];
  const float* W_ks = (const float*)d_in[5];
  const float* b_ks = (const float*)d_in[6];
  const float* W_ka = (const float*)d_in[7];
  const float* b_ka = (const float*)d_in[8];
  const float* W_vs = (const float*)d_in[9];
  const float* b_vs = (const float*)d_in[10];
  const float* W_f1 = (const float*)d_in[11];
  const float* b_f1 = (const float*)d_in[12];
  const float* W_f2 = (const float*)d_in[13];
  const float* b_f2 = (const float*)d_in[14];

  auto kProj  = &gke<1,1,2,1,true ,false,true >;   // 64 KB, vmcnt(8)
  auto kScore = &gke<1,1,2,5,false,false,true >;   // 64 KB, vmcnt(8) [was 128 KB]
  auto kLogit = &gke<1,1,2,0,false,false,true >;   // 64 KB
  auto kVsT   = &gke<0,1,2,4,true ,false,true >;   // 32 KB fp16 1-pass
  auto kPV    = &gke<0,1,2,3,false,false,false>;   // 32 KB bf16
  auto kFFN1  = &gke<0,1,2,3,true ,true ,false>;   // 32 KB bf16
  auto kFFN2  = &gke<0,1,2,0,true ,false,false>;   // 32 KB bf16
  hipFuncSetAttribute((const void*)kProj,  hipFuncAttributeMaxDynamicSharedMemorySize, 65536);
  hipFuncSetAttribute((const void*)kScore, hipFuncAttributeMaxDynamicSharedMemorySize, 65536);
  hipFuncSetAttribute((const void*)kLogit, hipFuncAttributeMaxDynamicSharedMemorySize, 65536);
  hipFuncSetAttribute((const void*)kVsT,   hipFuncAttributeMaxDynamicSharedMemorySize, 32768);
  hipFuncSetAttribute((const void*)kPV,    hipFuncAttributeMaxDynamicSharedMemorySize, 32768);
  hipFuncSetAttribute((const void*)kFFN1,  hipFuncAttributeMaxDynamicSharedMemorySize, 32768);
  hipFuncSetAttribute((const void*)kFFN2,  hipFuncAttributeMaxDynamicSharedMemorySize, 32768);

  char* W = (char*)d_ws;
  constexpr size_t MiB = 1048576;
  auto U = [&](double off) { return (unsigned short*)(W + (size_t)(off * MiB)); };
  auto F = [&](double off) { return (float*)(W + (size_t)(off * MiB)); };
  auto KY = [&](double off) { return (unsigned long long*)(W + (size_t)(off * MiB)); };

  // layout (MiB), audited r18 (passing):
  // tokP 0-8 -> suppP0 0-16 -> score[qt|sa] P0 0-16 -> PT 0-32
  // W: KA_p0@16 QA_p0@16.5 KA_p1@17 QA_p1@17.5 KS_p0@18 KS_p1@18.5 VS@19
  // kaqa P0 22-30, P1 30-38 (dead after S8) | dec 32-48 (written S11)
  // qryP0 46-62 -> suppP1 46-62 -> score P1 46-62 | qryP1 62-78 -> vsT 62-78
  // qq/ks planes 78-142 -> Lg 78-142 -> mid 94-142 (disjoint from dec 32-48)
  // WF1 142-143.5, WF2 143.5-145 | bias 148, keys 148.5-148.75
  const dim3 B256(256), BW(32, 8);
  float* dummyF = F(78);
  unsigned short* dummyU = U(78);
  unsigned long long* dummyK = KY(78);

  // S0: biases adjacent (ka first: merged-proj z=0 -> ka); zero merged keys
  hipMemcpyAsync(W + (size_t)(148.0 * MiB), b_ka, 2048, hipMemcpyDeviceToDevice, stream);
  hipMemcpyAsync(W + (size_t)(148.0 * MiB) + 2048, b_qa, 2048, hipMemcpyDeviceToDevice, stream);
  hipMemsetAsync(KY(148.5), 0, 32 * 1024 * 8, stream);

  // S1: weight + tok splits (W_ka/W_qa planes interleaved for affine z-stride)
  split_wT2h<<<dim3(16,16), BW, 0, stream>>>(W_ka, U(16),   U(17),   512, 512);
  split_wT2h<<<dim3(16,16), BW, 0, stream>>>(W_qa, U(16.5), U(17.5), 512, 512);
  split_wT2h<<<dim3(16,16), BW, 0, stream>>>(W_ks, U(18),   U(18.5), 512, 512);
  split_wT1<true><<<dim3(16,16), BW, 0, stream>>>(W_vs, U(19), 512, 512);
  split_act2h<<<dim3(2048), B256, 0, stream>>>((const f32x4*)tok, (u16x4*)U(0), (u16x4*)U(4), 524288);
  // S2: ka|qa merged projection (z=0 -> {W_ka,b_ka}, z=1 -> {W_qa,b_qa})
  kProj<<<dim3(32,4,2), B256, 65536, stream>>>(
      U(0),U(4), U(16),U(17),
      F(148), dummyF, U(22),U(30), dummyK, 512, 512, 0, 262144, 2097152, 512, 1.f);
  // S3: qry split
  split_act2h<<<dim3(8192), B256, 0, stream>>>((const f32x4*)qry, (u16x4*)U(46), (u16x4*)U(62), 2097152);
  // S4: qq projection -> qqP0@78, qqP1@110
  kProj<<<dim3(128,4,1), B256, 65536, stream>>>(
      U(46),U(62), U(16.5),U(17.5),
      b_qa, dummyF, U(78),U(110), dummyK, 512, 512, 0,0,0,0, 1.f);
  // S5: supp split (over dead tok / dead qryP0)
  split_act2h<<<dim3(8192), B256, 0, stream>>>((const f32x4*)supp, (u16x4*)U(0), (u16x4*)U(46), 2097152);
  // S6: ks projection -> ksP0@94, ksP1@126
  kProj<<<dim3(128,4,1), B256, 65536, stream>>>(
      U(0),U(46), U(18),U(18.5),
      b_ks, dummyF, U(94),U(126), dummyK, 512, 512, 0,0,0,0, 1.f);
  // S7: vs^T (reads suppP0) -> vsT@62 (over dead qryP1)
  kVsT<<<dim3(8,4,16), B256, 32768, stream>>>(
      U(0),dummyU, U(19),dummyU,
      b_vs, dummyF, U(62),dummyU, dummyK, 512, 1024,
      524288, 0, 524288, 0, 1.f);
  // S8: MERGED scores (z=0..15: qt = qq.ka^T/8; z=16..31: sa = ks.qa^T/8)
  //     now 64 KB LDS -> 2 blocks/CU (was 1)
  kScore<<<dim3(8,2,32), B256, 65536, stream>>>(
      U(78),U(110), U(22),U(30),
      nullptr, dummyF, U(0),U(46), KY(148.5), 512, 256,
      524288, 131072, 262144, 0, 0.125f);
  // FFN weight splits (region 142-145 free throughout)
  split_wT1<false><<<dim3(16,48), BW, 0, stream>>>(W_f1, U(142), 512, 1536);
  split_wT1<false><<<dim3(48,16), BW, 0, stream>>>(W_f2, U(143.5), 1536, 512);
  // S9: MERGED logits = sa . qt^T -> Lg[b][1024][1024] fp32 @78 (64 MiB)
  kLogit<<<dim3(8,8,16), B256, 65536, stream>>>(
      U(8),U(54), U(0),U(46),
      nullptr, F(78), dummyU,dummyU, dummyK, 256, 1024,
      262144, 262144, 1048576, 0, 1.f);
  // S10: masked softmax (full rows) -> P^T bf16 @0 (32 MiB)
  softmax_T<<<dim3(64,16), B256, 0, stream>>>(F(78), KY(148.5) + 16384, KY(148.5), U(0));
  // S11: dec = P^T . vs -> bf16 @32
  kPV<<<dim3(8,4,16), B256, 32768, stream>>>(
      U(0),dummyU, U(62),dummyU,
      nullptr, dummyF, U(32),dummyU, dummyK, 1024, 512,
      1048576, 524288, 524288, 0, 1.f);
  // S12: FFN1 = relu(dec @ W_f1 + b1) -> bf16 @94 (over dead Lg)
  kFFN1<<<dim3(128,12,1), B256, 32768, stream>>>(
      U(32),dummyU, U(142),dummyU,
      b_f1, dummyF, U(94),dummyU, dummyK, 512, 1536, 0,0,0,0, 1.f);
  // S13: FFN2 = mid @ W_f2 + b2 -> d_out fp32
  kFFN2<<<dim3(128,4,1), B256, 32768, stream>>>(
      U(94),dummyU, U(143.5),dummyU,
      b_f2, (float*)d_out, dummyU,dummyU, dummyK, 1536, 512, 0,0,0,0, 1.f);
}

// Round 20
// 384.277 us; speedup vs baseline: 1.0651x; 1.0092x over previous
//
#include <hip/hip_runtime.h>

typedef float          f32x4  __attribute__((ext_vector_type(4)));
typedef short          bf16x8 __attribute__((ext_vector_type(8)));
typedef _Float16       f16x8  __attribute__((ext_vector_type(8)));
typedef unsigned short u16x4  __attribute__((ext_vector_type(4)));

static constexpr int kBS = 16;
static constexpr int kHW = 1024;

__device__ __forceinline__ unsigned short f2bf(float x) {
  union { float f; unsigned int u; } v; v.f = x;
  unsigned int r = v.u + 0x7fffu + ((v.u >> 16) & 1u);
  return (unsigned short)(r >> 16);
}
__device__ __forceinline__ float bf2f(unsigned short h) {
  union { unsigned int u; float f; } v; v.u = ((unsigned int)h) << 16;
  return v.f;
}
__device__ __forceinline__ unsigned short h2u(_Float16 h) {
  union { _Float16 h; unsigned short u; } v; v.h = h; return v.u;
}
// order-preserving f32 -> u32 (finite floats)
__device__ __forceinline__ unsigned int fmono(float f) {
  union { float f; unsigned int u; } v; v.f = f;
  return (v.u & 0x80000000u) ? ~v.u : (v.u | 0x80000000u);
}

// 2-plane fp16 split with 4096-scaled residual: x ~= p0 + p1/4096.
__device__ __forceinline__ void split2h(float x, unsigned short& u0, unsigned short& u1) {
  _Float16 h0 = (_Float16)x;
  if (fabsf(x) < 6.1035156e-05f) h0 = (_Float16)0.f;
  const float r = (x - (float)h0) * 4096.f;
  u0 = h2u(h0);
  u1 = h2u((_Float16)r);
}

// ---------------------------------------------------------------------------
__global__ __launch_bounds__(256)
void split_act2h(const f32x4* __restrict__ X, u16x4* __restrict__ P0,
                 u16x4* __restrict__ P1, int n4)
{
  int i = blockIdx.x * 256 + threadIdx.x;
  if (i >= n4) return;
  f32x4 x = X[i];
  u16x4 s0, s1;
#pragma unroll
  for (int u = 0; u < 4; ++u) {
    unsigned short a, b;
    split2h(x[u], a, b);
    s0[u] = a; s1[u] = b;
  }
  P0[i] = s0; P1[i] = s1;
}

__global__ __launch_bounds__(256)
void split_wT2h(const float* __restrict__ Wm, unsigned short* __restrict__ T0,
                unsigned short* __restrict__ T1, int K, int N)
{
  __shared__ float ts[32][33];
  const int k0 = blockIdx.x * 32, n0 = blockIdx.y * 32;
  const int tx = threadIdx.x, ty = threadIdx.y;   // 32 x 8
#pragma unroll
  for (int r = 0; r < 4; ++r)
    ts[ty + r * 8][tx] = Wm[(size_t)(k0 + ty + r * 8) * N + n0 + tx];
  __syncthreads();
#pragma unroll
  for (int r = 0; r < 4; ++r) {
    const int n = ty + r * 8;
    const size_t off = (size_t)(n0 + n) * K + k0 + tx;
    unsigned short a, b;
    split2h(ts[tx][n], a, b);
    T0[off] = a; T1[off] = b;
  }
}

template<bool F16>
__global__ __launch_bounds__(256)
void split_wT1(const float* __restrict__ Wm, unsigned short* __restrict__ T0,
               int K, int N)
{
  __shared__ float ts[32][33];
  const int k0 = blockIdx.x * 32, n0 = blockIdx.y * 32;
  const int tx = threadIdx.x, ty = threadIdx.y;
#pragma unroll
  for (int r = 0; r < 4; ++r)
    ts[ty + r * 8][tx] = Wm[(size_t)(k0 + ty + r * 8) * N + n0 + tx];
  __syncthreads();
#pragma unroll
  for (int r = 0; r < 4; ++r) {
    const int n = ty + r * 8;
    const float x = ts[tx][n];
    const size_t off = (size_t)(n0 + n) * K + k0 + tx;
    T0[off] = F16 ? h2u((_Float16)x) : f2bf(x);
  }
}

// ---------------------------------------------------------------------------
// Staging: one 128x32 16-bit tile -> linear LDS via global_load_lds(16B),
// involution pre-swizzled source cols. 2 loads/wave.
// ---------------------------------------------------------------------------
__device__ __forceinline__ void stage_tile(const unsigned short* src, int K,
                                           unsigned short* ldst, int wv, int lane)
{
#pragma unroll
  for (int i = 0; i < 2; ++i) {
    const int s   = wv * 128 + i * 64 + lane;
    const int row = s >> 2;
    const int gc  = ((s & 3) ^ ((row >> 1) & 3)) * 8;
    __builtin_amdgcn_global_load_lds(
        (const __attribute__((address_space(1))) void*)(src + (size_t)row * K + gc),
        (__attribute__((address_space(3))) void*)(ldst + ((wv * 128 + i * 64) << 3)),
        16, 0, 0);
  }
}

// ---------------------------------------------------------------------------
// Unified 128x128 MFMA GEMM engine (r10 measured-best config). 4 waves, BK=32,
// KU tiles/phase, DEPTH-deep circular dbuf with counted vmcnt.
//  ORD0: 1-pass;  ORD1: fp16 scaled-residual 2-plane, 3 passes.
// OUTM: 0=f32, 1=2 fp16 planes, 3=bf16, 4=bf16 transposed ([N][M], ldc),
//       5=2 fp16 planes + fused row-argmax (packed-key atomicMax).
// SWZ: chunked XCD swizzle (bijective, requires nwg%8==0) -- each XCD owns
//      contiguous work (whole z-batches) so B-slice/A-panel re-reads hit the
//      XCD-local L2 instead of being refetched by all 8 XCDs [T1/m204].
// Batched via z strides sA/sB/sC/sBias (affine merged dispatches).
// ---------------------------------------------------------------------------
template<int ORD, int KU, int DEPTH, int OUTM, bool BIAS, bool RELU, bool F16IN, bool SWZ>
__global__ __launch_bounds__(256)
void gke(const unsigned short* __restrict__ A0, const unsigned short* __restrict__ A1,
         const unsigned short* __restrict__ B0, const unsigned short* __restrict__ B1,
         const float* __restrict__ bias,
         float* __restrict__ Cf, unsigned short* __restrict__ O0,
         unsigned short* __restrict__ O1, unsigned long long* __restrict__ keys,
         int K, int ldc, long sA, long sB, long sC, long sBias, float scale)
{
  constexpr int NP   = ORD + 1;
  constexpr int NT   = 2 * NP;
  constexpr int TPP  = KU * NT;
  constexpr int LPP  = TPP * 2;
  static_assert(DEPTH == 2 || DEPTH == 4, "DEPTH in {2,4}");
  static_assert(LPP == 4 || LPP == 8 || LPP == 16, "vmcnt literals");
  extern __shared__ __align__(16) unsigned short lds[];

  const int tid  = threadIdx.x;
  const int wv   = tid >> 6, lane = tid & 63;
  const int wr   = wv >> 1,  wc   = wv & 1;
  const int cr   = lane & 15, cg  = lane >> 4;

  unsigned bx = blockIdx.x, by = blockIdx.y, bz = blockIdx.z;
  if constexpr (SWZ) {
    const unsigned gx = gridDim.x, gy = gridDim.y;
    const unsigned nwg = gx * gy * gridDim.z;      // must be %8==0
    const unsigned lin = blockIdx.x + gx * (blockIdx.y + gy * blockIdx.z);
    const unsigned w = (lin & 7u) * (nwg >> 3) + (lin >> 3);
    bx = w % gx; by = (w / gx) % gy; bz = w / (gx * gy);
  }
  const int bm = bx * 128, bn = by * 128;

  const size_t zA = (size_t)bz * (size_t)sA;
  const size_t zB = (size_t)bz * (size_t)sB;
  const size_t zC = (size_t)bz * (size_t)sC;
  const size_t zBias = (size_t)bz * (size_t)sBias;

  const unsigned short* srcs[NT];
  srcs[0] = A0 + zA + (size_t)bm * K;
  if (NP == 2) srcs[1] = A1 + zA + (size_t)bm * K;
  srcs[NP + 0] = B0 + zB + (size_t)bn * K;
  if (NP == 2) srcs[NP + 1] = B1 + zB + (size_t)bn * K;

  f32x4 acc0[4][4], acc1[4][4];
#pragma unroll
  for (int i = 0; i < 4; ++i)
#pragma unroll
    for (int j = 0; j < 4; ++j)
#pragma unroll
      for (int r = 0; r < 4; ++r) {
        acc0[i][j][r] = 0.f;
        if (ORD == 1) acc1[i][j][r] = 0.f;
      }

#define STAGE_PH(ph, buf)                                                       \
  {                                                                             \
    _Pragma("unroll")                                                           \
    for (int u = 0; u < KU; ++u)                                                \
      _Pragma("unroll")                                                         \
      for (int t = 0; t < NT; ++t)                                              \
        stage_tile(srcs[t] + ((ph) * KU + u) * 32, K,                           \
                   lds + (size_t)((buf) * TPP + u * NT + t) * 4096, wv, lane);  \
  }
#define LOADA(u, pa)                                                            \
  {                                                                             \
    _Pragma("unroll")                                                           \
    for (int f = 0; f < 4; ++f) {                                               \
      const int ra = wr * 64 + f * 16 + cr;                                     \
      af[f] = *(const bf16x8*)&lb[(size_t)((u) * NT + (pa)) * 4096 +            \
                                  (ra * 4 + (cg ^ ((ra >> 1) & 3))) * 8];       \
    }                                                                           \
  }
#define DOPB(u, pb, ACC)                                                        \
  {                                                                             \
    bf16x8 bfr[4];                                                              \
    _Pragma("unroll")                                                           \
    for (int f = 0; f < 4; ++f) {                                               \
      const int rb = wc * 64 + f * 16 + cr;                                     \
      bfr[f] = *(const bf16x8*)&lb[(size_t)((u) * NT + NP + (pb)) * 4096 +      \
                                   (rb * 4 + (cg ^ ((rb >> 1) & 3))) * 8];      \
    }                                                                           \
    _Pragma("unroll")                                                           \
    for (int i = 0; i < 4; ++i)                                                 \
      _Pragma("unroll")                                                         \
      for (int j = 0; j < 4; ++j) {                                             \
        if constexpr (F16IN)                                                    \
          ACC[i][j] = __builtin_amdgcn_mfma_f32_16x16x32_f16(                   \
              __builtin_bit_cast(f16x8, af[i]), __builtin_bit_cast(f16x8, bfr[j]), \
              ACC[i][j], 0, 0, 0);                                              \
        else                                                                    \
          ACC[i][j] = __builtin_amdgcn_mfma_f32_16x16x32_bf16(af[i], bfr[j],    \
              ACC[i][j], 0, 0, 0);                                              \
      }                                                                         \
  }
#define COMPUTE_PH(buf)                                                         \
  {                                                                             \
    const unsigned short* lb = lds + (size_t)(buf) * TPP * 4096;                \
    bf16x8 af[4];                                                               \
    _Pragma("unroll")                                                           \
    for (int u = 0; u < KU; ++u) {                                              \
      if constexpr (ORD == 1) {                                                 \
        LOADA(u, 0); DOPB(u, 0, acc0); DOPB(u, 1, acc1);                        \
        LOADA(u, 1); DOPB(u, 0, acc1);                                          \
      } else {                                                                  \
        LOADA(u, 0); DOPB(u, 0, acc0);                                          \
      }                                                                         \
    }                                                                           \
  }

  const int nph = K / (32 * KU);
#pragma unroll
  for (int d = 0; d < DEPTH; ++d)
    if (d < nph) STAGE_PH(d, d);

  for (int ph = 0; ph < nph; ++ph) {
    const int rem = nph - 1 - ph;
    const int fut = rem < (DEPTH - 1) ? rem : (DEPTH - 1);
    if constexpr (LPP == 4) {
      if (fut >= 3)      asm volatile("s_waitcnt vmcnt(12)" ::: "memory");
      else if (fut == 2) asm volatile("s_waitcnt vmcnt(8)" ::: "memory");
      else if (fut == 1) asm volatile("s_waitcnt vmcnt(4)" ::: "memory");
      else               asm volatile("s_waitcnt vmcnt(0)" ::: "memory");
    } else if constexpr (LPP == 8) {
      if (fut >= 3)      asm volatile("s_waitcnt vmcnt(24)" ::: "memory");
      else if (fut == 2) asm volatile("s_waitcnt vmcnt(16)" ::: "memory");
      else if (fut == 1) asm volatile("s_waitcnt vmcnt(8)" ::: "memory");
      else               asm volatile("s_waitcnt vmcnt(0)" ::: "memory");
    } else {
      if (fut >= 1)      asm volatile("s_waitcnt vmcnt(16)" ::: "memory");
      else               asm volatile("s_waitcnt vmcnt(0)" ::: "memory");
    }
    __builtin_amdgcn_sched_barrier(0);
    __builtin_amdgcn_s_barrier();        // all waves' stores for buf landed
    COMPUTE_PH(ph & (DEPTH - 1));
    __builtin_amdgcn_s_barrier();        // all readers of buf done
    __builtin_amdgcn_sched_barrier(0);
    if (ph + DEPTH < nph) STAGE_PH(ph + DEPTH, ph & (DEPTH - 1));
  }
#undef STAGE_PH
#undef LOADA
#undef DOPB
#undef COMPUTE_PH

  // epilogue: C/D layout col = lane&15, row = 4*(lane>>4)+reg  [m89-verified]
  const float RS = 2.44140625e-4f;       // 1/4096
  float* CfB = Cf + zC;
  unsigned short* O0B = O0 + zC;
  unsigned short* O1B = O1 + zC;

  if constexpr (OUTM == 5) {
#pragma unroll
    for (int fm = 0; fm < 4; ++fm) {
      const int m0 = bm + wr * 64 + fm * 16 + 4 * cg;
      unsigned long long bk[4] = {0ull, 0ull, 0ull, 0ull};
#pragma unroll
      for (int fn = 0; fn < 4; ++fn) {
        const int n = bn + wc * 64 + fn * 16 + cr;
#pragma unroll
        for (int r = 0; r < 4; ++r) {
          const float x = (acc0[fm][fn][r] + acc1[fm][fn][r] * RS) * scale;
          unsigned short a, b;
          split2h(x, a, b);
          const size_t off = (size_t)(m0 + r) * ldc + n;
          O0B[off] = a; O1B[off] = b;
          const unsigned long long k =
              ((unsigned long long)fmono(x) << 32) | (unsigned)(255 - n);
          if (k > bk[r]) bk[r] = k;
        }
      }
#pragma unroll
      for (int r = 0; r < 4; ++r) {
        unsigned long long k = bk[r];
#pragma unroll
        for (int o = 1; o < 16; o <<= 1) {
          const unsigned long long ok =
              (unsigned long long)__shfl_xor((long long)k, o, 16);
          if (ok > k) k = ok;
        }
        if ((lane & 15) == 0)
          atomicMax(keys + (size_t)bz * 1024 + (m0 + r), k);
      }
    }
    return;
  }

#pragma unroll
  for (int fm = 0; fm < 4; ++fm) {
#pragma unroll
    for (int fn = 0; fn < 4; ++fn) {
      const int n  = bn + wc * 64 + fn * 16 + cr;
      const int m0 = bm + wr * 64 + fm * 16 + 4 * cg;
      float bv = 0.f;
      if (BIAS) bv = bias[zBias + n];
      if (OUTM == 4) {
        u16x4 o;
#pragma unroll
        for (int r = 0; r < 4; ++r) {
          float x = acc0[fm][fn][r];
          if constexpr (ORD == 1) x += acc1[fm][fn][r] * RS;
          x = x * scale + bv;
          if (RELU) x = fmaxf(x, 0.f);
          o[r] = f2bf(x);
        }
        *(u16x4*)(O0B + (size_t)n * ldc + m0) = o;
      } else {
#pragma unroll
        for (int r = 0; r < 4; ++r) {
          float x = acc0[fm][fn][r];
          if constexpr (ORD == 1) x += acc1[fm][fn][r] * RS;
          x = x * scale + bv;
          if (RELU) x = fmaxf(x, 0.f);
          const size_t off = (size_t)(m0 + r) * ldc + n;
          if (OUTM == 0) CfB[off] = x;
          else if (OUTM == 3) O0B[off] = f2bf(x);
          else {
            unsigned short a, b;
            split2h(x, a, b);
            O0B[off] = a; O1B[off] = b;
          }
        }
      }
    }
  }
}

// ---------------------------------------------------------------------------
// Masked softmax over full rows of length 1024; emits P^T[b][j][i] bf16.
// Lg layout [b][1024][1024]. Argmax indices decoded from packed keys:
// idx = 255 - (key & 0xFFFFFFFF).
// ---------------------------------------------------------------------------
__global__ __launch_bounds__(256)
void softmax_T(const float* __restrict__ Lg, const unsigned long long* __restrict__ keysA,
               const unsigned long long* __restrict__ keysB,
               unsigned short* __restrict__ PT)
{
  __shared__ int bj[1024];
  __shared__ unsigned short tile[1024 * 17];
  const int tid = threadIdx.x;
  const int i0  = blockIdx.x * 16;          // 0..1008
  const int b   = blockIdx.y;
  const int r   = tid >> 4;
  const int l16 = tid & 15;

  for (int j = tid; j < 1024; j += 256)
    bj[j] = 255 - (int)(keysB[(b << 10) + j] & 0xFFFFFFFFull);
  __syncthreads();

  const int ai = 255 - (int)(keysA[(b << 10) + i0 + r] & 0xFFFFFFFFull);
  const float* Lr = Lg + ((size_t)(b << 10) + i0 + r) * 1024;
  const int jb = l16 * 64;

  float x[64];
  float mx = -3.0e38f;
#pragma unroll
  for (int q = 0; q < 16; ++q) {
    f32x4 f = *(const f32x4*)(Lr + jb + (q << 2));
#pragma unroll
    for (int u = 0; u < 4; ++u) {
      const int j = jb + (q << 2) + u;
      float t = f[u];
      if (bj[j] != ai) t -= 1e6f;
      x[(q << 2) + u] = t;
      mx = fmaxf(mx, t);
    }
  }
#pragma unroll
  for (int off = 8; off >= 1; off >>= 1) mx = fmaxf(mx, __shfl_xor(mx, off));
  float s = 0.f;
#pragma unroll
  for (int k = 0; k < 64; ++k) { float e = expf(x[k] - mx); x[k] = e; s += e; }
#pragma unroll
  for (int off = 8; off >= 1; off >>= 1) s += __shfl_xor(s, off);
  const float inv = 1.f / s;

#pragma unroll
  for (int k = 0; k < 64; ++k)
    tile[(jb + k) * 17 + r] = f2bf(x[k] * inv);
  __syncthreads();

  for (int j = tid; j < 1024; j += 256) {
    const unsigned short* tp = &tile[j * 17];
    unsigned int w[8];
#pragma unroll
    for (int q = 0; q < 8; ++q)
      w[q] = (unsigned int)tp[2 * q] | ((unsigned int)tp[2 * q + 1] << 16);
    const size_t off = ((size_t)b << 20) + ((size_t)j << 10) + i0;
    unsigned int* dst = (unsigned int*)(PT + off);
    *(uint4*)dst       = make_uint4(w[0], w[1], w[2], w[3]);
    *((uint4*)dst + 1) = make_uint4(w[4], w[5], w[6], w[7]);
  }
}

// ---------------------------------------------------------------------------
extern "C" void kernel_launch(void* const* d_in, const int* in_sizes, int n_in,
                              void* d_out, int out_size, void* d_ws, size_t ws_size,
                              hipStream_t stream)
{
  (void)in_sizes; (void)n_in; (void)out_size; (void)ws_size;

  const float* tok  = (const float*)d_in[0];
  const float* supp = (const float*)d_in[1];
  const float* qry  = (const float*)d_in[2];
  const float* W_qa = (const float*)d_in[3];
  const float* b_qa = (const float*)d_in[4];
  const float* W_ks = (const float*)d_in[5];
  const float* b_ks = (const float*)d_in[6];
  const float* W_ka = (const float*)d_in[7];
  const float* b_ka = (const float*)d_in[8];
  const float* W_vs = (const float*)d_in[9];
  const float* b_vs = (const float*)d_in[10];
  const float* W_f1 = (const float*)d_in[11];
  const float* b_f1 = (const float*)d_in[12];
  const float* W_f2 = (const float*)d_in[13];
  const float* b_f2 = (const float*)d_in[14];

  auto kProj  = &gke<1,1,2,1,true ,false,true ,false>;  // 64 KB, vmcnt(8)
  auto kScore = &gke<1,1,2,5,false,false,true ,true >;  // 64 KB + XCD swizzle
  auto kLogit = &gke<1,1,2,0,false,false,true ,true >;  // 64 KB + XCD swizzle
  auto kVsT   = &gke<0,1,2,4,true ,false,true ,false>;  // 32 KB fp16 1-pass
  auto kPV    = &gke<0,1,2,3,false,false,false,false>;  // 32 KB bf16
  auto kFFN1  = &gke<0,1,2,3,true ,true ,false,false>;  // 32 KB bf16
  auto kFFN2  = &gke<0,1,2,0,true ,false,false,false>;  // 32 KB bf16
  hipFuncSetAttribute((const void*)kProj,  hipFuncAttributeMaxDynamicSharedMemorySize, 65536);
  hipFuncSetAttribute((const void*)kScore, hipFuncAttributeMaxDynamicSharedMemorySize, 65536);
  hipFuncSetAttribute((const void*)kLogit, hipFuncAttributeMaxDynamicSharedMemorySize, 65536);
  hipFuncSetAttribute((const void*)kVsT,   hipFuncAttributeMaxDynamicSharedMemorySize, 32768);
  hipFuncSetAttribute((const void*)kPV,    hipFuncAttributeMaxDynamicSharedMemorySize, 32768);
  hipFuncSetAttribute((const void*)kFFN1,  hipFuncAttributeMaxDynamicSharedMemorySize, 32768);
  hipFuncSetAttribute((const void*)kFFN2,  hipFuncAttributeMaxDynamicSharedMemorySize, 32768);

  char* W = (char*)d_ws;
  constexpr size_t MiB = 1048576;
  auto U = [&](double off) { return (unsigned short*)(W + (size_t)(off * MiB)); };
  auto F = [&](double off) { return (float*)(W + (size_t)(off * MiB)); };
  auto KY = [&](double off) { return (unsigned long long*)(W + (size_t)(off * MiB)); };

  // layout (MiB), audited r18 (passing):
  // tokP 0-8 -> suppP0 0-16 -> score[qt|sa] P0 0-16 -> PT 0-32
  // W: KA_p0@16 QA_p0@16.5 KA_p1@17 QA_p1@17.5 KS_p0@18 KS_p1@18.5 VS@19
  // kaqa P0 22-30, P1 30-38 (dead after S8) | dec 32-48 (written S11)
  // qryP0 46-62 -> suppP1 46-62 -> score P1 46-62 | qryP1 62-78 -> vsT 62-78
  // qq/ks planes 78-142 -> Lg 78-142 -> mid 94-142 (disjoint from dec 32-48)
  // WF1 142-143.5, WF2 143.5-145 | bias 148, keys 148.5-148.75
  const dim3 B256(256), BW(32, 8);
  float* dummyF = F(78);
  unsigned short* dummyU = U(78);
  unsigned long long* dummyK = KY(78);

  // S0: biases adjacent (ka first: merged-proj z=0 -> ka); zero merged keys
  hipMemcpyAsync(W + (size_t)(148.0 * MiB), b_ka, 2048, hipMemcpyDeviceToDevice, stream);
  hipMemcpyAsync(W + (size_t)(148.0 * MiB) + 2048, b_qa, 2048, hipMemcpyDeviceToDevice, stream);
  hipMemsetAsync(KY(148.5), 0, 32 * 1024 * 8, stream);

  // S1: weight + tok splits (W_ka/W_qa planes interleaved for affine z-stride)
  split_wT2h<<<dim3(16,16), BW, 0, stream>>>(W_ka, U(16),   U(17),   512, 512);
  split_wT2h<<<dim3(16,16), BW, 0, stream>>>(W_qa, U(16.5), U(17.5), 512, 512);
  split_wT2h<<<dim3(16,16), BW, 0, stream>>>(W_ks, U(18),   U(18.5), 512, 512);
  split_wT1<true><<<dim3(16,16), BW, 0, stream>>>(W_vs, U(19), 512, 512);
  split_act2h<<<dim3(2048), B256, 0, stream>>>((const f32x4*)tok, (u16x4*)U(0), (u16x4*)U(4), 524288);
  // S2: ka|qa merged projection (z=0 -> {W_ka,b_ka}, z=1 -> {W_qa,b_qa})
  kProj<<<dim3(32,4,2), B256, 65536, stream>>>(
      U(0),U(4), U(16),U(17),
      F(148), dummyF, U(22),U(30), dummyK, 512, 512, 0, 262144, 2097152, 512, 1.f);
  // S3: qry split
  split_act2h<<<dim3(8192), B256, 0, stream>>>((const f32x4*)qry, (u16x4*)U(46), (u16x4*)U(62), 2097152);
  // S4: qq projection -> qqP0@78, qqP1@110
  kProj<<<dim3(128,4,1), B256, 65536, stream>>>(
      U(46),U(62), U(16.5),U(17.5),
      b_qa, dummyF, U(78),U(110), dummyK, 512, 512, 0,0,0,0, 1.f);
  // S5: supp split (over dead tok / dead qryP0)
  split_act2h<<<dim3(8192), B256, 0, stream>>>((const f32x4*)supp, (u16x4*)U(0), (u16x4*)U(46), 2097152);
  // S6: ks projection -> ksP0@94, ksP1@126
  kProj<<<dim3(128,4,1), B256, 65536, stream>>>(
      U(0),U(46), U(18),U(18.5),
      b_ks, dummyF, U(94),U(126), dummyK, 512, 512, 0,0,0,0, 1.f);
  // S7: vs^T (reads suppP0) -> vsT@62 (over dead qryP1)
  kVsT<<<dim3(8,4,16), B256, 32768, stream>>>(
      U(0),dummyU, U(19),dummyU,
      b_vs, dummyF, U(62),dummyU, dummyK, 512, 1024,
      524288, 0, 524288, 0, 1.f);
  // S8: MERGED scores (z=0..15: qt = qq.ka^T/8; z=16..31: sa = ks.qa^T/8)
  //     chunked XCD swizzle: each XCD owns 4 whole z-batches (wset 2.5 MiB/z)
  kScore<<<dim3(8,2,32), B256, 65536, stream>>>(
      U(78),U(110), U(22),U(30),
      nullptr, dummyF, U(0),U(46), KY(148.5), 512, 256,
      524288, 131072, 262144, 0, 0.125f);
  // FFN weight splits (region 142-145 free throughout)
  split_wT1<false><<<dim3(16,48), BW, 0, stream>>>(W_f1, U(142), 512, 1536);
  split_wT1<false><<<dim3(48,16), BW, 0, stream>>>(W_f2, U(143.5), 1536, 512);
  // S9: MERGED logits = sa . qt^T -> Lg fp32 @78; XCD swizzle (2 z per XCD,
  //     wset 2 MiB/z -> qt B-slices no longer refetched by all 8 XCDs)
  kLogit<<<dim3(8,8,16), B256, 65536, stream>>>(
      U(8),U(54), U(0),U(46),
      nullptr, F(78), dummyU,dummyU, dummyK, 256, 1024,
      262144, 262144, 1048576, 0, 1.f);
  // S10: masked softmax (full rows) -> P^T bf16 @0 (32 MiB)
  softmax_T<<<dim3(64,16), B256, 0, stream>>>(F(78), KY(148.5) + 16384, KY(148.5), U(0));
  // S11: dec = P^T . vs -> bf16 @32
  kPV<<<dim3(8,4,16), B256, 32768, stream>>>(
      U(0),dummyU, U(62),dummyU,
      nullptr, dummyF, U(32),dummyU, dummyK, 1024, 512,
      1048576, 524288, 524288, 0, 1.f);
  // S12: FFN1 = relu(dec @ W_f1 + b1) -> bf16 @94 (over dead Lg)
  kFFN1<<<dim3(128,12,1), B256, 32768, stream>>>(
      U(32),dummyU, U(142),dummyU,
      b_f1, dummyF, U(94),dummyU, dummyK, 512, 1536, 0,0,0,0, 1.f);
  // S13: FFN2 = mid @ W_f2 + b2 -> d_out fp32
  kFFN2<<<dim3(128,4,1), B256, 32768, stream>>>(
      U(94),dummyU, U(143.5),dummyU,
      b_f2, (float*)d_out, dummyU,dummyU, dummyK, 1536, 512, 0,0,0,0, 1.f);
}

// Round 21
// 379.263 us; speedup vs baseline: 1.0791x; 1.0132x over previous
//
#include <hip/hip_runtime.h>

typedef float          f32x4  __attribute__((ext_vector_type(4)));
typedef short          bf16x8 __attribute__((ext_vector_type(8)));
typedef _Float16       f16x8  __attribute__((ext_vector_type(8)));
typedef unsigned short u16x4  __attribute__((ext_vector_type(4)));

static constexpr int kBS = 16;
static constexpr int kHW = 1024;

__device__ __forceinline__ unsigned short f2bf(float x) {
  union { float f; unsigned int u; } v; v.f = x;
  unsigned int r = v.u + 0x7fffu + ((v.u >> 16) & 1u);
  return (unsigned short)(r >> 16);
}
__device__ __forceinline__ float bf2f(unsigned short h) {
  union { unsigned int u; float f; } v; v.u = ((unsigned int)h) << 16;
  return v.f;
}
__device__ __forceinline__ unsigned short h2u(_Float16 h) {
  union { _Float16 h; unsigned short u; } v; v.h = h; return v.u;
}
// order-preserving f32 -> u32 (finite floats)
__device__ __forceinline__ unsigned int fmono(float f) {
  union { float f; unsigned int u; } v; v.f = f;
  return (v.u & 0x80000000u) ? ~v.u : (v.u | 0x80000000u);
}

// 2-plane fp16 split with 4096-scaled residual: x ~= p0 + p1/4096.
__device__ __forceinline__ void split2h(float x, unsigned short& u0, unsigned short& u1) {
  _Float16 h0 = (_Float16)x;
  if (fabsf(x) < 6.1035156e-05f) h0 = (_Float16)0.f;
  const float r = (x - (float)h0) * 4096.f;
  u0 = h2u(h0);
  u1 = h2u((_Float16)r);
}

// ---------------------------------------------------------------------------
__global__ __launch_bounds__(256)
void split_act2h(const f32x4* __restrict__ X, u16x4* __restrict__ P0,
                 u16x4* __restrict__ P1, int n4)
{
  int i = blockIdx.x * 256 + threadIdx.x;
  if (i >= n4) return;
  f32x4 x = X[i];
  u16x4 s0, s1;
#pragma unroll
  for (int u = 0; u < 4; ++u) {
    unsigned short a, b;
    split2h(x[u], a, b);
    s0[u] = a; s1[u] = b;
  }
  P0[i] = s0; P1[i] = s1;
}

__global__ __launch_bounds__(256)
void split_wT2h(const float* __restrict__ Wm, unsigned short* __restrict__ T0,
                unsigned short* __restrict__ T1, int K, int N)
{
  __shared__ float ts[32][33];
  const int k0 = blockIdx.x * 32, n0 = blockIdx.y * 32;
  const int tx = threadIdx.x, ty = threadIdx.y;   // 32 x 8
#pragma unroll
  for (int r = 0; r < 4; ++r)
    ts[ty + r * 8][tx] = Wm[(size_t)(k0 + ty + r * 8) * N + n0 + tx];
  __syncthreads();
#pragma unroll
  for (int r = 0; r < 4; ++r) {
    const int n = ty + r * 8;
    const size_t off = (size_t)(n0 + n) * K + k0 + tx;
    unsigned short a, b;
    split2h(ts[tx][n], a, b);
    T0[off] = a; T1[off] = b;
  }
}

template<bool F16>
__global__ __launch_bounds__(256)
void split_wT1(const float* __restrict__ Wm, unsigned short* __restrict__ T0,
               int K, int N)
{
  __shared__ float ts[32][33];
  const int k0 = blockIdx.x * 32, n0 = blockIdx.y * 32;
  const int tx = threadIdx.x, ty = threadIdx.y;
#pragma unroll
  for (int r = 0; r < 4; ++r)
    ts[ty + r * 8][tx] = Wm[(size_t)(k0 + ty + r * 8) * N + n0 + tx];
  __syncthreads();
#pragma unroll
  for (int r = 0; r < 4; ++r) {
    const int n = ty + r * 8;
    const float x = ts[tx][n];
    const size_t off = (size_t)(n0 + n) * K + k0 + tx;
    T0[off] = F16 ? h2u((_Float16)x) : f2bf(x);
  }
}

// ---------------------------------------------------------------------------
// Staging: one 128x32 16-bit tile -> linear LDS via global_load_lds(16B),
// involution pre-swizzled source cols. 2 loads/wave.
// ---------------------------------------------------------------------------
__device__ __forceinline__ void stage_tile(const unsigned short* src, int K,
                                           unsigned short* ldst, int wv, int lane)
{
#pragma unroll
  for (int i = 0; i < 2; ++i) {
    const int s   = wv * 128 + i * 64 + lane;
    const int row = s >> 2;
    const int gc  = ((s & 3) ^ ((row >> 1) & 3)) * 8;
    __builtin_amdgcn_global_load_lds(
        (const __attribute__((address_space(1))) void*)(src + (size_t)row * K + gc),
        (__attribute__((address_space(3))) void*)(ldst + ((wv * 128 + i * 64) << 3)),
        16, 0, 0);
  }
}

// ---------------------------------------------------------------------------
// Unified 128x128 MFMA GEMM engine (r10 measured-best config). 4 waves, BK=32,
// KU tiles/phase, DEPTH-deep circular dbuf with counted vmcnt.
//  ORD0: 1-pass;  ORD1: fp16 scaled-residual 2-plane, 3 passes.
// OUTM: 0=f32, 1=2 fp16 planes, 3=bf16, 4=bf16 transposed ([N][M], ldc),
//       5=2 fp16 planes + fused row-argmax (packed-key atomicMax).
// SWZ: chunked XCD swizzle (bijective, requires nwg%8==0) -- each XCD owns
//      contiguous work (whole z-batches) so per-z panels hit XCD-local L2
//      [T1/m204; r20-verified: score FETCH 98.6->41.3 MB].
// Batched via z strides sA/sB/sC/sBias (affine merged dispatches).
// ---------------------------------------------------------------------------
template<int ORD, int KU, int DEPTH, int OUTM, bool BIAS, bool RELU, bool F16IN, bool SWZ>
__global__ __launch_bounds__(256)
void gke(const unsigned short* __restrict__ A0, const unsigned short* __restrict__ A1,
         const unsigned short* __restrict__ B0, const unsigned short* __restrict__ B1,
         const float* __restrict__ bias,
         float* __restrict__ Cf, unsigned short* __restrict__ O0,
         unsigned short* __restrict__ O1, unsigned long long* __restrict__ keys,
         int K, int ldc, long sA, long sB, long sC, long sBias, float scale)
{
  constexpr int NP   = ORD + 1;
  constexpr int NT   = 2 * NP;
  constexpr int TPP  = KU * NT;
  constexpr int LPP  = TPP * 2;
  static_assert(DEPTH == 2 || DEPTH == 4, "DEPTH in {2,4}");
  static_assert(LPP == 4 || LPP == 8 || LPP == 16, "vmcnt literals");
  extern __shared__ __align__(16) unsigned short lds[];

  const int tid  = threadIdx.x;
  const int wv   = tid >> 6, lane = tid & 63;
  const int wr   = wv >> 1,  wc   = wv & 1;
  const int cr   = lane & 15, cg  = lane >> 4;

  unsigned bx = blockIdx.x, by = blockIdx.y, bz = blockIdx.z;
  if constexpr (SWZ) {
    const unsigned gx = gridDim.x, gy = gridDim.y;
    const unsigned nwg = gx * gy * gridDim.z;      // must be %8==0
    const unsigned lin = blockIdx.x + gx * (blockIdx.y + gy * blockIdx.z);
    const unsigned w = (lin & 7u) * (nwg >> 3) + (lin >> 3);
    bx = w % gx; by = (w / gx) % gy; bz = w / (gx * gy);
  }
  const int bm = bx * 128, bn = by * 128;

  const size_t zA = (size_t)bz * (size_t)sA;
  const size_t zB = (size_t)bz * (size_t)sB;
  const size_t zC = (size_t)bz * (size_t)sC;
  const size_t zBias = (size_t)bz * (size_t)sBias;

  const unsigned short* srcs[NT];
  srcs[0] = A0 + zA + (size_t)bm * K;
  if (NP == 2) srcs[1] = A1 + zA + (size_t)bm * K;
  srcs[NP + 0] = B0 + zB + (size_t)bn * K;
  if (NP == 2) srcs[NP + 1] = B1 + zB + (size_t)bn * K;

  f32x4 acc0[4][4], acc1[4][4];
#pragma unroll
  for (int i = 0; i < 4; ++i)
#pragma unroll
    for (int j = 0; j < 4; ++j)
#pragma unroll
      for (int r = 0; r < 4; ++r) {
        acc0[i][j][r] = 0.f;
        if (ORD == 1) acc1[i][j][r] = 0.f;
      }

#define STAGE_PH(ph, buf)                                                       \
  {                                                                             \
    _Pragma("unroll")                                                           \
    for (int u = 0; u < KU; ++u)                                                \
      _Pragma("unroll")                                                         \
      for (int t = 0; t < NT; ++t)                                              \
        stage_tile(srcs[t] + ((ph) * KU + u) * 32, K,                           \
                   lds + (size_t)((buf) * TPP + u * NT + t) * 4096, wv, lane);  \
  }
#define LOADA(u, pa)                                                            \
  {                                                                             \
    _Pragma("unroll")                                                           \
    for (int f = 0; f < 4; ++f) {                                               \
      const int ra = wr * 64 + f * 16 + cr;                                     \
      af[f] = *(const bf16x8*)&lb[(size_t)((u) * NT + (pa)) * 4096 +            \
                                  (ra * 4 + (cg ^ ((ra >> 1) & 3))) * 8];       \
    }                                                                           \
  }
#define DOPB(u, pb, ACC)                                                        \
  {                                                                             \
    bf16x8 bfr[4];                                                              \
    _Pragma("unroll")                                                           \
    for (int f = 0; f < 4; ++f) {                                               \
      const int rb = wc * 64 + f * 16 + cr;                                     \
      bfr[f] = *(const bf16x8*)&lb[(size_t)((u) * NT + NP + (pb)) * 4096 +      \
                                   (rb * 4 + (cg ^ ((rb >> 1) & 3))) * 8];      \
    }                                                                           \
    _Pragma("unroll")                                                           \
    for (int i = 0; i < 4; ++i)                                                 \
      _Pragma("unroll")                                                         \
      for (int j = 0; j < 4; ++j) {                                             \
        if constexpr (F16IN)                                                    \
          ACC[i][j] = __builtin_amdgcn_mfma_f32_16x16x32_f16(                   \
              __builtin_bit_cast(f16x8, af[i]), __builtin_bit_cast(f16x8, bfr[j]), \
              ACC[i][j], 0, 0, 0);                                              \
        else                                                                    \
          ACC[i][j] = __builtin_amdgcn_mfma_f32_16x16x32_bf16(af[i], bfr[j],    \
              ACC[i][j], 0, 0, 0);                                              \
      }                                                                         \
  }
#define COMPUTE_PH(buf)                                                         \
  {                                                                             \
    const unsigned short* lb = lds + (size_t)(buf) * TPP * 4096;                \
    bf16x8 af[4];                                                               \
    _Pragma("unroll")                                                           \
    for (int u = 0; u < KU; ++u) {                                              \
      if constexpr (ORD == 1) {                                                 \
        LOADA(u, 0); DOPB(u, 0, acc0); DOPB(u, 1, acc1);                        \
        LOADA(u, 1); DOPB(u, 0, acc1);                                          \
      } else {                                                                  \
        LOADA(u, 0); DOPB(u, 0, acc0);                                          \
      }                                                                         \
    }                                                                           \
  }

  const int nph = K / (32 * KU);
#pragma unroll
  for (int d = 0; d < DEPTH; ++d)
    if (d < nph) STAGE_PH(d, d);

  for (int ph = 0; ph < nph; ++ph) {
    const int rem = nph - 1 - ph;
    const int fut = rem < (DEPTH - 1) ? rem : (DEPTH - 1);
    if constexpr (LPP == 4) {
      if (fut >= 3)      asm volatile("s_waitcnt vmcnt(12)" ::: "memory");
      else if (fut == 2) asm volatile("s_waitcnt vmcnt(8)" ::: "memory");
      else if (fut == 1) asm volatile("s_waitcnt vmcnt(4)" ::: "memory");
      else               asm volatile("s_waitcnt vmcnt(0)" ::: "memory");
    } else if constexpr (LPP == 8) {
      if (fut >= 3)      asm volatile("s_waitcnt vmcnt(24)" ::: "memory");
      else if (fut == 2) asm volatile("s_waitcnt vmcnt(16)" ::: "memory");
      else if (fut == 1) asm volatile("s_waitcnt vmcnt(8)" ::: "memory");
      else               asm volatile("s_waitcnt vmcnt(0)" ::: "memory");
    } else {
      if (fut >= 1)      asm volatile("s_waitcnt vmcnt(16)" ::: "memory");
      else               asm volatile("s_waitcnt vmcnt(0)" ::: "memory");
    }
    __builtin_amdgcn_sched_barrier(0);
    __builtin_amdgcn_s_barrier();        // all waves' stores for buf landed
    COMPUTE_PH(ph & (DEPTH - 1));
    __builtin_amdgcn_s_barrier();        // all readers of buf done
    __builtin_amdgcn_sched_barrier(0);
    if (ph + DEPTH < nph) STAGE_PH(ph + DEPTH, ph & (DEPTH - 1));
  }
#undef STAGE_PH
#undef LOADA
#undef DOPB
#undef COMPUTE_PH

  // epilogue: C/D layout col = lane&15, row = 4*(lane>>4)+reg  [m89-verified]
  const float RS = 2.44140625e-4f;       // 1/4096
  float* CfB = Cf + zC;
  unsigned short* O0B = O0 + zC;
  unsigned short* O1B = O1 + zC;

  if constexpr (OUTM == 5) {
#pragma unroll
    for (int fm = 0; fm < 4; ++fm) {
      const int m0 = bm + wr * 64 + fm * 16 + 4 * cg;
      unsigned long long bk[4] = {0ull, 0ull, 0ull, 0ull};
#pragma unroll
      for (int fn = 0; fn < 4; ++fn) {
        const int n = bn + wc * 64 + fn * 16 + cr;
#pragma unroll
        for (int r = 0; r < 4; ++r) {
          const float x = (acc0[fm][fn][r] + acc1[fm][fn][r] * RS) * scale;
          unsigned short a, b;
          split2h(x, a, b);
          const size_t off = (size_t)(m0 + r) * ldc + n;
          O0B[off] = a; O1B[off] = b;
          const unsigned long long k =
              ((unsigned long long)fmono(x) << 32) | (unsigned)(255 - n);
          if (k > bk[r]) bk[r] = k;
        }
      }
#pragma unroll
      for (int r = 0; r < 4; ++r) {
        unsigned long long k = bk[r];
#pragma unroll
        for (int o = 1; o < 16; o <<= 1) {
          const unsigned long long ok =
              (unsigned long long)__shfl_xor((long long)k, o, 16);
          if (ok > k) k = ok;
        }
        if ((lane & 15) == 0)
          atomicMax(keys + (size_t)bz * 1024 + (m0 + r), k);
      }
    }
    return;
  }

#pragma unroll
  for (int fm = 0; fm < 4; ++fm) {
#pragma unroll
    for (int fn = 0; fn < 4; ++fn) {
      const int n  = bn + wc * 64 + fn * 16 + cr;
      const int m0 = bm + wr * 64 + fm * 16 + 4 * cg;
      float bv = 0.f;
      if (BIAS) bv = bias[zBias + n];
      if (OUTM == 4) {
        u16x4 o;
#pragma unroll
        for (int r = 0; r < 4; ++r) {
          float x = acc0[fm][fn][r];
          if constexpr (ORD == 1) x += acc1[fm][fn][r] * RS;
          x = x * scale + bv;
          if (RELU) x = fmaxf(x, 0.f);
          o[r] = f2bf(x);
        }
        *(u16x4*)(O0B + (size_t)n * ldc + m0) = o;
      } else {
#pragma unroll
        for (int r = 0; r < 4; ++r) {
          float x = acc0[fm][fn][r];
          if constexpr (ORD == 1) x += acc1[fm][fn][r] * RS;
          x = x * scale + bv;
          if (RELU) x = fmaxf(x, 0.f);
          const size_t off = (size_t)(m0 + r) * ldc + n;
          if (OUTM == 0) CfB[off] = x;
          else if (OUTM == 3) O0B[off] = f2bf(x);
          else {
            unsigned short a, b;
            split2h(x, a, b);
            O0B[off] = a; O1B[off] = b;
          }
        }
      }
    }
  }
}

// ---------------------------------------------------------------------------
// Masked softmax over full rows of length 1024; emits P^T[b][j][i] bf16.
// Lg layout [b][1024][1024]. Argmax indices decoded from packed keys:
// idx = 255 - (key & 0xFFFFFFFF).
// ---------------------------------------------------------------------------
__global__ __launch_bounds__(256)
void softmax_T(const float* __restrict__ Lg, const unsigned long long* __restrict__ keysA,
               const unsigned long long* __restrict__ keysB,
               unsigned short* __restrict__ PT)
{
  __shared__ int bj[1024];
  __shared__ unsigned short tile[1024 * 17];
  const int tid = threadIdx.x;
  const int i0  = blockIdx.x * 16;          // 0..1008
  const int b   = blockIdx.y;
  const int r   = tid >> 4;
  const int l16 = tid & 15;

  for (int j = tid; j < 1024; j += 256)
    bj[j] = 255 - (int)(keysB[(b << 10) + j] & 0xFFFFFFFFull);
  __syncthreads();

  const int ai = 255 - (int)(keysA[(b << 10) + i0 + r] & 0xFFFFFFFFull);
  const float* Lr = Lg + ((size_t)(b << 10) + i0 + r) * 1024;
  const int jb = l16 * 64;

  float x[64];
  float mx = -3.0e38f;
#pragma unroll
  for (int q = 0; q < 16; ++q) {
    f32x4 f = *(const f32x4*)(Lr + jb + (q << 2));
#pragma unroll
    for (int u = 0; u < 4; ++u) {
      const int j = jb + (q << 2) + u;
      float t = f[u];
      if (bj[j] != ai) t -= 1e6f;
      x[(q << 2) + u] = t;
      mx = fmaxf(mx, t);
    }
  }
#pragma unroll
  for (int off = 8; off >= 1; off >>= 1) mx = fmaxf(mx, __shfl_xor(mx, off));
  float s = 0.f;
#pragma unroll
  for (int k = 0; k < 64; ++k) { float e = expf(x[k] - mx); x[k] = e; s += e; }
#pragma unroll
  for (int off = 8; off >= 1; off >>= 1) s += __shfl_xor(s, off);
  const float inv = 1.f / s;

#pragma unroll
  for (int k = 0; k < 64; ++k)
    tile[(jb + k) * 17 + r] = f2bf(x[k] * inv);
  __syncthreads();

  for (int j = tid; j < 1024; j += 256) {
    const unsigned short* tp = &tile[j * 17];
    unsigned int w[8];
#pragma unroll
    for (int q = 0; q < 8; ++q)
      w[q] = (unsigned int)tp[2 * q] | ((unsigned int)tp[2 * q + 1] << 16);
    const size_t off = ((size_t)b << 20) + ((size_t)j << 10) + i0;
    unsigned int* dst = (unsigned int*)(PT + off);
    *(uint4*)dst       = make_uint4(w[0], w[1], w[2], w[3]);
    *((uint4*)dst + 1) = make_uint4(w[4], w[5], w[6], w[7]);
  }
}

// ---------------------------------------------------------------------------
extern "C" void kernel_launch(void* const* d_in, const int* in_sizes, int n_in,
                              void* d_out, int out_size, void* d_ws, size_t ws_size,
                              hipStream_t stream)
{
  (void)in_sizes; (void)n_in; (void)out_size; (void)ws_size;

  const float* tok  = (const float*)d_in[0];
  const float* supp = (const float*)d_in[1];
  const float* qry  = (const float*)d_in[2];
  const float* W_qa = (const float*)d_in[3];
  const float* b_qa = (const float*)d_in[4];
  const float* W_ks = (const float*)d_in[5];
  const float* b_ks = (const float*)d_in[6];
  const float* W_ka = (const float*)d_in[7];
  const float* b_ka = (const float*)d_in[8];
  const float* W_vs = (const float*)d_in[9];
  const float* b_vs = (const float*)d_in[10];
  const float* W_f1 = (const float*)d_in[11];
  const float* b_f1 = (const float*)d_in[12];
  const float* W_f2 = (const float*)d_in[13];
  const float* b_f2 = (const float*)d_in[14];

  auto kProj  = &gke<1,1,2,1,true ,false,true ,false>;  // 64 KB, vmcnt(8)
  auto kScore = &gke<1,1,2,5,false,false,true ,true >;  // 64 KB + XCD swizzle
  auto kLogit = &gke<1,1,2,0,false,false,true ,true >;  // 64 KB + XCD swizzle
  auto kVsT   = &gke<0,1,2,4,true ,false,true ,true >;  // 32 KB fp16 + swizzle
  auto kPV    = &gke<0,1,2,3,false,false,false,true >;  // 32 KB bf16 + swizzle
  auto kFFN1  = &gke<0,1,2,3,true ,true ,false,false>;  // 32 KB bf16
  auto kFFN2  = &gke<0,1,2,0,true ,false,false,false>;  // 32 KB bf16
  hipFuncSetAttribute((const void*)kProj,  hipFuncAttributeMaxDynamicSharedMemorySize, 65536);
  hipFuncSetAttribute((const void*)kScore, hipFuncAttributeMaxDynamicSharedMemorySize, 65536);
  hipFuncSetAttribute((const void*)kLogit, hipFuncAttributeMaxDynamicSharedMemorySize, 65536);
  hipFuncSetAttribute((const void*)kVsT,   hipFuncAttributeMaxDynamicSharedMemorySize, 32768);
  hipFuncSetAttribute((const void*)kPV,    hipFuncAttributeMaxDynamicSharedMemorySize, 32768);
  hipFuncSetAttribute((const void*)kFFN1,  hipFuncAttributeMaxDynamicSharedMemorySize, 32768);
  hipFuncSetAttribute((const void*)kFFN2,  hipFuncAttributeMaxDynamicSharedMemorySize, 32768);

  char* W = (char*)d_ws;
  constexpr size_t MiB = 1048576;
  auto U = [&](double off) { return (unsigned short*)(W + (size_t)(off * MiB)); };
  auto F = [&](double off) { return (float*)(W + (size_t)(off * MiB)); };
  auto KY = [&](double off) { return (unsigned long long*)(W + (size_t)(off * MiB)); };

  // layout (MiB), audited r18 (passing):
  // tokP 0-8 -> suppP0 0-16 -> score[qt|sa] P0 0-16 -> PT 0-32
  // W: KA_p0@16 QA_p0@16.5 KA_p1@17 QA_p1@17.5 KS_p0@18 KS_p1@18.5 VS@19
  // kaqa P0 22-30, P1 30-38 (dead after S8) | dec 32-48 (written S11)
  // qryP0 46-62 -> suppP1 46-62 -> score P1 46-62 | qryP1 62-78 -> vsT 62-78
  // qq/ks planes 78-142 -> Lg 78-142 -> mid 94-142 (disjoint from dec 32-48)
  // WF1 142-143.5, WF2 143.5-145 | bias 148, keys 148.5-148.75
  const dim3 B256(256), BW(32, 8);
  float* dummyF = F(78);
  unsigned short* dummyU = U(78);
  unsigned long long* dummyK = KY(78);

  // S0: biases adjacent (ka first: merged-proj z=0 -> ka); zero merged keys
  hipMemcpyAsync(W + (size_t)(148.0 * MiB), b_ka, 2048, hipMemcpyDeviceToDevice, stream);
  hipMemcpyAsync(W + (size_t)(148.0 * MiB) + 2048, b_qa, 2048, hipMemcpyDeviceToDevice, stream);
  hipMemsetAsync(KY(148.5), 0, 32 * 1024 * 8, stream);

  // S1: weight + tok splits (W_ka/W_qa planes interleaved for affine z-stride)
  split_wT2h<<<dim3(16,16), BW, 0, stream>>>(W_ka, U(16),   U(17),   512, 512);
  split_wT2h<<<dim3(16,16), BW, 0, stream>>>(W_qa, U(16.5), U(17.5), 512, 512);
  split_wT2h<<<dim3(16,16), BW, 0, stream>>>(W_ks, U(18),   U(18.5), 512, 512);
  split_wT1<true><<<dim3(16,16), BW, 0, stream>>>(W_vs, U(19), 512, 512);
  split_act2h<<<dim3(2048), B256, 0, stream>>>((const f32x4*)tok, (u16x4*)U(0), (u16x4*)U(4), 524288);
  // S2: ka|qa merged projection (z=0 -> {W_ka,b_ka}, z=1 -> {W_qa,b_qa})
  kProj<<<dim3(32,4,2), B256, 65536, stream>>>(
      U(0),U(4), U(16),U(17),
      F(148), dummyF, U(22),U(30), dummyK, 512, 512, 0, 262144, 2097152, 512, 1.f);
  // S3: qry split
  split_act2h<<<dim3(8192), B256, 0, stream>>>((const f32x4*)qry, (u16x4*)U(46), (u16x4*)U(62), 2097152);
  // S4: qq projection -> qqP0@78, qqP1@110
  kProj<<<dim3(128,4,1), B256, 65536, stream>>>(
      U(46),U(62), U(16.5),U(17.5),
      b_qa, dummyF, U(78),U(110), dummyK, 512, 512, 0,0,0,0, 1.f);
  // S5: supp split (over dead tok / dead qryP0)
  split_act2h<<<dim3(8192), B256, 0, stream>>>((const f32x4*)supp, (u16x4*)U(0), (u16x4*)U(46), 2097152);
  // S6: ks projection -> ksP0@94, ksP1@126
  kProj<<<dim3(128,4,1), B256, 65536, stream>>>(
      U(0),U(46), U(18),U(18.5),
      b_ks, dummyF, U(94),U(126), dummyK, 512, 512, 0,0,0,0, 1.f);
  // S7: vs^T (reads suppP0) -> vsT@62 (over dead qryP1); XCD swizzle (2 z/XCD)
  kVsT<<<dim3(8,4,16), B256, 32768, stream>>>(
      U(0),dummyU, U(19),dummyU,
      b_vs, dummyF, U(62),dummyU, dummyK, 512, 1024,
      524288, 0, 524288, 0, 1.f);
  // S8: MERGED scores (z=0..15: qt = qq.ka^T/8; z=16..31: sa = ks.qa^T/8)
  //     XCD swizzle: 4 whole z per XCD (r20-verified: FETCH 98.6->41.3 MB)
  kScore<<<dim3(8,2,32), B256, 65536, stream>>>(
      U(78),U(110), U(22),U(30),
      nullptr, dummyF, U(0),U(46), KY(148.5), 512, 256,
      524288, 131072, 262144, 0, 0.125f);
  // FFN weight splits (region 142-145 free throughout)
  split_wT1<false><<<dim3(16,48), BW, 0, stream>>>(W_f1, U(142), 512, 1536);
  split_wT1<false><<<dim3(48,16), BW, 0, stream>>>(W_f2, U(143.5), 1536, 512);
  // S9: MERGED logits = sa . qt^T -> Lg fp32 @78; XCD swizzle (2 z/XCD)
  kLogit<<<dim3(8,8,16), B256, 65536, stream>>>(
      U(8),U(54), U(0),U(46),
      nullptr, F(78), dummyU,dummyU, dummyK, 256, 1024,
      262144, 262144, 1048576, 0, 1.f);
  // S10: masked softmax (full rows) -> P^T bf16 @0 (32 MiB)
  softmax_T<<<dim3(64,16), B256, 0, stream>>>(F(78), KY(148.5) + 16384, KY(148.5), U(0));
  // S11: dec = P^T . vs -> bf16 @32; XCD swizzle (per-z ws 3 MiB < 4 MiB L2)
  kPV<<<dim3(8,4,16), B256, 32768, stream>>>(
      U(0),dummyU, U(62),dummyU,
      nullptr, dummyF, U(32),dummyU, dummyK, 1024, 512,
      1048576, 524288, 524288, 0, 1.f);
  // S12: FFN1 = relu(dec @ W_f1 + b1) -> bf16 @94 (over dead Lg)
  kFFN1<<<dim3(128,12,1), B256, 32768, stream>>>(
      U(32),dummyU, U(142),dummyU,
      b_f1, dummyF, U(94),dummyU, dummyK, 512, 1536, 0,0,0,0, 1.f);
  // S13: FFN2 = mid @ W_f2 + b2 -> d_out fp32
  kFFN2<<<dim3(128,4,1), B256, 32768, stream>>>(
      U(94),dummyU, U(143.5),dummyU,
      b_f2, (float*)d_out, dummyU,dummyU, dummyK, 1536, 512, 0,0,0,0, 1.f);
}

// Round 22
// 366.393 us; speedup vs baseline: 1.1170x; 1.0351x over previous
//
#include <hip/hip_runtime.h>

typedef float          f32x4  __attribute__((ext_vector_type(4)));
typedef short          bf16x8 __attribute__((ext_vector_type(8)));
typedef _Float16       f16x8  __attribute__((ext_vector_type(8)));
typedef unsigned short u16x4  __attribute__((ext_vector_type(4)));

static constexpr int kBS = 16;
static constexpr int kHW = 1024;

__device__ __forceinline__ unsigned short f2bf(float x) {
  union { float f; unsigned int u; } v; v.f = x;
  unsigned int r = v.u + 0x7fffu + ((v.u >> 16) & 1u);
  return (unsigned short)(r >> 16);
}
__device__ __forceinline__ float bf2f(unsigned short h) {
  union { unsigned int u; float f; } v; v.u = ((unsigned int)h) << 16;
  return v.f;
}
__device__ __forceinline__ unsigned short h2u(_Float16 h) {
  union { _Float16 h; unsigned short u; } v; v.h = h; return v.u;
}
// order-preserving f32 -> u32 (finite floats)
__device__ __forceinline__ unsigned int fmono(float f) {
  union { float f; unsigned int u; } v; v.f = f;
  return (v.u & 0x80000000u) ? ~v.u : (v.u | 0x80000000u);
}

// 2-plane fp16 split with 4096-scaled residual: x ~= p0 + p1/4096.
__device__ __forceinline__ void split2h(float x, unsigned short& u0, unsigned short& u1) {
  _Float16 h0 = (_Float16)x;
  if (fabsf(x) < 6.1035156e-05f) h0 = (_Float16)0.f;
  const float r = (x - (float)h0) * 4096.f;
  u0 = h2u(h0);
  u1 = h2u((_Float16)r);
}

// ---------------------------------------------------------------------------
// init_aux: zero argmax key buffer (32768 x u64) + stage ka|qa biases
// adjacently. Replaces 1 memset + 2 d2d memcpys (3 dispatch boundaries -> 1).
// ---------------------------------------------------------------------------
__global__ __launch_bounds__(256)
void init_aux(unsigned long long* __restrict__ keys, float* __restrict__ biasDst,
              const float* __restrict__ b_ka, const float* __restrict__ b_qa)
{
  const int b = blockIdx.x;
  if (b < 64) {
    const int i = (b * 256 + threadIdx.x) * 2;
    keys[i] = 0ull; keys[i + 1] = 0ull;
  } else {
#pragma unroll
    for (int u = 0; u < 4; ++u) {
      const int idx = threadIdx.x + u * 256;
      biasDst[idx] = (idx < 512) ? b_ka[idx] : b_qa[idx - 512];
    }
  }
}

// ---------------------------------------------------------------------------
__global__ __launch_bounds__(256)
void split_act2h(const f32x4* __restrict__ X, u16x4* __restrict__ P0,
                 u16x4* __restrict__ P1, int n4)
{
  int i = blockIdx.x * 256 + threadIdx.x;
  if (i >= n4) return;
  f32x4 x = X[i];
  u16x4 s0, s1;
#pragma unroll
  for (int u = 0; u < 4; ++u) {
    unsigned short a, b;
    split2h(x[u], a, b);
    s0[u] = a; s1[u] = b;
  }
  P0[i] = s0; P1[i] = s1;
}

// ---------------------------------------------------------------------------
// Merged 512x512 weight split: z=0 W_ka, z=1 W_qa, z=2 W_ks (fp16 2-plane
// W^T), z=3 W_vs (fp16 1-plane W^T). 4 dispatches -> 1.
// ---------------------------------------------------------------------------
__global__ __launch_bounds__(256)
void split_w_all(const float* __restrict__ Wka, const float* __restrict__ Wqa,
                 const float* __restrict__ Wks, const float* __restrict__ Wvs,
                 unsigned short* __restrict__ ka0, unsigned short* __restrict__ ka1,
                 unsigned short* __restrict__ qa0, unsigned short* __restrict__ qa1,
                 unsigned short* __restrict__ ks0, unsigned short* __restrict__ ks1,
                 unsigned short* __restrict__ vs0)
{
  __shared__ float ts[32][33];
  const int z = blockIdx.z;
  const float* src = (z == 0) ? Wka : (z == 1) ? Wqa : (z == 2) ? Wks : Wvs;
  unsigned short* d0 = (z == 0) ? ka0 : (z == 1) ? qa0 : (z == 2) ? ks0 : vs0;
  unsigned short* d1 = (z == 0) ? ka1 : (z == 1) ? qa1 : (z == 2) ? ks1 : vs0;
  constexpr int K = 512, N = 512;
  const int k0 = blockIdx.x * 32, n0 = blockIdx.y * 32;
  const int tx = threadIdx.x, ty = threadIdx.y;   // 32 x 8
#pragma unroll
  for (int r = 0; r < 4; ++r)
    ts[ty + r * 8][tx] = src[(size_t)(k0 + ty + r * 8) * N + n0 + tx];
  __syncthreads();
#pragma unroll
  for (int r = 0; r < 4; ++r) {
    const int n = ty + r * 8;
    const float x = ts[tx][n];
    const size_t off = (size_t)(n0 + n) * K + k0 + tx;
    if (z == 3) {
      d0[off] = h2u((_Float16)x);
    } else {
      unsigned short a, b;
      split2h(x, a, b);
      d0[off] = a; d1[off] = b;
    }
  }
}

// bf16 W^T 1-plane split (FFN weights; non-square geometry)
template<bool F16>
__global__ __launch_bounds__(256)
void split_wT1(const float* __restrict__ Wm, unsigned short* __restrict__ T0,
               int K, int N)
{
  __shared__ float ts[32][33];
  const int k0 = blockIdx.x * 32, n0 = blockIdx.y * 32;
  const int tx = threadIdx.x, ty = threadIdx.y;
#pragma unroll
  for (int r = 0; r < 4; ++r)
    ts[ty + r * 8][tx] = Wm[(size_t)(k0 + ty + r * 8) * N + n0 + tx];
  __syncthreads();
#pragma unroll
  for (int r = 0; r < 4; ++r) {
    const int n = ty + r * 8;
    const float x = ts[tx][n];
    const size_t off = (size_t)(n0 + n) * K + k0 + tx;
    T0[off] = F16 ? h2u((_Float16)x) : f2bf(x);
  }
}

// ---------------------------------------------------------------------------
// Staging: one 128x32 16-bit tile -> linear LDS via global_load_lds(16B),
// involution pre-swizzled source cols. 2 loads/wave.
// ---------------------------------------------------------------------------
__device__ __forceinline__ void stage_tile(const unsigned short* src, int K,
                                           unsigned short* ldst, int wv, int lane)
{
#pragma unroll
  for (int i = 0; i < 2; ++i) {
    const int s   = wv * 128 + i * 64 + lane;
    const int row = s >> 2;
    const int gc  = ((s & 3) ^ ((row >> 1) & 3)) * 8;
    __builtin_amdgcn_global_load_lds(
        (const __attribute__((address_space(1))) void*)(src + (size_t)row * K + gc),
        (__attribute__((address_space(3))) void*)(ldst + ((wv * 128 + i * 64) << 3)),
        16, 0, 0);
  }
}

// ---------------------------------------------------------------------------
// Unified 128x128 MFMA GEMM engine (r10 measured-best config). 4 waves, BK=32,
// KU tiles/phase, DEPTH-deep circular dbuf with counted vmcnt.
//  ORD0: 1-pass;  ORD1: fp16 scaled-residual 2-plane, 3 passes.
// OUTM: 0=f32, 1=2 fp16 planes, 3=bf16, 4=bf16 transposed ([N][M], ldc),
//       5=2 fp16 planes + fused row-argmax (packed-key atomicMax).
// SWZ: chunked XCD swizzle (bijective, requires nwg%8==0) [T1/m204;
//      r20-verified: score FETCH 98.6->41.3 MB].
// Batched via z strides sA/sB/sC/sBias (affine merged dispatches).
// ---------------------------------------------------------------------------
template<int ORD, int KU, int DEPTH, int OUTM, bool BIAS, bool RELU, bool F16IN, bool SWZ>
__global__ __launch_bounds__(256)
void gke(const unsigned short* __restrict__ A0, const unsigned short* __restrict__ A1,
         const unsigned short* __restrict__ B0, const unsigned short* __restrict__ B1,
         const float* __restrict__ bias,
         float* __restrict__ Cf, unsigned short* __restrict__ O0,
         unsigned short* __restrict__ O1, unsigned long long* __restrict__ keys,
         int K, int ldc, long sA, long sB, long sC, long sBias, float scale)
{
  constexpr int NP   = ORD + 1;
  constexpr int NT   = 2 * NP;
  constexpr int TPP  = KU * NT;
  constexpr int LPP  = TPP * 2;
  static_assert(DEPTH == 2 || DEPTH == 4, "DEPTH in {2,4}");
  static_assert(LPP == 4 || LPP == 8 || LPP == 16, "vmcnt literals");
  extern __shared__ __align__(16) unsigned short lds[];

  const int tid  = threadIdx.x;
  const int wv   = tid >> 6, lane = tid & 63;
  const int wr   = wv >> 1,  wc   = wv & 1;
  const int cr   = lane & 15, cg  = lane >> 4;

  unsigned bx = blockIdx.x, by = blockIdx.y, bz = blockIdx.z;
  if constexpr (SWZ) {
    const unsigned gx = gridDim.x, gy = gridDim.y;
    const unsigned nwg = gx * gy * gridDim.z;      // must be %8==0
    const unsigned lin = blockIdx.x + gx * (blockIdx.y + gy * blockIdx.z);
    const unsigned w = (lin & 7u) * (nwg >> 3) + (lin >> 3);
    bx = w % gx; by = (w / gx) % gy; bz = w / (gx * gy);
  }
  const int bm = bx * 128, bn = by * 128;

  const size_t zA = (size_t)bz * (size_t)sA;
  const size_t zB = (size_t)bz * (size_t)sB;
  const size_t zC = (size_t)bz * (size_t)sC;
  const size_t zBias = (size_t)bz * (size_t)sBias;

  const unsigned short* srcs[NT];
  srcs[0] = A0 + zA + (size_t)bm * K;
  if (NP == 2) srcs[1] = A1 + zA + (size_t)bm * K;
  srcs[NP + 0] = B0 + zB + (size_t)bn * K;
  if (NP == 2) srcs[NP + 1] = B1 + zB + (size_t)bn * K;

  f32x4 acc0[4][4], acc1[4][4];
#pragma unroll
  for (int i = 0; i < 4; ++i)
#pragma unroll
    for (int j = 0; j < 4; ++j)
#pragma unroll
      for (int r = 0; r < 4; ++r) {
        acc0[i][j][r] = 0.f;
        if (ORD == 1) acc1[i][j][r] = 0.f;
      }

#define STAGE_PH(ph, buf)                                                       \
  {                                                                             \
    _Pragma("unroll")                                                           \
    for (int u = 0; u < KU; ++u)                                                \
      _Pragma("unroll")                                                         \
      for (int t = 0; t < NT; ++t)                                              \
        stage_tile(srcs[t] + ((ph) * KU + u) * 32, K,                           \
                   lds + (size_t)((buf) * TPP + u * NT + t) * 4096, wv, lane);  \
  }
#define LOADA(u, pa)                                                            \
  {                                                                             \
    _Pragma("unroll")                                                           \
    for (int f = 0; f < 4; ++f) {                                               \
      const int ra = wr * 64 + f * 16 + cr;                                     \
      af[f] = *(const bf16x8*)&lb[(size_t)((u) * NT + (pa)) * 4096 +            \
                                  (ra * 4 + (cg ^ ((ra >> 1) & 3))) * 8];       \
    }                                                                           \
  }
#define DOPB(u, pb, ACC)                                                        \
  {                                                                             \
    bf16x8 bfr[4];                                                              \
    _Pragma("unroll")                                                           \
    for (int f = 0; f < 4; ++f) {                                               \
      const int rb = wc * 64 + f * 16 + cr;                                     \
      bfr[f] = *(const bf16x8*)&lb[(size_t)((u) * NT + NP + (pb)) * 4096 +      \
                                   (rb * 4 + (cg ^ ((rb >> 1) & 3))) * 8];      \
    }                                                                           \
    _Pragma("unroll")                                                           \
    for (int i = 0; i < 4; ++i)                                                 \
      _Pragma("unroll")                                                         \
      for (int j = 0; j < 4; ++j) {                                             \
        if constexpr (F16IN)                                                    \
          ACC[i][j] = __builtin_amdgcn_mfma_f32_16x16x32_f16(                   \
              __builtin_bit_cast(f16x8, af[i]), __builtin_bit_cast(f16x8, bfr[j]), \
              ACC[i][j], 0, 0, 0);                                              \
        else                                                                    \
          ACC[i][j] = __builtin_amdgcn_mfma_f32_16x16x32_bf16(af[i], bfr[j],    \
              ACC[i][j], 0, 0, 0);                                              \
      }                                                                         \
  }
#define COMPUTE_PH(buf)                                                         \
  {                                                                             \
    const unsigned short* lb = lds + (size_t)(buf) * TPP * 4096;                \
    bf16x8 af[4];                                                               \
    _Pragma("unroll")                                                           \
    for (int u = 0; u < KU; ++u) {                                              \
      if constexpr (ORD == 1) {                                                 \
        LOADA(u, 0); DOPB(u, 0, acc0); DOPB(u, 1, acc1);                        \
        LOADA(u, 1); DOPB(u, 0, acc1);                                          \
      } else {                                                                  \
        LOADA(u, 0); DOPB(u, 0, acc0);                                          \
      }                                                                         \
    }                                                                           \
  }

  const int nph = K / (32 * KU);
#pragma unroll
  for (int d = 0; d < DEPTH; ++d)
    if (d < nph) STAGE_PH(d, d);

  for (int ph = 0; ph < nph; ++ph) {
    const int rem = nph - 1 - ph;
    const int fut = rem < (DEPTH - 1) ? rem : (DEPTH - 1);
    if constexpr (LPP == 4) {
      if (fut >= 3)      asm volatile("s_waitcnt vmcnt(12)" ::: "memory");
      else if (fut == 2) asm volatile("s_waitcnt vmcnt(8)" ::: "memory");
      else if (fut == 1) asm volatile("s_waitcnt vmcnt(4)" ::: "memory");
      else               asm volatile("s_waitcnt vmcnt(0)" ::: "memory");
    } else if constexpr (LPP == 8) {
      if (fut >= 3)      asm volatile("s_waitcnt vmcnt(24)" ::: "memory");
      else if (fut == 2) asm volatile("s_waitcnt vmcnt(16)" ::: "memory");
      else if (fut == 1) asm volatile("s_waitcnt vmcnt(8)" ::: "memory");
      else               asm volatile("s_waitcnt vmcnt(0)" ::: "memory");
    } else {
      if (fut >= 1)      asm volatile("s_waitcnt vmcnt(16)" ::: "memory");
      else               asm volatile("s_waitcnt vmcnt(0)" ::: "memory");
    }
    __builtin_amdgcn_sched_barrier(0);
    __builtin_amdgcn_s_barrier();        // all waves' stores for buf landed
    COMPUTE_PH(ph & (DEPTH - 1));
    __builtin_amdgcn_s_barrier();        // all readers of buf done
    __builtin_amdgcn_sched_barrier(0);
    if (ph + DEPTH < nph) STAGE_PH(ph + DEPTH, ph & (DEPTH - 1));
  }
#undef STAGE_PH
#undef LOADA
#undef DOPB
#undef COMPUTE_PH

  // epilogue: C/D layout col = lane&15, row = 4*(lane>>4)+reg  [m89-verified]
  const float RS = 2.44140625e-4f;       // 1/4096
  float* CfB = Cf + zC;
  unsigned short* O0B = O0 + zC;
  unsigned short* O1B = O1 + zC;

  if constexpr (OUTM == 5) {
#pragma unroll
    for (int fm = 0; fm < 4; ++fm) {
      const int m0 = bm + wr * 64 + fm * 16 + 4 * cg;
      unsigned long long bk[4] = {0ull, 0ull, 0ull, 0ull};
#pragma unroll
      for (int fn = 0; fn < 4; ++fn) {
        const int n = bn + wc * 64 + fn * 16 + cr;
#pragma unroll
        for (int r = 0; r < 4; ++r) {
          const float x = (acc0[fm][fn][r] + acc1[fm][fn][r] * RS) * scale;
          unsigned short a, b;
          split2h(x, a, b);
          const size_t off = (size_t)(m0 + r) * ldc + n;
          O0B[off] = a; O1B[off] = b;
          const unsigned long long k =
              ((unsigned long long)fmono(x) << 32) | (unsigned)(255 - n);
          if (k > bk[r]) bk[r] = k;
        }
      }
#pragma unroll
      for (int r = 0; r < 4; ++r) {
        unsigned long long k = bk[r];
#pragma unroll
        for (int o = 1; o < 16; o <<= 1) {
          const unsigned long long ok =
              (unsigned long long)__shfl_xor((long long)k, o, 16);
          if (ok > k) k = ok;
        }
        if ((lane & 15) == 0)
          atomicMax(keys + (size_t)bz * 1024 + (m0 + r), k);
      }
    }
    return;
  }

#pragma unroll
  for (int fm = 0; fm < 4; ++fm) {
#pragma unroll
    for (int fn = 0; fn < 4; ++fn) {
      const int n  = bn + wc * 64 + fn * 16 + cr;
      const int m0 = bm + wr * 64 + fm * 16 + 4 * cg;
      float bv = 0.f;
      if (BIAS) bv = bias[zBias + n];
      if (OUTM == 4) {
        u16x4 o;
#pragma unroll
        for (int r = 0; r < 4; ++r) {
          float x = acc0[fm][fn][r];
          if constexpr (ORD == 1) x += acc1[fm][fn][r] * RS;
          x = x * scale + bv;
          if (RELU) x = fmaxf(x, 0.f);
          o[r] = f2bf(x);
        }
        *(u16x4*)(O0B + (size_t)n * ldc + m0) = o;
      } else {
#pragma unroll
        for (int r = 0; r < 4; ++r) {
          float x = acc0[fm][fn][r];
          if constexpr (ORD == 1) x += acc1[fm][fn][r] * RS;
          x = x * scale + bv;
          if (RELU) x = fmaxf(x, 0.f);
          const size_t off = (size_t)(m0 + r) * ldc + n;
          if (OUTM == 0) CfB[off] = x;
          else if (OUTM == 3) O0B[off] = f2bf(x);
          else {
            unsigned short a, b;
            split2h(x, a, b);
            O0B[off] = a; O1B[off] = b;
          }
        }
      }
    }
  }
}

// ---------------------------------------------------------------------------
// Masked softmax over full rows of length 1024; emits P^T[b][j][i] bf16.
// Lg layout [b][1024][1024]. Argmax indices decoded from packed keys:
// idx = 255 - (key & 0xFFFFFFFF).
// ---------------------------------------------------------------------------
__global__ __launch_bounds__(256)
void softmax_T(const float* __restrict__ Lg, const unsigned long long* __restrict__ keysA,
               const unsigned long long* __restrict__ keysB,
               unsigned short* __restrict__ PT)
{
  __shared__ int bj[1024];
  __shared__ unsigned short tile[1024 * 17];
  const int tid = threadIdx.x;
  const int i0  = blockIdx.x * 16;          // 0..1008
  const int b   = blockIdx.y;
  const int r   = tid >> 4;
  const int l16 = tid & 15;

  for (int j = tid; j < 1024; j += 256)
    bj[j] = 255 - (int)(keysB[(b << 10) + j] & 0xFFFFFFFFull);
  __syncthreads();

  const int ai = 255 - (int)(keysA[(b << 10) + i0 + r] & 0xFFFFFFFFull);
  const float* Lr = Lg + ((size_t)(b << 10) + i0 + r) * 1024;
  const int jb = l16 * 64;

  float x[64];
  float mx = -3.0e38f;
#pragma unroll
  for (int q = 0; q < 16; ++q) {
    f32x4 f = *(const f32x4*)(Lr + jb + (q << 2));
#pragma unroll
    for (int u = 0; u < 4; ++u) {
      const int j = jb + (q << 2) + u;
      float t = f[u];
      if (bj[j] != ai) t -= 1e6f;
      x[(q << 2) + u] = t;
      mx = fmaxf(mx, t);
    }
  }
#pragma unroll
  for (int off = 8; off >= 1; off >>= 1) mx = fmaxf(mx, __shfl_xor(mx, off));
  float s = 0.f;
#pragma unroll
  for (int k = 0; k < 64; ++k) { float e = expf(x[k] - mx); x[k] = e; s += e; }
#pragma unroll
  for (int off = 8; off >= 1; off >>= 1) s += __shfl_xor(s, off);
  const float inv = 1.f / s;

#pragma unroll
  for (int k = 0; k < 64; ++k)
    tile[(jb + k) * 17 + r] = f2bf(x[k] * inv);
  __syncthreads();

  for (int j = tid; j < 1024; j += 256) {
    const unsigned short* tp = &tile[j * 17];
    unsigned int w[8];
#pragma unroll
    for (int q = 0; q < 8; ++q)
      w[q] = (unsigned int)tp[2 * q] | ((unsigned int)tp[2 * q + 1] << 16);
    const size_t off = ((size_t)b << 20) + ((size_t)j << 10) + i0;
    unsigned int* dst = (unsigned int*)(PT + off);
    *(uint4*)dst       = make_uint4(w[0], w[1], w[2], w[3]);
    *((uint4*)dst + 1) = make_uint4(w[4], w[5], w[6], w[7]);
  }
}

// ---------------------------------------------------------------------------
extern "C" void kernel_launch(void* const* d_in, const int* in_sizes, int n_in,
                              void* d_out, int out_size, void* d_ws, size_t ws_size,
                              hipStream_t stream)
{
  (void)in_sizes; (void)n_in; (void)out_size; (void)ws_size;

  const float* tok  = (const float*)d_in[0];
  const float* supp = (const float*)d_in[1];
  const float* qry  = (const float*)d_in[2];
  const float* W_qa = (const float*)d_in[3];
  const float* b_qa = (const float*)d_in[4];
  const float* W_ks = (const float*)d_in[5];
  const float* b_ks = (const float*)d_in[6];
  const float* W_ka = (const float*)d_in[7];
  const float* b_ka = (const float*)d_in[8];
  const float* W_vs = (const float*)d_in[9];
  const float* b_vs = (const float*)d_in[10];
  const float* W_f1 = (const float*)d_in[11];
  const float* b_f1 = (const float*)d_in[12];
  const float* W_f2 = (const float*)d_in[13];
  const float* b_f2 = (const float*)d_in[14];

  auto kProj  = &gke<1,1,2,1,true ,false,true ,false>;  // 64 KB, vmcnt(8)
  auto kScore = &gke<1,1,2,5,false,false,true ,true >;  // 64 KB + XCD swizzle
  auto kLogit = &gke<1,1,2,0,false,false,true ,true >;  // 64 KB + XCD swizzle
  auto kVsT   = &gke<0,1,2,4,true ,false,true ,true >;  // 32 KB fp16 + swizzle
  auto kPV    = &gke<0,1,2,3,false,false,false,true >;  // 32 KB bf16 + swizzle
  auto kFFN1  = &gke<0,1,2,3,true ,true ,false,false>;  // 32 KB bf16
  auto kFFN2  = &gke<0,1,2,0,true ,false,false,false>;  // 32 KB bf16
  hipFuncSetAttribute((const void*)kProj,  hipFuncAttributeMaxDynamicSharedMemorySize, 65536);
  hipFuncSetAttribute((const void*)kScore, hipFuncAttributeMaxDynamicSharedMemorySize, 65536);
  hipFuncSetAttribute((const void*)kLogit, hipFuncAttributeMaxDynamicSharedMemorySize, 65536);
  hipFuncSetAttribute((const void*)kVsT,   hipFuncAttributeMaxDynamicSharedMemorySize, 32768);
  hipFuncSetAttribute((const void*)kPV,    hipFuncAttributeMaxDynamicSharedMemorySize, 32768);
  hipFuncSetAttribute((const void*)kFFN1,  hipFuncAttributeMaxDynamicSharedMemorySize, 32768);
  hipFuncSetAttribute((const void*)kFFN2,  hipFuncAttributeMaxDynamicSharedMemorySize, 32768);

  char* W = (char*)d_ws;
  constexpr size_t MiB = 1048576;
  auto U = [&](double off) { return (unsigned short*)(W + (size_t)(off * MiB)); };
  auto F = [&](double off) { return (float*)(W + (size_t)(off * MiB)); };
  auto KY = [&](double off) { return (unsigned long long*)(W + (size_t)(off * MiB)); };

  // layout (MiB), audited (passing since r18):
  // tokP 0-8 -> suppP0 0-16 -> score[qt|sa] P0 0-16 -> PT 0-32
  // W: KA_p0@16 QA_p0@16.5 KA_p1@17 QA_p1@17.5 KS_p0@18 KS_p1@18.5 VS@19
  // kaqa P0 22-30, P1 30-38 (dead after S8) | dec 32-48 (written S11)
  // qryP0 46-62 -> suppP1 46-62 -> score P1 46-62 | qryP1 62-78 -> vsT 62-78
  // qq/ks planes 78-142 -> Lg 78-142 -> mid 94-142 (disjoint from dec 32-48)
  // WF1 142-143.5, WF2 143.5-145 | bias 148, keys 148.5-148.75
  const dim3 B256(256), BW(32, 8);
  float* dummyF = F(78);
  unsigned short* dummyU = U(78);
  unsigned long long* dummyK = KY(78);

  // S0: init aux (zero merged keys + stage ka|qa biases adjacently)
  init_aux<<<dim3(65), B256, 0, stream>>>(KY(148.5), F(148), b_ka, b_qa);

  // S1: merged weight split (ka/qa/ks 2-plane + vs 1-plane) + tok split
  split_w_all<<<dim3(16,16,4), BW, 0, stream>>>(
      W_ka, W_qa, W_ks, W_vs,
      U(16), U(17), U(16.5), U(17.5), U(18), U(18.5), U(19));
  split_act2h<<<dim3(2048), B256, 0, stream>>>((const f32x4*)tok, (u16x4*)U(0), (u16x4*)U(4), 524288);
  // S2: ka|qa merged projection (z=0 -> {W_ka,b_ka}, z=1 -> {W_qa,b_qa})
  kProj<<<dim3(32,4,2), B256, 65536, stream>>>(
      U(0),U(4), U(16),U(17),
      F(148), dummyF, U(22),U(30), dummyK, 512, 512, 0, 262144, 2097152, 512, 1.f);
  // S3: qry split
  split_act2h<<<dim3(8192), B256, 0, stream>>>((const f32x4*)qry, (u16x4*)U(46), (u16x4*)U(62), 2097152);
  // S4: qq projection -> qqP0@78, qqP1@110
  kProj<<<dim3(128,4,1), B256, 65536, stream>>>(
      U(46),U(62), U(16.5),U(17.5),
      b_qa, dummyF, U(78),U(110), dummyK, 512, 512, 0,0,0,0, 1.f);
  // S5: supp split (over dead tok / dead qryP0)
  split_act2h<<<dim3(8192), B256, 0, stream>>>((const f32x4*)supp, (u16x4*)U(0), (u16x4*)U(46), 2097152);
  // S6: ks projection -> ksP0@94, ksP1@126
  kProj<<<dim3(128,4,1), B256, 65536, stream>>>(
      U(0),U(46), U(18),U(18.5),
      b_ks, dummyF, U(94),U(126), dummyK, 512, 512, 0,0,0,0, 1.f);
  // S7: vs^T (reads suppP0) -> vsT@62 (over dead qryP1); XCD swizzle
  kVsT<<<dim3(8,4,16), B256, 32768, stream>>>(
      U(0),dummyU, U(19),dummyU,
      b_vs, dummyF, U(62),dummyU, dummyK, 512, 1024,
      524288, 0, 524288, 0, 1.f);
  // S8: MERGED scores (z=0..15: qt = qq.ka^T/8; z=16..31: sa = ks.qa^T/8)
  //     XCD swizzle (r20-verified: FETCH 98.6->41.3 MB)
  kScore<<<dim3(8,2,32), B256, 65536, stream>>>(
      U(78),U(110), U(22),U(30),
      nullptr, dummyF, U(0),U(46), KY(148.5), 512, 256,
      524288, 131072, 262144, 0, 0.125f);
  // FFN weight splits (region 142-145 free throughout)
  split_wT1<false><<<dim3(16,48), BW, 0, stream>>>(W_f1, U(142), 512, 1536);
  split_wT1<false><<<dim3(48,16), BW, 0, stream>>>(W_f2, U(143.5), 1536, 512);
  // S9: MERGED logits = sa . qt^T -> Lg fp32 @78; XCD swizzle
  kLogit<<<dim3(8,8,16), B256, 65536, stream>>>(
      U(8),U(54), U(0),U(46),
      nullptr, F(78), dummyU,dummyU, dummyK, 256, 1024,
      262144, 262144, 1048576, 0, 1.f);
  // S10: masked softmax (full rows) -> P^T bf16 @0 (32 MiB)
  softmax_T<<<dim3(64,16), B256, 0, stream>>>(F(78), KY(148.5) + 16384, KY(148.5), U(0));
  // S11: dec = P^T . vs -> bf16 @32; XCD swizzle
  kPV<<<dim3(8,4,16), B256, 32768, stream>>>(
      U(0),dummyU, U(62),dummyU,
      nullptr, dummyF, U(32),dummyU, dummyK, 1024, 512,
      1048576, 524288, 524288, 0, 1.f);
  // S12: FFN1 = relu(dec @ W_f1 + b1) -> bf16 @94 (over dead Lg)
  kFFN1<<<dim3(128,12,1), B256, 32768, stream>>>(
      U(32),dummyU, U(142),dummyU,
      b_f1, dummyF, U(94),dummyU, dummyK, 512, 1536, 0,0,0,0, 1.f);
  // S13: FFN2 = mid @ W_f2 + b2 -> d_out fp32
  kFFN2<<<dim3(128,4,1), B256, 32768, stream>>>(
      U(94),dummyU, U(143.5),dummyU,
      b_f2, (float*)d_out, dummyU,dummyU, dummyK, 1536, 512, 0,0,0,0, 1.f);
}

// Round 23
// 364.742 us; speedup vs baseline: 1.1221x; 1.0045x over previous
//
#include <hip/hip_runtime.h>

typedef float          f32x4  __attribute__((ext_vector_type(4)));
typedef short          bf16x8 __attribute__((ext_vector_type(8)));
typedef _Float16       f16x8  __attribute__((ext_vector_type(8)));
typedef unsigned short u16x4  __attribute__((ext_vector_type(4)));

static constexpr int kBS = 16;
static constexpr int kHW = 1024;

__device__ __forceinline__ unsigned short f2bf(float x) {
  union { float f; unsigned int u; } v; v.f = x;
  unsigned int r = v.u + 0x7fffu + ((v.u >> 16) & 1u);
  return (unsigned short)(r >> 16);
}
__device__ __forceinline__ float bf2f(unsigned short h) {
  union { unsigned int u; float f; } v; v.u = ((unsigned int)h) << 16;
  return v.f;
}
__device__ __forceinline__ unsigned short h2u(_Float16 h) {
  union { _Float16 h; unsigned short u; } v; v.h = h; return v.u;
}
// order-preserving f32 -> u32 (finite floats)
__device__ __forceinline__ unsigned int fmono(float f) {
  union { float f; unsigned int u; } v; v.f = f;
  return (v.u & 0x80000000u) ? ~v.u : (v.u | 0x80000000u);
}

// 2-plane fp16 split with 4096-scaled residual: x ~= p0 + p1/4096.
__device__ __forceinline__ void split2h(float x, unsigned short& u0, unsigned short& u1) {
  _Float16 h0 = (_Float16)x;
  if (fabsf(x) < 6.1035156e-05f) h0 = (_Float16)0.f;
  const float r = (x - (float)h0) * 4096.f;
  u0 = h2u(h0);
  u1 = h2u((_Float16)r);
}

// ---------------------------------------------------------------------------
// init_aux: zero argmax key buffer (32768 x u64) + stage ka|qa biases.
// ---------------------------------------------------------------------------
__global__ __launch_bounds__(256)
void init_aux(unsigned long long* __restrict__ keys, float* __restrict__ biasDst,
              const float* __restrict__ b_ka, const float* __restrict__ b_qa)
{
  const int b = blockIdx.x;
  if (b < 64) {
    const int i = (b * 256 + threadIdx.x) * 2;
    keys[i] = 0ull; keys[i + 1] = 0ull;
  } else {
#pragma unroll
    for (int u = 0; u < 4; ++u) {
      const int idx = threadIdx.x + u * 256;
      biasDst[idx] = (idx < 512) ? b_ka[idx] : b_qa[idx - 512];
    }
  }
}

// ---------------------------------------------------------------------------
// single-input fp32 -> 2 fp16 planes (used for supp, which must run after S4)
// ---------------------------------------------------------------------------
__global__ __launch_bounds__(256)
void split_act2h(const f32x4* __restrict__ X, u16x4* __restrict__ P0,
                 u16x4* __restrict__ P1, int n4)
{
  int i = blockIdx.x * 256 + threadIdx.x;
  if (i >= n4) return;
  f32x4 x = X[i];
  u16x4 s0, s1;
#pragma unroll
  for (int u = 0; u < 4; ++u) {
    unsigned short a, b;
    split2h(x[u], a, b);
    s0[u] = a; s1[u] = b;
  }
  P0[i] = s0; P1[i] = s1;
}

// ---------------------------------------------------------------------------
// MERGED tok+qry act split: blocks [0,2048) -> tok (524288 f32x4),
// blocks [2048,10240) -> qry (2097152 f32x4). Exact multiples, no bounds.
// ---------------------------------------------------------------------------
__global__ __launch_bounds__(256)
void split_act2h_2(const f32x4* __restrict__ X0, u16x4* __restrict__ A0,
                   u16x4* __restrict__ A1,
                   const f32x4* __restrict__ X1, u16x4* __restrict__ B0,
                   u16x4* __restrict__ B1)
{
  const int b = blockIdx.x;
  const f32x4* X; u16x4 *P0, *P1; int i;
  if (b < 2048) { X = X0; P0 = A0; P1 = A1; i = b * 256 + threadIdx.x; }
  else          { X = X1; P0 = B0; P1 = B1; i = (b - 2048) * 256 + threadIdx.x; }
  f32x4 x = X[i];
  u16x4 s0, s1;
#pragma unroll
  for (int u = 0; u < 4; ++u) {
    unsigned short a, b2;
    split2h(x[u], a, b2);
    s0[u] = a; s1[u] = b2;
  }
  P0[i] = s0; P1[i] = s1;
}

// ---------------------------------------------------------------------------
// Merged 512x512 weight split: z=0 W_ka, z=1 W_qa, z=2 W_ks (fp16 2-plane
// W^T), z=3 W_vs (fp16 1-plane W^T).
// ---------------------------------------------------------------------------
__global__ __launch_bounds__(256)
void split_w_all(const float* __restrict__ Wka, const float* __restrict__ Wqa,
                 const float* __restrict__ Wks, const float* __restrict__ Wvs,
                 unsigned short* __restrict__ ka0, unsigned short* __restrict__ ka1,
                 unsigned short* __restrict__ qa0, unsigned short* __restrict__ qa1,
                 unsigned short* __restrict__ ks0, unsigned short* __restrict__ ks1,
                 unsigned short* __restrict__ vs0)
{
  __shared__ float ts[32][33];
  const int z = blockIdx.z;
  const float* src = (z == 0) ? Wka : (z == 1) ? Wqa : (z == 2) ? Wks : Wvs;
  unsigned short* d0 = (z == 0) ? ka0 : (z == 1) ? qa0 : (z == 2) ? ks0 : vs0;
  unsigned short* d1 = (z == 0) ? ka1 : (z == 1) ? qa1 : (z == 2) ? ks1 : vs0;
  constexpr int K = 512, N = 512;
  const int k0 = blockIdx.x * 32, n0 = blockIdx.y * 32;
  const int tx = threadIdx.x, ty = threadIdx.y;   // 32 x 8
#pragma unroll
  for (int r = 0; r < 4; ++r)
    ts[ty + r * 8][tx] = src[(size_t)(k0 + ty + r * 8) * N + n0 + tx];
  __syncthreads();
#pragma unroll
  for (int r = 0; r < 4; ++r) {
    const int n = ty + r * 8;
    const float x = ts[tx][n];
    const size_t off = (size_t)(n0 + n) * K + k0 + tx;
    if (z == 3) {
      d0[off] = h2u((_Float16)x);
    } else {
      unsigned short a, b;
      split2h(x, a, b);
      d0[off] = a; d1[off] = b;
    }
  }
}

// ---------------------------------------------------------------------------
// MERGED FFN weight split (bf16 W^T): y=0 -> W_f1 (K=512,N=1536, 16x48
// block grid); y=1 -> W_f2 (K=1536,N=512, 48x16). 768 blocks per z.
// ---------------------------------------------------------------------------
__global__ __launch_bounds__(256)
void split_w_ffn(const float* __restrict__ Wf1, const float* __restrict__ Wf2,
                 unsigned short* __restrict__ T1o, unsigned short* __restrict__ T2o)
{
  __shared__ float ts[32][33];
  const int z = blockIdx.y;
  const float* Wm = z ? Wf2 : Wf1;
  unsigned short* T0 = z ? T2o : T1o;
  const int K = z ? 1536 : 512, N = z ? 512 : 1536;
  const int nbx = z ? 48 : 16;
  const int k0 = (blockIdx.x % nbx) * 32, n0 = (blockIdx.x / nbx) * 32;
  const int tx = threadIdx.x, ty = threadIdx.y;   // 32 x 8
#pragma unroll
  for (int r = 0; r < 4; ++r)
    ts[ty + r * 8][tx] = Wm[(size_t)(k0 + ty + r * 8) * N + n0 + tx];
  __syncthreads();
#pragma unroll
  for (int r = 0; r < 4; ++r) {
    const int n = ty + r * 8;
    const size_t off = (size_t)(n0 + n) * K + k0 + tx;
    T0[off] = f2bf(ts[tx][n]);
  }
}

// ---------------------------------------------------------------------------
// Staging: one 128x32 16-bit tile -> linear LDS via global_load_lds(16B),
// involution pre-swizzled source cols. 2 loads/wave.
// ---------------------------------------------------------------------------
__device__ __forceinline__ void stage_tile(const unsigned short* src, int K,
                                           unsigned short* ldst, int wv, int lane)
{
#pragma unroll
  for (int i = 0; i < 2; ++i) {
    const int s   = wv * 128 + i * 64 + lane;
    const int row = s >> 2;
    const int gc  = ((s & 3) ^ ((row >> 1) & 3)) * 8;
    __builtin_amdgcn_global_load_lds(
        (const __attribute__((address_space(1))) void*)(src + (size_t)row * K + gc),
        (__attribute__((address_space(3))) void*)(ldst + ((wv * 128 + i * 64) << 3)),
        16, 0, 0);
  }
}

// ---------------------------------------------------------------------------
// Unified 128x128 MFMA GEMM engine (r10 measured-best config). 4 waves, BK=32,
// KU tiles/phase, DEPTH-deep circular dbuf with counted vmcnt.
//  ORD0: 1-pass;  ORD1: fp16 scaled-residual 2-plane, 3 passes.
// OUTM: 0=f32, 1=2 fp16 planes, 3=bf16, 4=bf16 transposed ([N][M], ldc),
//       5=2 fp16 planes + fused row-argmax (packed-key atomicMax).
// SWZ: chunked XCD swizzle (bijective, requires nwg%8==0) [T1/m204;
//      r20-verified: score FETCH 98.6->41.3 MB].
// Batched via z strides sA/sB/sC/sBias (affine merged dispatches).
// ---------------------------------------------------------------------------
template<int ORD, int KU, int DEPTH, int OUTM, bool BIAS, bool RELU, bool F16IN, bool SWZ>
__global__ __launch_bounds__(256)
void gke(const unsigned short* __restrict__ A0, const unsigned short* __restrict__ A1,
         const unsigned short* __restrict__ B0, const unsigned short* __restrict__ B1,
         const float* __restrict__ bias,
         float* __restrict__ Cf, unsigned short* __restrict__ O0,
         unsigned short* __restrict__ O1, unsigned long long* __restrict__ keys,
         int K, int ldc, long sA, long sB, long sC, long sBias, float scale)
{
  constexpr int NP   = ORD + 1;
  constexpr int NT   = 2 * NP;
  constexpr int TPP  = KU * NT;
  constexpr int LPP  = TPP * 2;
  static_assert(DEPTH == 2 || DEPTH == 4, "DEPTH in {2,4}");
  static_assert(LPP == 4 || LPP == 8 || LPP == 16, "vmcnt literals");
  extern __shared__ __align__(16) unsigned short lds[];

  const int tid  = threadIdx.x;
  const int wv   = tid >> 6, lane = tid & 63;
  const int wr   = wv >> 1,  wc   = wv & 1;
  const int cr   = lane & 15, cg  = lane >> 4;

  unsigned bx = blockIdx.x, by = blockIdx.y, bz = blockIdx.z;
  if constexpr (SWZ) {
    const unsigned gx = gridDim.x, gy = gridDim.y;
    const unsigned nwg = gx * gy * gridDim.z;      // must be %8==0
    const unsigned lin = blockIdx.x + gx * (blockIdx.y + gy * blockIdx.z);
    const unsigned w = (lin & 7u) * (nwg >> 3) + (lin >> 3);
    bx = w % gx; by = (w / gx) % gy; bz = w / (gx * gy);
  }
  const int bm = bx * 128, bn = by * 128;

  const size_t zA = (size_t)bz * (size_t)sA;
  const size_t zB = (size_t)bz * (size_t)sB;
  const size_t zC = (size_t)bz * (size_t)sC;
  const size_t zBias = (size_t)bz * (size_t)sBias;

  const unsigned short* srcs[NT];
  srcs[0] = A0 + zA + (size_t)bm * K;
  if (NP == 2) srcs[1] = A1 + zA + (size_t)bm * K;
  srcs[NP + 0] = B0 + zB + (size_t)bn * K;
  if (NP == 2) srcs[NP + 1] = B1 + zB + (size_t)bn * K;

  f32x4 acc0[4][4], acc1[4][4];
#pragma unroll
  for (int i = 0; i < 4; ++i)
#pragma unroll
    for (int j = 0; j < 4; ++j)
#pragma unroll
      for (int r = 0; r < 4; ++r) {
        acc0[i][j][r] = 0.f;
        if (ORD == 1) acc1[i][j][r] = 0.f;
      }

#define STAGE_PH(ph, buf)                                                       \
  {                                                                             \
    _Pragma("unroll")                                                           \
    for (int u = 0; u < KU; ++u)                                                \
      _Pragma("unroll")                                                         \
      for (int t = 0; t < NT; ++t)                                              \
        stage_tile(srcs[t] + ((ph) * KU + u) * 32, K,                           \
                   lds + (size_t)((buf) * TPP + u * NT + t) * 4096, wv, lane);  \
  }
#define LOADA(u, pa)                                                            \
  {                                                                             \
    _Pragma("unroll")                                                           \
    for (int f = 0; f < 4; ++f) {                                               \
      const int ra = wr * 64 + f * 16 + cr;                                     \
      af[f] = *(const bf16x8*)&lb[(size_t)((u) * NT + (pa)) * 4096 +            \
                                  (ra * 4 + (cg ^ ((ra >> 1) & 3))) * 8];       \
    }                                                                           \
  }
#define DOPB(u, pb, ACC)                                                        \
  {                                                                             \
    bf16x8 bfr[4];                                                              \
    _Pragma("unroll")                                                           \
    for (int f = 0; f < 4; ++f) {                                               \
      const int rb = wc * 64 + f * 16 + cr;                                     \
      bfr[f] = *(const bf16x8*)&lb[(size_t)((u) * NT + NP + (pb)) * 4096 +      \
                                   (rb * 4 + (cg ^ ((rb >> 1) & 3))) * 8];      \
    }                                                                           \
    _Pragma("unroll")                                                           \
    for (int i = 0; i < 4; ++i)                                                 \
      _Pragma("unroll")                                                         \
      for (int j = 0; j < 4; ++j) {                                             \
        if constexpr (F16IN)                                                    \
          ACC[i][j] = __builtin_amdgcn_mfma_f32_16x16x32_f16(                   \
              __builtin_bit_cast(f16x8, af[i]), __builtin_bit_cast(f16x8, bfr[j]), \
              ACC[i][j], 0, 0, 0);                                              \
        else                                                                    \
          ACC[i][j] = __builtin_amdgcn_mfma_f32_16x16x32_bf16(af[i], bfr[j],    \
              ACC[i][j], 0, 0, 0);                                              \
      }                                                                         \
  }
#define COMPUTE_PH(buf)                                                         \
  {                                                                             \
    const unsigned short* lb = lds + (size_t)(buf) * TPP * 4096;                \
    bf16x8 af[4];                                                               \
    _Pragma("unroll")                                                           \
    for (int u = 0; u < KU; ++u) {                                              \
      if constexpr (ORD == 1) {                                                 \
        LOADA(u, 0); DOPB(u, 0, acc0); DOPB(u, 1, acc1);                        \
        LOADA(u, 1); DOPB(u, 0, acc1);                                          \
      } else {                                                                  \
        LOADA(u, 0); DOPB(u, 0, acc0);                                          \
      }                                                                         \
    }                                                                           \
  }

  const int nph = K / (32 * KU);
#pragma unroll
  for (int d = 0; d < DEPTH; ++d)
    if (d < nph) STAGE_PH(d, d);

  for (int ph = 0; ph < nph; ++ph) {
    const int rem = nph - 1 - ph;
    const int fut = rem < (DEPTH - 1) ? rem : (DEPTH - 1);
    if constexpr (LPP == 4) {
      if (fut >= 3)      asm volatile("s_waitcnt vmcnt(12)" ::: "memory");
      else if (fut == 2) asm volatile("s_waitcnt vmcnt(8)" ::: "memory");
      else if (fut == 1) asm volatile("s_waitcnt vmcnt(4)" ::: "memory");
      else               asm volatile("s_waitcnt vmcnt(0)" ::: "memory");
    } else if constexpr (LPP == 8) {
      if (fut >= 3)      asm volatile("s_waitcnt vmcnt(24)" ::: "memory");
      else if (fut == 2) asm volatile("s_waitcnt vmcnt(16)" ::: "memory");
      else if (fut == 1) asm volatile("s_waitcnt vmcnt(8)" ::: "memory");
      else               asm volatile("s_waitcnt vmcnt(0)" ::: "memory");
    } else {
      if (fut >= 1)      asm volatile("s_waitcnt vmcnt(16)" ::: "memory");
      else               asm volatile("s_waitcnt vmcnt(0)" ::: "memory");
    }
    __builtin_amdgcn_sched_barrier(0);
    __builtin_amdgcn_s_barrier();        // all waves' stores for buf landed
    COMPUTE_PH(ph & (DEPTH - 1));
    __builtin_amdgcn_s_barrier();        // all readers of buf done
    __builtin_amdgcn_sched_barrier(0);
    if (ph + DEPTH < nph) STAGE_PH(ph + DEPTH, ph & (DEPTH - 1));
  }
#undef STAGE_PH
#undef LOADA
#undef DOPB
#undef COMPUTE_PH

  // epilogue: C/D layout col = lane&15, row = 4*(lane>>4)+reg  [m89-verified]
  const float RS = 2.44140625e-4f;       // 1/4096
  float* CfB = Cf + zC;
  unsigned short* O0B = O0 + zC;
  unsigned short* O1B = O1 + zC;

  if constexpr (OUTM == 5) {
#pragma unroll
    for (int fm = 0; fm < 4; ++fm) {
      const int m0 = bm + wr * 64 + fm * 16 + 4 * cg;
      unsigned long long bk[4] = {0ull, 0ull, 0ull, 0ull};
#pragma unroll
      for (int fn = 0; fn < 4; ++fn) {
        const int n = bn + wc * 64 + fn * 16 + cr;
#pragma unroll
        for (int r = 0; r < 4; ++r) {
          const float x = (acc0[fm][fn][r] + acc1[fm][fn][r] * RS) * scale;
          unsigned short a, b;
          split2h(x, a, b);
          const size_t off = (size_t)(m0 + r) * ldc + n;
          O0B[off] = a; O1B[off] = b;
          const unsigned long long k =
              ((unsigned long long)fmono(x) << 32) | (unsigned)(255 - n);
          if (k > bk[r]) bk[r] = k;
        }
      }
#pragma unroll
      for (int r = 0; r < 4; ++r) {
        unsigned long long k = bk[r];
#pragma unroll
        for (int o = 1; o < 16; o <<= 1) {
          const unsigned long long ok =
              (unsigned long long)__shfl_xor((long long)k, o, 16);
          if (ok > k) k = ok;
        }
        if ((lane & 15) == 0)
          atomicMax(keys + (size_t)bz * 1024 + (m0 + r), k);
      }
    }
    return;
  }

#pragma unroll
  for (int fm = 0; fm < 4; ++fm) {
#pragma unroll
    for (int fn = 0; fn < 4; ++fn) {
      const int n  = bn + wc * 64 + fn * 16 + cr;
      const int m0 = bm + wr * 64 + fm * 16 + 4 * cg;
      float bv = 0.f;
      if (BIAS) bv = bias[zBias + n];
      if (OUTM == 4) {
        u16x4 o;
#pragma unroll
        for (int r = 0; r < 4; ++r) {
          float x = acc0[fm][fn][r];
          if constexpr (ORD == 1) x += acc1[fm][fn][r] * RS;
          x = x * scale + bv;
          if (RELU) x = fmaxf(x, 0.f);
          o[r] = f2bf(x);
        }
        *(u16x4*)(O0B + (size_t)n * ldc + m0) = o;
      } else {
#pragma unroll
        for (int r = 0; r < 4; ++r) {
          float x = acc0[fm][fn][r];
          if constexpr (ORD == 1) x += acc1[fm][fn][r] * RS;
          x = x * scale + bv;
          if (RELU) x = fmaxf(x, 0.f);
          const size_t off = (size_t)(m0 + r) * ldc + n;
          if (OUTM == 0) CfB[off] = x;
          else if (OUTM == 3) O0B[off] = f2bf(x);
          else {
            unsigned short a, b;
            split2h(x, a, b);
            O0B[off] = a; O1B[off] = b;
          }
        }
      }
    }
  }
}

// ---------------------------------------------------------------------------
// Masked softmax over full rows of length 1024; emits P^T[b][j][i] bf16.
// Lg layout [b][1024][1024]. Argmax indices decoded from packed keys:
// idx = 255 - (key & 0xFFFFFFFF).
// ---------------------------------------------------------------------------
__global__ __launch_bounds__(256)
void softmax_T(const float* __restrict__ Lg, const unsigned long long* __restrict__ keysA,
               const unsigned long long* __restrict__ keysB,
               unsigned short* __restrict__ PT)
{
  __shared__ int bj[1024];
  __shared__ unsigned short tile[1024 * 17];
  const int tid = threadIdx.x;
  const int i0  = blockIdx.x * 16;          // 0..1008
  const int b   = blockIdx.y;
  const int r   = tid >> 4;
  const int l16 = tid & 15;

  for (int j = tid; j < 1024; j += 256)
    bj[j] = 255 - (int)(keysB[(b << 10) + j] & 0xFFFFFFFFull);
  __syncthreads();

  const int ai = 255 - (int)(keysA[(b << 10) + i0 + r] & 0xFFFFFFFFull);
  const float* Lr = Lg + ((size_t)(b << 10) + i0 + r) * 1024;
  const int jb = l16 * 64;

  float x[64];
  float mx = -3.0e38f;
#pragma unroll
  for (int q = 0; q < 16; ++q) {
    f32x4 f = *(const f32x4*)(Lr + jb + (q << 2));
#pragma unroll
    for (int u = 0; u < 4; ++u) {
      const int j = jb + (q << 2) + u;
      float t = f[u];
      if (bj[j] != ai) t -= 1e6f;
      x[(q << 2) + u] = t;
      mx = fmaxf(mx, t);
    }
  }
#pragma unroll
  for (int off = 8; off >= 1; off >>= 1) mx = fmaxf(mx, __shfl_xor(mx, off));
  float s = 0.f;
#pragma unroll
  for (int k = 0; k < 64; ++k) { float e = expf(x[k] - mx); x[k] = e; s += e; }
#pragma unroll
  for (int off = 8; off >= 1; off >>= 1) s += __shfl_xor(s, off);
  const float inv = 1.f / s;

#pragma unroll
  for (int k = 0; k < 64; ++k)
    tile[(jb + k) * 17 + r] = f2bf(x[k] * inv);
  __syncthreads();

  for (int j = tid; j < 1024; j += 256) {
    const unsigned short* tp = &tile[j * 17];
    unsigned int w[8];
#pragma unroll
    for (int q = 0; q < 8; ++q)
      w[q] = (unsigned int)tp[2 * q] | ((unsigned int)tp[2 * q + 1] << 16);
    const size_t off = ((size_t)b << 20) + ((size_t)j << 10) + i0;
    unsigned int* dst = (unsigned int*)(PT + off);
    *(uint4*)dst       = make_uint4(w[0], w[1], w[2], w[3]);
    *((uint4*)dst + 1) = make_uint4(w[4], w[5], w[6], w[7]);
  }
}

// ---------------------------------------------------------------------------
extern "C" void kernel_launch(void* const* d_in, const int* in_sizes, int n_in,
                              void* d_out, int out_size, void* d_ws, size_t ws_size,
                              hipStream_t stream)
{
  (void)in_sizes; (void)n_in; (void)out_size; (void)ws_size;

  const float* tok  = (const float*)d_in[0];
  const float* supp = (const float*)d_in[1];
  const float* qry  = (const float*)d_in[2];
  const float* W_qa = (const float*)d_in[3];
  const float* b_qa = (const float*)d_in[4];
  const float* W_ks = (const float*)d_in[5];
  const float* b_ks = (const float*)d_in[6];
  const float* W_ka = (const float*)d_in[7];
  const float* b_ka = (const float*)d_in[8];
  const float* W_vs = (const float*)d_in[9];
  const float* b_vs = (const float*)d_in[10];
  const float* W_f1 = (const float*)d_in[11];
  const float* b_f1 = (const float*)d_in[12];
  const float* W_f2 = (const float*)d_in[13];
  const float* b_f2 = (const float*)d_in[14];

  auto kProj  = &gke<1,1,2,1,true ,false,true ,false>;  // 64 KB, vmcnt(8)
  auto kScore = &gke<1,1,2,5,false,false,true ,true >;  // 64 KB + XCD swizzle
  auto kLogit = &gke<1,1,2,0,false,false,true ,true >;  // 64 KB + XCD swizzle
  auto kVsT   = &gke<0,1,2,4,true ,false,true ,true >;  // 32 KB fp16 + swizzle
  auto kPV    = &gke<0,1,2,3,false,false,false,true >;  // 32 KB bf16 + swizzle
  auto kFFN1  = &gke<0,1,2,3,true ,true ,false,false>;  // 32 KB bf16
  auto kFFN2  = &gke<0,1,2,0,true ,false,false,false>;  // 32 KB bf16
  hipFuncSetAttribute((const void*)kProj,  hipFuncAttributeMaxDynamicSharedMemorySize, 65536);
  hipFuncSetAttribute((const void*)kScore, hipFuncAttributeMaxDynamicSharedMemorySize, 65536);
  hipFuncSetAttribute((const void*)kLogit, hipFuncAttributeMaxDynamicSharedMemorySize, 65536);
  hipFuncSetAttribute((const void*)kVsT,   hipFuncAttributeMaxDynamicSharedMemorySize, 32768);
  hipFuncSetAttribute((const void*)kPV,    hipFuncAttributeMaxDynamicSharedMemorySize, 32768);
  hipFuncSetAttribute((const void*)kFFN1,  hipFuncAttributeMaxDynamicSharedMemorySize, 32768);
  hipFuncSetAttribute((const void*)kFFN2,  hipFuncAttributeMaxDynamicSharedMemorySize, 32768);

  char* W = (char*)d_ws;
  constexpr size_t MiB = 1048576;
  auto U = [&](double off) { return (unsigned short*)(W + (size_t)(off * MiB)); };
  auto F = [&](double off) { return (float*)(W + (size_t)(off * MiB)); };
  auto KY = [&](double off) { return (unsigned long long*)(W + (size_t)(off * MiB)); };

  // layout (MiB), audited (passing since r18):
  // tokP 0-8 -> suppP0 0-16 -> score[qt|sa] P0 0-16 -> PT 0-32
  // W: KA_p0@16 QA_p0@16.5 KA_p1@17 QA_p1@17.5 KS_p0@18 KS_p1@18.5 VS@19
  // kaqa P0 22-30, P1 30-38 (dead after S8) | dec 32-48 (written S11)
  // qryP0 46-62 -> suppP1 46-62 -> score P1 46-62 | qryP1 62-78 -> vsT 62-78
  // qq/ks planes 78-142 -> Lg 78-142 -> mid 94-142 (disjoint from dec 32-48)
  // WF1 142-143.5, WF2 143.5-145 | bias 148, keys 148.5-148.75
  const dim3 B256(256), BW(32, 8);
  float* dummyF = F(78);
  unsigned short* dummyU = U(78);
  unsigned long long* dummyK = KY(78);

  // S0: init aux (zero merged keys + stage ka|qa biases adjacently)
  init_aux<<<dim3(65), B256, 0, stream>>>(KY(148.5), F(148), b_ka, b_qa);

  // S1: merged weight split + MERGED tok+qry act split (2 dispatches)
  split_w_all<<<dim3(16,16,4), BW, 0, stream>>>(
      W_ka, W_qa, W_ks, W_vs,
      U(16), U(17), U(16.5), U(17.5), U(18), U(18.5), U(19));
  split_act2h_2<<<dim3(10240), B256, 0, stream>>>(
      (const f32x4*)tok, (u16x4*)U(0), (u16x4*)U(4),
      (const f32x4*)qry, (u16x4*)U(46), (u16x4*)U(62));
  // S2: ka|qa merged projection (z=0 -> {W_ka,b_ka}, z=1 -> {W_qa,b_qa})
  kProj<<<dim3(32,4,2), B256, 65536, stream>>>(
      U(0),U(4), U(16),U(17),
      F(148), dummyF, U(22),U(30), dummyK, 512, 512, 0, 262144, 2097152, 512, 1.f);
  // S4: qq projection -> qqP0@78, qqP1@110
  kProj<<<dim3(128,4,1), B256, 65536, stream>>>(
      U(46),U(62), U(16.5),U(17.5),
      b_qa, dummyF, U(78),U(110), dummyK, 512, 512, 0,0,0,0, 1.f);
  // S5: supp split (over dead tok / dead qryP0)
  split_act2h<<<dim3(8192), B256, 0, stream>>>((const f32x4*)supp, (u16x4*)U(0), (u16x4*)U(46), 2097152);
  // S6: ks projection -> ksP0@94, ksP1@126
  kProj<<<dim3(128,4,1), B256, 65536, stream>>>(
      U(0),U(46), U(18),U(18.5),
      b_ks, dummyF, U(94),U(126), dummyK, 512, 512, 0,0,0,0, 1.f);
  // S7: vs^T (reads suppP0) -> vsT@62 (over dead qryP1); XCD swizzle
  kVsT<<<dim3(8,4,16), B256, 32768, stream>>>(
      U(0),dummyU, U(19),dummyU,
      b_vs, dummyF, U(62),dummyU, dummyK, 512, 1024,
      524288, 0, 524288, 0, 1.f);
  // S8: MERGED scores (z=0..15: qt = qq.ka^T/8; z=16..31: sa = ks.qa^T/8)
  //     XCD swizzle (r20-verified: FETCH 98.6->41.3 MB)
  kScore<<<dim3(8,2,32), B256, 65536, stream>>>(
      U(78),U(110), U(22),U(30),
      nullptr, dummyF, U(0),U(46), KY(148.5), 512, 256,
      524288, 131072, 262144, 0, 0.125f);
  // MERGED FFN weight split (region 142-145 free throughout)
  split_w_ffn<<<dim3(768,2), BW, 0, stream>>>(W_f1, W_f2, U(142), U(143.5));
  // S9: MERGED logits = sa . qt^T -> Lg fp32 @78; XCD swizzle
  kLogit<<<dim3(8,8,16), B256, 65536, stream>>>(
      U(8),U(54), U(0),U(46),
      nullptr, F(78), dummyU,dummyU, dummyK, 256, 1024,
      262144, 262144, 1048576, 0, 1.f);
  // S10: masked softmax (full rows) -> P^T bf16 @0 (32 MiB)
  softmax_T<<<dim3(64,16), B256, 0, stream>>>(F(78), KY(148.5) + 16384, KY(148.5), U(0));
  // S11: dec = P^T . vs -> bf16 @32; XCD swizzle
  kPV<<<dim3(8,4,16), B256, 32768, stream>>>(
      U(0),dummyU, U(62),dummyU,
      nullptr, dummyF, U(32),dummyU, dummyK, 1024, 512,
      1048576, 524288, 524288, 0, 1.f);
  // S12: FFN1 = relu(dec @ W_f1 + b1) -> bf16 @94 (over dead Lg)
  kFFN1<<<dim3(128,12,1), B256, 32768, stream>>>(
      U(32),dummyU, U(142),dummyU,
      b_f1, dummyF, U(94),dummyU, dummyK, 512, 1536, 0,0,0,0, 1.f);
  // S13: FFN2 = mid @ W_f2 + b2 -> d_out fp32
  kFFN2<<<dim3(128,4,1), B256, 32768, stream>>>(
      U(94),dummyU, U(143.5),dummyU,
      b_f2, (float*)d_out, dummyU,dummyU, dummyK, 1536, 512, 0,0,0,0, 1.f);
}